// Round 4
// baseline (2590.760 us; speedup 1.0000x reference)
//
#include <hip/hip_runtime.h>

typedef unsigned short bf16;

#define B_    2
#define S_    64
#define R_    2048
#define D_    1024
#define H_    16
#define KVH_  4
#define SCALE_ 0.125f

__device__ __forceinline__ void load4(const float* p, float* dst) {
  float4 v = *reinterpret_cast<const float4*>(p);
  dst[0] = v.x; dst[1] = v.y; dst[2] = v.z; dst[3] = v.w;
}

// Generic GEMM: Y = X@W + b. X: [N][K] f32, W: [K][C] f32, b: [C] f32.
// EPI: 1 = RoPE-1D + head-split fp32 [b][h][pos][64]
//      2 = RoPE-2D (structural bar=pos>>5, tib=pos&31) + head-split fp32
//      3 = head-split fp32, no rope
//      4 = plain fp32 [N][C] (final output)
template<int EPI>
__global__ __launch_bounds__(256)
void gemm_k(const float* __restrict__ X, const float* __restrict__ W,
            const float* __restrict__ Bv, void* __restrict__ outp,
            int K, int C, int LB)
{
  __shared__ float Xs[64][17];
  __shared__ float Ws[16][64];
  __shared__ float Tile[(EPI == 1 || EPI == 2) ? 64 * 65 : 1];

  const int tid = threadIdx.x;
  const int tx = tid & 15, ty = tid >> 4;
  const int c0 = blockIdx.x * 64, r0 = blockIdx.y * 64;

  float acc[4][4] = {};

  const int xi = tid >> 2, xk = (tid & 3) * 4;
  const int wk = tid >> 4, wj = (tid & 15) * 4;

  for (int k0 = 0; k0 < K; k0 += 16) {
    float t4[4];
    load4(X + (size_t)(r0 + xi) * K + k0 + xk, t4);
    Xs[xi][xk + 0] = t4[0]; Xs[xi][xk + 1] = t4[1];
    Xs[xi][xk + 2] = t4[2]; Xs[xi][xk + 3] = t4[3];
    load4(W + (size_t)(k0 + wk) * C + c0 + wj, t4);
    Ws[wk][wj + 0] = t4[0]; Ws[wk][wj + 1] = t4[1];
    Ws[wk][wj + 2] = t4[2]; Ws[wk][wj + 3] = t4[3];
    __syncthreads();
    #pragma unroll
    for (int kk = 0; kk < 16; kk++) {
      float a[4], b[4];
      #pragma unroll
      for (int i = 0; i < 4; i++) a[i] = Xs[ty * 4 + i][kk];
      #pragma unroll
      for (int j = 0; j < 4; j++) b[j] = Ws[kk][tx * 4 + j];
      #pragma unroll
      for (int i = 0; i < 4; i++)
        #pragma unroll
        for (int j = 0; j < 4; j++)
          acc[i][j] += a[i] * b[j];
    }
    __syncthreads();
  }

  float bv[4];
  #pragma unroll
  for (int j = 0; j < 4; j++) bv[j] = Bv[c0 + tx * 4 + j];

  if constexpr (EPI == 4) {
    float* out = (float*)outp;
    #pragma unroll
    for (int i = 0; i < 4; i++)
      #pragma unroll
      for (int j = 0; j < 4; j++)
        out[(size_t)(r0 + ty * 4 + i) * C + c0 + tx * 4 + j] = acc[i][j] + bv[j];
  } else if constexpr (EPI == 3) {
    float* out = (float*)outp;
    const int NH = C >> 6;
    #pragma unroll
    for (int i = 0; i < 4; i++) {
      int rr = r0 + ty * 4 + i;
      int b = rr / LB, pos = rr - b * LB;
      #pragma unroll
      for (int j = 0; j < 4; j++) {
        int cc = c0 + tx * 4 + j;
        out[(((size_t)b * NH + (cc >> 6)) * LB + pos) * 64 + (cc & 63)] = acc[i][j] + bv[j];
      }
    }
  } else {
    // RoPE epilogue: column tile c0..c0+63 spans exactly one head, so the
    // rotate_half partner (d ^ 32) is inside this tile. Stage to LDS first.
    #pragma unroll
    for (int i = 0; i < 4; i++)
      #pragma unroll
      for (int j = 0; j < 4; j++)
        Tile[(ty * 4 + i) * 65 + tx * 4 + j] = acc[i][j] + bv[j];
    __syncthreads();
    float* out = (float*)outp;
    const int NH = C >> 6;
    const int hh = c0 >> 6;
    #pragma unroll
    for (int i = 0; i < 4; i++) {
      int li = ty * 4 + i;
      int rr = r0 + li;
      int b = rr / LB, pos = rr - b * LB;
      #pragma unroll
      for (int j = 0; j < 4; j++) {
        int lj = tx * 4 + j;
        float v0 = Tile[li * 65 + lj];
        float v1 = Tile[li * 65 + (lj ^ 32)];
        int m = lj & 31;
        float ang;
        if constexpr (EPI == 1) {
          // 1D RoPE: inv[m] = 10000^(-m/32), angle = pos * inv
          ang = (float)pos * powf(10000.f, -(float)m / 32.f);
        } else {
          // 2D RoPE, structural ids: bar = pos>>5, tib = pos&31
          int bar = pos >> 5;
          int tib = pos & 31;
          ang = (m < 16) ? (float)bar * powf(10000.f, -(float)m / 16.f)
                         : (float)tib * powf(10000.f, -(float)(m - 16) / 16.f);
        }
        float cs = cosf(ang), sn = sinf(ang);
        float rot = (lj < 32) ? -v1 : v1;   // rotate_half: [-x2, x1]
        out[(((size_t)b * NH + hh) * LB + pos) * 64 + lj] = v0 * cs + rot * sn;
      }
    }
  }
}

// Flash-style masked GQA attention over concat([summary(64), regular(2048)]) keys.
// PHASE 1: summary query i: summary key j ok if j<=i; regular key t ok if (t>>5)<=i
// PHASE 2: regular query t: summary key s ok if s<=(t>>5); regular key s ok if s<=t
template<int PHASE>
__global__ __launch_bounds__(256)
void attn_k(const float* __restrict__ Q, const float* __restrict__ KS,
            const float* __restrict__ KR, const float* __restrict__ VS,
            const float* __restrict__ VR, float* __restrict__ Out)
{
  const int LQ  = (PHASE == 1) ? S_ : R_;
  const int NTQ = LQ / 32;
  const int gid = blockIdx.x;
  const int qt  = gid % NTQ;
  const int h   = (gid / NTQ) % H_;
  const int b   = gid / (NTQ * H_);
  const int q0  = qt * 32;
  const int kh  = h >> 2;                            // GQA repeat_interleave(4)

  __shared__ float Qs[32][65];
  __shared__ float Ks[64][65];
  __shared__ float Vs[64][65];
  __shared__ float Ps[32][65];
  __shared__ float mrow[32], lrow[32], frow[32];

  const int tid = threadIdx.x;

  const float* qbase = Q + (((size_t)b * H_ + h) * LQ + q0) * 64;
  for (int idx = tid; idx < 32 * 16; idx += 256) {
    int qr = idx >> 4, v = idx & 15;
    float4 t = *reinterpret_cast<const float4*>(qbase + qr * 64 + v * 4);
    Qs[qr][v * 4 + 0] = t.x * SCALE_;
    Qs[qr][v * 4 + 1] = t.y * SCALE_;
    Qs[qr][v * 4 + 2] = t.z * SCALE_;
    Qs[qr][v * 4 + 3] = t.w * SCALE_;
  }
  if (tid < 32) { mrow[tid] = -1e30f; lrow[tid] = 0.f; }

  float Ol[8] = {0.f, 0.f, 0.f, 0.f, 0.f, 0.f, 0.f, 0.f};

  const int qr   = tid >> 3;
  const int kg   = tid & 7;
  const int qpos = q0 + qr;
  const int kend = (PHASE == 1) ? (64 + 32 * (q0 + 32)) : (64 + q0 + 32);
  const int ntiles = (kend + 63) >> 6;

  __syncthreads();

  for (int kt = 0; kt < ntiles; kt++) {
    const int kbase = kt * 64;
    for (int idx = tid; idx < 64 * 16; idx += 256) {
      int kr = idx >> 4, v = idx & 15;
      int kidx = kbase + kr;
      float4 tk, tv;
      if (kidx < 64) {
        size_t off = (((size_t)b * KVH_ + kh) * 64 + kidx) * 64 + v * 4;
        tk = *reinterpret_cast<const float4*>(KS + off);
        tv = *reinterpret_cast<const float4*>(VS + off);
      } else {
        size_t off = (((size_t)b * KVH_ + kh) * R_ + (kidx - 64)) * 64 + v * 4;
        tk = *reinterpret_cast<const float4*>(KR + off);
        tv = *reinterpret_cast<const float4*>(VR + off);
      }
      Ks[kr][v * 4 + 0] = tk.x; Ks[kr][v * 4 + 1] = tk.y;
      Ks[kr][v * 4 + 2] = tk.z; Ks[kr][v * 4 + 3] = tk.w;
      Vs[kr][v * 4 + 0] = tv.x; Vs[kr][v * 4 + 1] = tv.y;
      Vs[kr][v * 4 + 2] = tv.z; Vs[kr][v * 4 + 3] = tv.w;
    }
    __syncthreads();

    float s8[8] = {0, 0, 0, 0, 0, 0, 0, 0};
    #pragma unroll 4
    for (int d = 0; d < 64; d++) {
      float qv = Qs[qr][d];
      #pragma unroll
      for (int kk = 0; kk < 8; kk++) s8[kk] += qv * Ks[kg * 8 + kk][d];
    }
    float tmax = -1e30f;
    #pragma unroll
    for (int kk = 0; kk < 8; kk++) {
      int kidx = kbase + kg * 8 + kk;
      bool ok;
      if (PHASE == 1) ok = (kidx < 64) ? (kidx <= qpos) : (((kidx - 64) >> 5) <= qpos);
      else            ok = (kidx < 64) ? (kidx <= (qpos >> 5)) : ((kidx - 64) <= qpos);
      if (!ok) s8[kk] = -1e30f;
      tmax = fmaxf(tmax, s8[kk]);
    }
    #pragma unroll
    for (int off = 1; off < 8; off <<= 1) tmax = fmaxf(tmax, __shfl_xor(tmax, off));
    const float mold = mrow[qr];
    const float mnew = fmaxf(mold, tmax);
    const float fac  = expf(mold - mnew);
    float p8[8];
    float rsum = 0.f;
    #pragma unroll
    for (int kk = 0; kk < 8; kk++) { p8[kk] = expf(s8[kk] - mnew); rsum += p8[kk]; }
    #pragma unroll
    for (int off = 1; off < 8; off <<= 1) rsum += __shfl_xor(rsum, off);
    #pragma unroll
    for (int kk = 0; kk < 8; kk++) Ps[qr][kg * 8 + kk] = p8[kk];
    if (kg == 0) { mrow[qr] = mnew; lrow[qr] = lrow[qr] * fac + rsum; frow[qr] = fac; }
    __syncthreads();

    const float f = frow[qr];
    const int d0 = kg * 8;
    #pragma unroll
    for (int jd = 0; jd < 8; jd++) Ol[jd] *= f;
    #pragma unroll 4
    for (int kc = 0; kc < 64; kc++) {
      float pk = Ps[qr][kc];
      #pragma unroll
      for (int jd = 0; jd < 8; jd++) Ol[jd] += pk * Vs[kc][d0 + jd];
    }
    __syncthreads();
  }

  const float linv = 1.f / lrow[qr];
  float* o = Out + ((size_t)b * LQ + qpos) * D_ + h * 64 + kg * 8;
  #pragma unroll
  for (int jd = 0; jd < 8; jd++) o[jd] = Ol[jd] * linv;
}

extern "C" void kernel_launch(void* const* d_in, const int* in_sizes, int n_in,
                              void* d_out, int out_size, void* d_ws, size_t ws_size,
                              hipStream_t stream)
{
  (void)out_size; (void)ws_size;

  // Input order/size guard: on mismatch, launch nothing (out stays zero ->
  // distinctive absmax signature 0.2695 = max|ref0|).
  static const int expect[22] = {
    131072, 4194304,                    // sum_x, reg_x
    1048576, 1024, 262144, 256,         // w_sq,b_sq, w_sk,b_sk
    262144, 256, 1048576, 1024,         // w_sv,b_sv, w_so,b_so
    1048576, 1024, 262144, 256,         // w_rq,b_rq, w_rk,b_rk
    262144, 256, 1048576, 1024,         // w_rv,b_rv, w_ro,b_ro
    262144, 256, 262144, 256            // w_k2,b_k2, w_v2,b_v2
  };
  if (n_in < 22) return;
  for (int i = 0; i < 22; i++) if (in_sizes[i] != expect[i]) return;

  const float* sum_x = (const float*)d_in[0];
  const float* reg_x = (const float*)d_in[1];
  const float* w_sq = (const float*)d_in[2];  const float* b_sq = (const float*)d_in[3];
  const float* w_sk = (const float*)d_in[4];  const float* b_sk = (const float*)d_in[5];
  const float* w_sv = (const float*)d_in[6];  const float* b_sv = (const float*)d_in[7];
  const float* w_so = (const float*)d_in[8];  const float* b_so = (const float*)d_in[9];
  const float* w_rq = (const float*)d_in[10]; const float* b_rq = (const float*)d_in[11];
  const float* w_rk = (const float*)d_in[12]; const float* b_rk = (const float*)d_in[13];
  const float* w_rv = (const float*)d_in[14]; const float* b_rv = (const float*)d_in[15];
  const float* w_ro = (const float*)d_in[16]; const float* b_ro = (const float*)d_in[17];
  const float* w_k2 = (const float*)d_in[18]; const float* b_k2 = (const float*)d_in[19];
  const float* w_v2 = (const float*)d_in[20]; const float* b_v2 = (const float*)d_in[21];

  // fp32 workspace layout
  float* ws    = (float*)d_ws;
  float* sq    = ws;                  // [B][H][S][64]     131072
  float* sk    = sq    + 131072;      // [B][KVH][S][64]   32768
  float* sv    = sk    + 32768;       // [B][KVH][S][64]   32768
  float* rk    = sv    + 32768;       // [B][KVH][R][64]   1048576
  float* rv    = rk    + 1048576;     // [B][KVH][R][64]   1048576
  float* sattn = rv    + 1048576;     // [B*S][D]          131072
  float* rq    = sattn + 131072;      // [B][H][R][64]     4194304
  float* k2    = rq    + 4194304;     // [B][KVH][S][64]   32768
  float* v2    = k2    + 32768;       // [B][KVH][S][64]   32768
  float* rattn = v2    + 32768;       // [B*R][D]          4194304

  float* out_sum = (float*)d_out;          // (B,S,D) fp32
  float* out_reg = out_sum + 131072;       // (B,R,D) fp32

  dim3 blk(256);

  // QKV projections (+RoPE fused in epilogue)
  gemm_k<1><<<dim3(16, 2),  blk, 0, stream>>>(sum_x, w_sq, b_sq, sq, 1024, 1024, 64);
  gemm_k<1><<<dim3(4, 2),   blk, 0, stream>>>(sum_x, w_sk, b_sk, sk, 1024, 256, 64);
  gemm_k<3><<<dim3(4, 2),   blk, 0, stream>>>(sum_x, w_sv, b_sv, sv, 1024, 256, 64);
  gemm_k<2><<<dim3(16, 64), blk, 0, stream>>>(reg_x, w_rq, b_rq, rq, 1024, 1024, 2048);
  gemm_k<2><<<dim3(4, 64),  blk, 0, stream>>>(reg_x, w_rk, b_rk, rk, 1024, 256, 2048);
  gemm_k<3><<<dim3(4, 64),  blk, 0, stream>>>(reg_x, w_rv, b_rv, rv, 1024, 256, 2048);

  // phase 1: summarize
  attn_k<1><<<dim3(64), blk, 0, stream>>>(sq, sk, rk, sv, rv, sattn);

  // K2/V2 projections from sum_attn; summary output projection
  gemm_k<3><<<dim3(4, 2),  blk, 0, stream>>>(sattn, w_k2, b_k2, k2, 1024, 256, 64);
  gemm_k<3><<<dim3(4, 2),  blk, 0, stream>>>(sattn, w_v2, b_v2, v2, 1024, 256, 64);
  gemm_k<4><<<dim3(16, 2), blk, 0, stream>>>(sattn, w_so, b_so, out_sum, 1024, 1024, 64);

  // phase 2: updating
  attn_k<2><<<dim3(2048), blk, 0, stream>>>(rq, k2, rk, v2, rv, rattn);

  // regular output projection
  gemm_k<4><<<dim3(16, 64), blk, 0, stream>>>(rattn, w_ro, b_ro, out_reg, 1024, 1024, 2048);
}

// Round 5
// 1077.462 us; speedup vs baseline: 2.4045x; 2.4045x over previous
//
#include <hip/hip_runtime.h>

typedef unsigned short u16;
typedef __attribute__((ext_vector_type(8))) short s8v;   // 8 x bf16 MFMA A/B frag
typedef __attribute__((ext_vector_type(4))) float f4v;   // MFMA C/D frag

#define B_    2
#define S_    64
#define R_    2048
#define D_    1024
#define H_    16
#define KVH_  4
#define SCALE_ 0.125f

__device__ __forceinline__ u16 f2bf(float f) {
  union { float f; unsigned int i; } v; v.f = f;
  unsigned int x = v.i;
  return (u16)((x + 0x7FFFu + ((x >> 16) & 1u)) >> 16);
}

__device__ __forceinline__ void load4(const float* p, float* dst) {
  float4 v = *reinterpret_cast<const float4*>(p);
  dst[0] = v.x; dst[1] = v.y; dst[2] = v.z; dst[3] = v.w;
}

// ---------------------------------------------------------------------------
// Generic GEMM: Y = X@W + b. X: [N][K] f32, W: [K][C] f32, b: [C] f32.
// EPI: 1 = RoPE-1D + head-split fp32 [b][h][pos][64]
//      2 = RoPE-2D (structural bar=pos>>5, tib=pos&31) + head-split fp32
//      3 = head-split fp32, no rope
//      4 = plain fp32 [N][C] (final output)
// ---------------------------------------------------------------------------
template<int EPI>
__global__ __launch_bounds__(256)
void gemm_k(const float* __restrict__ X, const float* __restrict__ W,
            const float* __restrict__ Bv, void* __restrict__ outp,
            int K, int C, int LB)
{
  __shared__ float Xs[64][17];
  __shared__ float Ws[16][64];
  __shared__ float Tile[(EPI == 1 || EPI == 2) ? 64 * 65 : 1];

  const int tid = threadIdx.x;
  const int tx = tid & 15, ty = tid >> 4;
  const int c0 = blockIdx.x * 64, r0 = blockIdx.y * 64;

  float acc[4][4] = {};

  const int xi = tid >> 2, xk = (tid & 3) * 4;
  const int wk = tid >> 4, wj = (tid & 15) * 4;

  for (int k0 = 0; k0 < K; k0 += 16) {
    float t4[4];
    load4(X + (size_t)(r0 + xi) * K + k0 + xk, t4);
    Xs[xi][xk + 0] = t4[0]; Xs[xi][xk + 1] = t4[1];
    Xs[xi][xk + 2] = t4[2]; Xs[xi][xk + 3] = t4[3];
    load4(W + (size_t)(k0 + wk) * C + c0 + wj, t4);
    Ws[wk][wj + 0] = t4[0]; Ws[wk][wj + 1] = t4[1];
    Ws[wk][wj + 2] = t4[2]; Ws[wk][wj + 3] = t4[3];
    __syncthreads();
    #pragma unroll
    for (int kk = 0; kk < 16; kk++) {
      float a[4], b[4];
      #pragma unroll
      for (int i = 0; i < 4; i++) a[i] = Xs[ty * 4 + i][kk];
      #pragma unroll
      for (int j = 0; j < 4; j++) b[j] = Ws[kk][tx * 4 + j];
      #pragma unroll
      for (int i = 0; i < 4; i++)
        #pragma unroll
        for (int j = 0; j < 4; j++)
          acc[i][j] += a[i] * b[j];
    }
    __syncthreads();
  }

  float bv[4];
  #pragma unroll
  for (int j = 0; j < 4; j++) bv[j] = Bv[c0 + tx * 4 + j];

  if constexpr (EPI == 4) {
    float* out = (float*)outp;
    #pragma unroll
    for (int i = 0; i < 4; i++)
      #pragma unroll
      for (int j = 0; j < 4; j++)
        out[(size_t)(r0 + ty * 4 + i) * C + c0 + tx * 4 + j] = acc[i][j] + bv[j];
  } else if constexpr (EPI == 3) {
    float* out = (float*)outp;
    const int NH = C >> 6;
    #pragma unroll
    for (int i = 0; i < 4; i++) {
      int rr = r0 + ty * 4 + i;
      int b = rr / LB, pos = rr - b * LB;
      #pragma unroll
      for (int j = 0; j < 4; j++) {
        int cc = c0 + tx * 4 + j;
        out[(((size_t)b * NH + (cc >> 6)) * LB + pos) * 64 + (cc & 63)] = acc[i][j] + bv[j];
      }
    }
  } else {
    #pragma unroll
    for (int i = 0; i < 4; i++)
      #pragma unroll
      for (int j = 0; j < 4; j++)
        Tile[(ty * 4 + i) * 65 + tx * 4 + j] = acc[i][j] + bv[j];
    __syncthreads();
    float* out = (float*)outp;
    const int NH = C >> 6;
    const int hh = c0 >> 6;
    #pragma unroll
    for (int i = 0; i < 4; i++) {
      int li = ty * 4 + i;
      int rr = r0 + li;
      int b = rr / LB, pos = rr - b * LB;
      #pragma unroll
      for (int j = 0; j < 4; j++) {
        int lj = tx * 4 + j;
        float v0 = Tile[li * 65 + lj];
        float v1 = Tile[li * 65 + (lj ^ 32)];
        int m = lj & 31;
        float ang;
        if constexpr (EPI == 1) {
          ang = (float)pos * powf(10000.f, -(float)m / 32.f);
        } else {
          int bar = pos >> 5;
          int tib = pos & 31;
          ang = (m < 16) ? (float)bar * powf(10000.f, -(float)m / 16.f)
                         : (float)tib * powf(10000.f, -(float)(m - 16) / 16.f);
        }
        float cs = cosf(ang), sn = sinf(ang);
        float rot = (lj < 32) ? -v1 : v1;
        out[(((size_t)b * NH + hh) * LB + pos) * 64 + lj] = v0 * cs + rot * sn;
      }
    }
  }
}

// ---------------------------------------------------------------------------
// MFMA flash attention over concat([summary(64), regular(2048)]) keys, bf16.
// Block = 256 threads = 4 waves; wave w owns 16 q-rows; KV tiles of 64 keys.
// mfma_f32_16x16x32_bf16: A/B frag = lane holds free-dim row (l&15), 8
// contiguous k at (l>>4)*8 (+32 for second frag). C/D: col=l&15,
// row=(l>>4)*4+reg [m89-verified].
// PHASE 1: summary query i: summary key j<=i; regular key t: (t>>5)<=i
// PHASE 2: regular query t: summary key s<=(t>>5); regular key s<=t
// Tile 0 is all-summary (exactly 64 summary keys); key 0 is valid for every
// query in both phases => m > -1e30 after tile 0, so masked entries
// (s=-1e30) give exp(-1e30-m) == 0 exactly. No all-masked pathology.
// ---------------------------------------------------------------------------
template<int PHASE>
__global__ __launch_bounds__(256)
void mattn_k(const float* __restrict__ Q, const float* __restrict__ KS,
             const float* __restrict__ KR, const float* __restrict__ VS,
             const float* __restrict__ VR, float* __restrict__ Out)
{
  const int LQ  = (PHASE == 1) ? S_ : R_;
  const int NQB = LQ / 64;
  const int gid = blockIdx.x;
  const int qb  = gid % NQB;
  const int h   = (gid / NQB) % H_;
  const int b   = gid / (NQB * H_);
  const int q0  = qb * 64;
  const int kh  = h >> 2;                      // GQA repeat_interleave(4)

  // 72-padding: rows are 144B (16B-aligned for b128 frag reads; bank stride
  // 36 words => rows spread over even banks, max 2-way aliasing = free).
  __shared__ u16 Kt[64][72];                   // K tile,   [key][d]
  __shared__ u16 Vt[64][72];                   // V tile^T, [d][key]
  __shared__ u16 Pt[4][16][72];                // per-wave P, [q][key]

  const int tid  = threadIdx.x;
  const int lane = tid & 63;
  const int w    = tid >> 6;
  const int l15  = lane & 15;
  const int l4   = lane >> 4;
  const int qw   = q0 + w * 16;

  // Q fragments (row = l15, k = l4*8+j), pre-scaled by 1/sqrt(HD)
  s8v qf0, qf1;
  {
    const float* qp = Q + (((size_t)b * H_ + h) * LQ + qw + l15) * 64 + l4 * 8;
    float4 x0 = *(const float4*)(qp);
    float4 x1 = *(const float4*)(qp + 4);
    float4 y0 = *(const float4*)(qp + 32);
    float4 y1 = *(const float4*)(qp + 36);
    qf0[0] = (short)f2bf(x0.x * SCALE_); qf0[1] = (short)f2bf(x0.y * SCALE_);
    qf0[2] = (short)f2bf(x0.z * SCALE_); qf0[3] = (short)f2bf(x0.w * SCALE_);
    qf0[4] = (short)f2bf(x1.x * SCALE_); qf0[5] = (short)f2bf(x1.y * SCALE_);
    qf0[6] = (short)f2bf(x1.z * SCALE_); qf0[7] = (short)f2bf(x1.w * SCALE_);
    qf1[0] = (short)f2bf(y0.x * SCALE_); qf1[1] = (short)f2bf(y0.y * SCALE_);
    qf1[2] = (short)f2bf(y0.z * SCALE_); qf1[3] = (short)f2bf(y0.w * SCALE_);
    qf1[4] = (short)f2bf(y1.x * SCALE_); qf1[5] = (short)f2bf(y1.y * SCALE_);
    qf1[6] = (short)f2bf(y1.z * SCALE_); qf1[7] = (short)f2bf(y1.w * SCALE_);
  }

  f4v acc[4] = {{0.f,0.f,0.f,0.f},{0.f,0.f,0.f,0.f},{0.f,0.f,0.f,0.f},{0.f,0.f,0.f,0.f}};
  float m[4]    = {-1e30f, -1e30f, -1e30f, -1e30f};
  float lsum[4] = {0.f, 0.f, 0.f, 0.f};

  const int kend   = (PHASE == 1) ? (64 + R_) : (64 + q0 + 64);
  const int ntiles = kend >> 6;
  const size_t bh_kv = (size_t)b * KVH_ + kh;

  for (int kt = 0; kt < ntiles; kt++) {
    const int kbase = kt * 64;
    __syncthreads();                            // prev-tile LDS reads done

    // ---- stage K tile: bf16 row-major [key][d] ----
    const float* kfsrc = (kbase == 0) ? (KS + bh_kv * 64 * 64)
                                      : (KR + (bh_kv * R_ + (kbase - 64)) * 64);
    #pragma unroll
    for (int it = 0; it < 4; it++) {
      int idx = tid + it * 256;
      int k = idx >> 4, c = (idx & 15) * 4;
      float4 t = *(const float4*)(kfsrc + k * 64 + c);
      ushort4 u4;
      u4.x = f2bf(t.x); u4.y = f2bf(t.y); u4.z = f2bf(t.z); u4.w = f2bf(t.w);
      *(ushort4*)&Kt[k][c] = u4;
    }
    // ---- stage V tile transposed: bf16 [d][key] ----
    const float* vfsrc = (kbase == 0) ? (VS + bh_kv * 64 * 64)
                                      : (VR + (bh_kv * R_ + (kbase - 64)) * 64);
    {
      int d = tid & 63, kq = tid >> 6;
      unsigned int* dst = (unsigned int*)&Vt[d][kq * 16];
      #pragma unroll
      for (int j = 0; j < 8; j++) {
        float v0 = vfsrc[(kq * 16 + 2 * j) * 64 + d];
        float v1 = vfsrc[(kq * 16 + 2 * j + 1) * 64 + d];
        dst[j] = (unsigned)f2bf(v0) | ((unsigned)f2bf(v1) << 16);
      }
    }
    __syncthreads();

    // ---- QK^T: S[16 q][64 k] per wave (8 MFMA) ----
    f4v s[4];
    #pragma unroll
    for (int n = 0; n < 4; n++) {
      s8v kf0 = *(const s8v*)&Kt[n * 16 + l15][l4 * 8];
      s8v kf1 = *(const s8v*)&Kt[n * 16 + l15][32 + l4 * 8];
      f4v t = {0.f, 0.f, 0.f, 0.f};
      t = __builtin_amdgcn_mfma_f32_16x16x32_bf16(qf0, kf0, t, 0, 0, 0);
      t = __builtin_amdgcn_mfma_f32_16x16x32_bf16(qf1, kf1, t, 0, 0, 0);
      s[n] = t;
    }

    // ---- mask + row-max ----
    float rmax[4] = {-1e30f, -1e30f, -1e30f, -1e30f};
    #pragma unroll
    for (int n = 0; n < 4; n++) {
      int kidx = kbase + n * 16 + l15;
      #pragma unroll
      for (int r = 0; r < 4; r++) {
        int qrow = qw + l4 * 4 + r;
        bool ok;
        if (kbase == 0) ok = kidx <= ((PHASE == 1) ? qrow : (qrow >> 5));
        else { int kr = kidx - 64; ok = (PHASE == 1) ? ((kr >> 5) <= qrow) : (kr <= qrow); }
        float sv = ok ? s[n][r] : -1e30f;
        s[n][r] = sv;
        rmax[r] = fmaxf(rmax[r], sv);
      }
    }
    // ---- online softmax (reduce across the 16-lane key group) ----
    float fac[4];
    #pragma unroll
    for (int r = 0; r < 4; r++) {
      float v = rmax[r];
      v = fmaxf(v, __shfl_xor(v, 1));
      v = fmaxf(v, __shfl_xor(v, 2));
      v = fmaxf(v, __shfl_xor(v, 4));
      v = fmaxf(v, __shfl_xor(v, 8));
      float mn = fmaxf(m[r], v);
      fac[r] = __expf(m[r] - mn);
      m[r] = mn;
    }
    float rsum[4] = {0.f, 0.f, 0.f, 0.f};
    #pragma unroll
    for (int n = 0; n < 4; n++) {
      #pragma unroll
      for (int r = 0; r < 4; r++) {
        float p = __expf(s[n][r] - m[r]);      // masked: exp(-1e30-m) == 0
        Pt[w][l4 * 4 + r][n * 16 + l15] = f2bf(p);
        rsum[r] += p;
      }
    }
    #pragma unroll
    for (int r = 0; r < 4; r++) {
      float v = rsum[r];
      v += __shfl_xor(v, 1); v += __shfl_xor(v, 2);
      v += __shfl_xor(v, 4); v += __shfl_xor(v, 8);
      lsum[r] = lsum[r] * fac[r] + v;
      #pragma unroll
      for (int dt = 0; dt < 4; dt++) acc[dt][r] *= fac[r];
    }

    // same-wave P write -> P read ordering
    asm volatile("s_waitcnt lgkmcnt(0)" ::: "memory");

    // ---- PV: O[16 q][64 d] += P[16x64] * V[64x64] (8 MFMA) ----
    s8v pf0 = *(const s8v*)&Pt[w][l15][l4 * 8];
    s8v pf1 = *(const s8v*)&Pt[w][l15][32 + l4 * 8];
    #pragma unroll
    for (int dt = 0; dt < 4; dt++) {
      s8v vf0 = *(const s8v*)&Vt[dt * 16 + l15][l4 * 8];
      s8v vf1 = *(const s8v*)&Vt[dt * 16 + l15][32 + l4 * 8];
      acc[dt] = __builtin_amdgcn_mfma_f32_16x16x32_bf16(pf0, vf0, acc[dt], 0, 0, 0);
      acc[dt] = __builtin_amdgcn_mfma_f32_16x16x32_bf16(pf1, vf1, acc[dt], 0, 0, 0);
    }
  }

  // ---- epilogue: O / l, scatter to [b][q][h*64+d] ----
  #pragma unroll
  for (int r = 0; r < 4; r++) {
    float linv = 1.f / lsum[r];
    int qrow = qw + l4 * 4 + r;
    float* o = Out + ((size_t)b * LQ + qrow) * D_ + h * 64 + l15;
    #pragma unroll
    for (int dt = 0; dt < 4; dt++) o[dt * 16] = acc[dt][r] * linv;
  }
}

extern "C" void kernel_launch(void* const* d_in, const int* in_sizes, int n_in,
                              void* d_out, int out_size, void* d_ws, size_t ws_size,
                              hipStream_t stream)
{
  (void)out_size; (void)ws_size;

  static const int expect[22] = {
    131072, 4194304,
    1048576, 1024, 262144, 256,
    262144, 256, 1048576, 1024,
    1048576, 1024, 262144, 256,
    262144, 256, 1048576, 1024,
    262144, 256, 262144, 256
  };
  if (n_in < 22) return;
  for (int i = 0; i < 22; i++) if (in_sizes[i] != expect[i]) return;

  const float* sum_x = (const float*)d_in[0];
  const float* reg_x = (const float*)d_in[1];
  const float* w_sq = (const float*)d_in[2];  const float* b_sq = (const float*)d_in[3];
  const float* w_sk = (const float*)d_in[4];  const float* b_sk = (const float*)d_in[5];
  const float* w_sv = (const float*)d_in[6];  const float* b_sv = (const float*)d_in[7];
  const float* w_so = (const float*)d_in[8];  const float* b_so = (const float*)d_in[9];
  const float* w_rq = (const float*)d_in[10]; const float* b_rq = (const float*)d_in[11];
  const float* w_rk = (const float*)d_in[12]; const float* b_rk = (const float*)d_in[13];
  const float* w_rv = (const float*)d_in[14]; const float* b_rv = (const float*)d_in[15];
  const float* w_ro = (const float*)d_in[16]; const float* b_ro = (const float*)d_in[17];
  const float* w_k2 = (const float*)d_in[18]; const float* b_k2 = (const float*)d_in[19];
  const float* w_v2 = (const float*)d_in[20]; const float* b_v2 = (const float*)d_in[21];

  float* ws    = (float*)d_ws;
  float* sq    = ws;                  // [B][H][S][64]     131072
  float* sk    = sq    + 131072;      // [B][KVH][S][64]   32768
  float* sv    = sk    + 32768;       // [B][KVH][S][64]   32768
  float* rk    = sv    + 32768;       // [B][KVH][R][64]   1048576
  float* rv    = rk    + 1048576;     // [B][KVH][R][64]   1048576
  float* sattn = rv    + 1048576;     // [B*S][D]          131072
  float* rq    = sattn + 131072;      // [B][H][R][64]     4194304
  float* k2    = rq    + 4194304;     // [B][KVH][S][64]   32768
  float* v2    = k2    + 32768;       // [B][KVH][S][64]   32768
  float* rattn = v2    + 32768;       // [B*R][D]          4194304

  float* out_sum = (float*)d_out;          // (B,S,D) fp32
  float* out_reg = out_sum + 131072;       // (B,R,D) fp32

  dim3 blk(256);

  // QKV projections (+RoPE fused in epilogue)
  gemm_k<1><<<dim3(16, 2),  blk, 0, stream>>>(sum_x, w_sq, b_sq, sq, 1024, 1024, 64);
  gemm_k<1><<<dim3(4, 2),   blk, 0, stream>>>(sum_x, w_sk, b_sk, sk, 1024, 256, 64);
  gemm_k<3><<<dim3(4, 2),   blk, 0, stream>>>(sum_x, w_sv, b_sv, sv, 1024, 256, 64);
  gemm_k<2><<<dim3(16, 64), blk, 0, stream>>>(reg_x, w_rq, b_rq, rq, 1024, 1024, 2048);
  gemm_k<2><<<dim3(4, 64),  blk, 0, stream>>>(reg_x, w_rk, b_rk, rk, 1024, 256, 2048);
  gemm_k<3><<<dim3(4, 64),  blk, 0, stream>>>(reg_x, w_rv, b_rv, rv, 1024, 256, 2048);

  // phase 1: summarize (MFMA flash)
  mattn_k<1><<<dim3(B_ * H_), blk, 0, stream>>>(sq, sk, rk, sv, rv, sattn);

  // K2/V2 projections from sum_attn; summary output projection
  gemm_k<3><<<dim3(4, 2),  blk, 0, stream>>>(sattn, w_k2, b_k2, k2, 1024, 256, 64);
  gemm_k<3><<<dim3(4, 2),  blk, 0, stream>>>(sattn, w_v2, b_v2, v2, 1024, 256, 64);
  gemm_k<4><<<dim3(16, 2), blk, 0, stream>>>(sattn, w_so, b_so, out_sum, 1024, 1024, 64);

  // phase 2: updating (MFMA flash)
  mattn_k<2><<<dim3(B_ * H_ * 32), blk, 0, stream>>>(rq, k2, rk, v2, rv, rattn);

  // regular output projection
  gemm_k<4><<<dim3(16, 64), blk, 0, stream>>>(rattn, w_ro, b_ro, out_reg, 1024, 1024, 2048);
}

// Round 6
// 545.549 us; speedup vs baseline: 4.7489x; 1.9750x over previous
//
#include <hip/hip_runtime.h>

typedef unsigned short u16;
typedef __attribute__((ext_vector_type(8))) short s8v;   // 8 x bf16 MFMA A/B frag
typedef __attribute__((ext_vector_type(4))) float f4v;   // MFMA C/D frag

#define B_    2
#define S_    64
#define R_    2048
#define D_    1024
#define H_    16
#define KVH_  4
#define SCALE_ 0.125f
#define LOG2_10K 13.287712379549449f

__device__ __forceinline__ u16 f2bf(float f) {
  union { float f; unsigned int i; } v; v.f = f;
  unsigned int x = v.i;
  return (u16)((x + 0x7FFFu + ((x >> 16) & 1u)) >> 16);
}

// ---------------------------------------------------------------------------
// Prep: weight transpose+convert  W[K=1024][C] f32  ->  WT[C][1024] bf16
// ---------------------------------------------------------------------------
struct W6 { const float* w[6]; u16* o[6]; };

__global__ __launch_bounds__(256)
void transw_k(W6 ws, int C)
{
  __shared__ float t[32][33];
  const int c0 = blockIdx.x * 32, k0 = blockIdx.y * 32;
  const float* w = ws.w[blockIdx.z];
  u16* o = ws.o[blockIdx.z];
  const int x = threadIdx.x & 31, y = threadIdx.x >> 5;       // y: 0..7
  #pragma unroll
  for (int j = 0; j < 4; j++)
    t[y + 8 * j][x] = w[(size_t)(k0 + y + 8 * j) * C + c0 + x];
  __syncthreads();
  #pragma unroll
  for (int j = 0; j < 4; j++)
    o[(size_t)(c0 + y + 8 * j) * 1024 + k0 + x] = f2bf(t[x][y + 8 * j]);
}

// Prep: activation convert f32 -> bf16 (sum_x then reg_x, fused)
__global__ __launch_bounds__(256)
void convx_k(const float* __restrict__ xa, const float* __restrict__ xb,
             u16* __restrict__ oa, u16* __restrict__ ob)
{
  int i = (blockIdx.x * 256 + threadIdx.x) * 8;
  const float* src; u16* dst; int off;
  if (i < 131072) { src = xa; dst = oa; off = i; }
  else            { src = xb; dst = ob; off = i - 131072; }
  float4 a = *(const float4*)(src + off);
  float4 b = *(const float4*)(src + off + 4);
  s8v r;
  r[0] = (short)f2bf(a.x); r[1] = (short)f2bf(a.y);
  r[2] = (short)f2bf(a.z); r[3] = (short)f2bf(a.w);
  r[4] = (short)f2bf(b.x); r[5] = (short)f2bf(b.y);
  r[6] = (short)f2bf(b.z); r[7] = (short)f2bf(b.w);
  *(s8v*)(dst + off) = r;
}

// ---------------------------------------------------------------------------
// MFMA GEMM: Y = X@W + b.  X: [N][K] bf16, WT: [C][K] bf16, Bv: [C] f32.
// 128x128 tile, BK=64, 256 thr = 4 waves (2x2 of 64x64).
// mfma_f32_16x16x32_bf16 (verified r5): A frag = X[row l15][k l4*8+j],
// B frag = WT[col l15][k ...]; D: col=lane&15 (B-free), row=(lane>>4)*4+reg.
// EPI: 1 = RoPE-1D + head-split -> bf16 [b][h][pos][64]
//      2 = RoPE-2D (bar=pos>>5, tib=pos&31) + head-split -> bf16
//      3 = head-split -> bf16
//      4 = plain f32 [N][C] (final output)
// ---------------------------------------------------------------------------
template<int EPI>
__global__ __launch_bounds__(256)
void mgemm_k(const u16* __restrict__ X, const u16* __restrict__ WT,
             const float* __restrict__ Bv, void* __restrict__ outp,
             int K, int C, int LB)
{
  __shared__ u16 As[128][72];     // [row][k], 144B rows: 2-way bank alias max
  __shared__ u16 Bs[128][72];     // [col][k]

  const int tid  = threadIdx.x;
  const int lane = tid & 63;
  const int w    = tid >> 6;
  const int l15  = lane & 15;
  const int l4   = lane >> 4;
  const int wro  = (w >> 1) * 64;              // wave row offset in tile
  const int wco  = (w & 1) * 64;               // wave col offset in tile
  const int c0   = blockIdx.x * 128, r0 = blockIdx.y * 128;

  f4v acc[4][4];
  #pragma unroll
  for (int i = 0; i < 4; i++)
    #pragma unroll
    for (int j = 0; j < 4; j++) acc[i][j] = (f4v){0.f, 0.f, 0.f, 0.f};

  for (int k0 = 0; k0 < K; k0 += 64) {
    __syncthreads();
    #pragma unroll
    for (int it = 0; it < 4; it++) {
      int seg = tid + it * 256;
      int r = seg >> 3, sg = seg & 7;
      *(s8v*)&As[r][sg * 8] = *(const s8v*)(X  + (size_t)(r0 + r) * K + k0 + sg * 8);
      *(s8v*)&Bs[r][sg * 8] = *(const s8v*)(WT + (size_t)(c0 + r) * K + k0 + sg * 8);
    }
    __syncthreads();

    s8v af[4][2], bf[4][2];
    #pragma unroll
    for (int rc = 0; rc < 4; rc++) {
      af[rc][0] = *(const s8v*)&As[wro + rc * 16 + l15][l4 * 8];
      af[rc][1] = *(const s8v*)&As[wro + rc * 16 + l15][32 + l4 * 8];
    }
    #pragma unroll
    for (int cc = 0; cc < 4; cc++) {
      bf[cc][0] = *(const s8v*)&Bs[wco + cc * 16 + l15][l4 * 8];
      bf[cc][1] = *(const s8v*)&Bs[wco + cc * 16 + l15][32 + l4 * 8];
    }
    #pragma unroll
    for (int rc = 0; rc < 4; rc++)
      #pragma unroll
      for (int cc = 0; cc < 4; cc++) {
        acc[rc][cc] = __builtin_amdgcn_mfma_f32_16x16x32_bf16(af[rc][0], bf[cc][0], acc[rc][cc], 0, 0, 0);
        acc[rc][cc] = __builtin_amdgcn_mfma_f32_16x16x32_bf16(af[rc][1], bf[cc][1], acc[rc][cc], 0, 0, 0);
      }
  }

  // ---- epilogue ----
  float bv[4];
  #pragma unroll
  for (int cc = 0; cc < 4; cc++) bv[cc] = Bv[c0 + wco + cc * 16 + l15];

  if constexpr (EPI == 4) {
    float* out = (float*)outp;
    #pragma unroll
    for (int rc = 0; rc < 4; rc++)
      #pragma unroll
      for (int reg = 0; reg < 4; reg++) {
        int row = r0 + wro + rc * 16 + l4 * 4 + reg;
        #pragma unroll
        for (int cc = 0; cc < 4; cc++)
          out[(size_t)row * C + c0 + wco + cc * 16 + l15] = acc[rc][cc][reg] + bv[cc];
      }
  } else if constexpr (EPI == 3) {
    u16* out = (u16*)outp;
    const int NH = C >> 6;
    const int lbs = 31 - __clz(LB);
    #pragma unroll
    for (int rc = 0; rc < 4; rc++)
      #pragma unroll
      for (int reg = 0; reg < 4; reg++) {
        int row = r0 + wro + rc * 16 + l4 * 4 + reg;
        int b = row >> lbs, pos = row & (LB - 1);
        #pragma unroll
        for (int cc = 0; cc < 4; cc++) {
          int cg = c0 + wco + cc * 16 + l15;
          out[(((size_t)b * NH + (cg >> 6)) << lbs | pos) * 64 + (cg & 63)] =
              f2bf(acc[rc][cc][reg] + bv[cc]);
        }
      }
  } else {
    // RoPE: wave spans exactly one 64-wide head; partner col^32 = acc[rc][cc^2].
    u16* out = (u16*)outp;
    const int NH = C >> 6;
    const int hh = (c0 + wco) >> 6;
    const int lbs = 31 - __clz(LB);
    float inv_lo, inv_hi;
    if constexpr (EPI == 1) {
      inv_lo = exp2f(-(float)l15 * (LOG2_10K / 32.f));
      inv_hi = inv_lo * exp2f(-16.f * (LOG2_10K / 32.f));
    } else {
      inv_lo = exp2f(-(float)l15 * (LOG2_10K / 16.f));
      inv_hi = inv_lo;
    }
    #pragma unroll
    for (int rc = 0; rc < 4; rc++)
      #pragma unroll
      for (int reg = 0; reg < 4; reg++) {
        int row = r0 + wro + rc * 16 + l4 * 4 + reg;
        int b = row >> lbs, pos = row & (LB - 1);
        int bar = pos >> 5, tib = pos & 31;
        #pragma unroll
        for (int cc = 0; cc < 4; cc++) {
          int ch = cc * 16 + l15;                       // col within head
          float inv = (cc & 1) ? inv_hi : inv_lo;
          float base = (EPI == 1) ? (float)pos : (float)((cc & 1) ? tib : bar);
          float ang = base * inv;
          float sn, cs;
          sincosf(ang, &sn, &cs);
          float v0 = acc[rc][cc][reg] + bv[cc];
          float v1 = acc[rc][cc ^ 2][reg] + bv[cc ^ 2];
          float rot = (cc < 2) ? -v1 : v1;
          out[(((size_t)b * NH + hh) << lbs | pos) * 64 + ch] = f2bf(v0 * cs + rot * sn);
        }
      }
  }
}

// ---------------------------------------------------------------------------
// MFMA flash attention (all-bf16 I/O) over concat([summary(64), regular]) keys.
// Block = 256 thr = 4 waves; wave owns 16 q-rows; KV tiles of 64 keys.
// Scale folded post-QK^T. Key 0 valid for every query => masked exp()==0 safe.
// ---------------------------------------------------------------------------
template<int PHASE>
__global__ __launch_bounds__(256)
void mattn_k(const u16* __restrict__ Q, const u16* __restrict__ KS,
             const u16* __restrict__ KR, const u16* __restrict__ VS,
             const u16* __restrict__ VR, u16* __restrict__ Out)
{
  const int LQ  = (PHASE == 1) ? S_ : R_;
  const int NQB = LQ / 64;
  const int gid = blockIdx.x;
  const int qb  = gid % NQB;
  const int h   = (gid / NQB) % H_;
  const int b   = gid / (NQB * H_);
  const int q0  = qb * 64;
  const int kh  = h >> 2;                      // GQA repeat_interleave(4)

  __shared__ u16 Kt[64][72];                   // K tile,   [key][d]
  __shared__ u16 Vt[64][72];                   // V tile^T, [d][key]
  __shared__ u16 Pt[4][16][72];                // per-wave P, [q][key]

  const int tid  = threadIdx.x;
  const int lane = tid & 63;
  const int w    = tid >> 6;
  const int l15  = lane & 15;
  const int l4   = lane >> 4;
  const int qw   = q0 + w * 16;

  const u16* qp = Q + (((size_t)b * H_ + h) * LQ + qw + l15) * 64;
  s8v qf0 = *(const s8v*)(qp + l4 * 8);
  s8v qf1 = *(const s8v*)(qp + 32 + l4 * 8);

  f4v acc[4];
  #pragma unroll
  for (int dt = 0; dt < 4; dt++) acc[dt] = (f4v){0.f, 0.f, 0.f, 0.f};
  float m[4]    = {-1e30f, -1e30f, -1e30f, -1e30f};
  float lsum[4] = {0.f, 0.f, 0.f, 0.f};

  const int kend   = (PHASE == 1) ? (64 + R_) : (64 + q0 + 64);
  const int ntiles = kend >> 6;
  const size_t bh_kv = (size_t)b * KVH_ + kh;

  for (int kt = 0; kt < ntiles; kt++) {
    const int kbase = kt * 64;
    __syncthreads();                            // prev-tile LDS reads done

    const u16* kfsrc = (kbase == 0) ? (KS + bh_kv * 64 * 64)
                                    : (KR + (bh_kv * R_ + (kbase - 64)) * 64);
    #pragma unroll
    for (int it = 0; it < 2; it++) {
      int idx = tid + it * 256;
      int k = idx >> 3, sg = idx & 7;
      *(s8v*)&Kt[k][sg * 8] = *(const s8v*)(kfsrc + k * 64 + sg * 8);
    }
    const u16* vfsrc = (kbase == 0) ? (VS + bh_kv * 64 * 64)
                                    : (VR + (bh_kv * R_ + (kbase - 64)) * 64);
    {
      int d = tid & 63, kq = tid >> 6;
      unsigned int* dst = (unsigned int*)&Vt[d][kq * 16];
      #pragma unroll
      for (int j = 0; j < 8; j++) {
        unsigned lo = vfsrc[(kq * 16 + 2 * j) * 64 + d];
        unsigned hi = vfsrc[(kq * 16 + 2 * j + 1) * 64 + d];
        dst[j] = lo | (hi << 16);
      }
    }
    __syncthreads();

    // ---- QK^T ----
    f4v s[4];
    #pragma unroll
    for (int n = 0; n < 4; n++) {
      s8v kf0 = *(const s8v*)&Kt[n * 16 + l15][l4 * 8];
      s8v kf1 = *(const s8v*)&Kt[n * 16 + l15][32 + l4 * 8];
      f4v t = {0.f, 0.f, 0.f, 0.f};
      t = __builtin_amdgcn_mfma_f32_16x16x32_bf16(qf0, kf0, t, 0, 0, 0);
      t = __builtin_amdgcn_mfma_f32_16x16x32_bf16(qf1, kf1, t, 0, 0, 0);
      s[n] = t;
    }

    // ---- scale + mask + row-max ----
    float rmax[4] = {-1e30f, -1e30f, -1e30f, -1e30f};
    #pragma unroll
    for (int n = 0; n < 4; n++) {
      int kidx = kbase + n * 16 + l15;
      #pragma unroll
      for (int r = 0; r < 4; r++) {
        int qrow = qw + l4 * 4 + r;
        bool ok;
        if (kbase == 0) ok = kidx <= ((PHASE == 1) ? qrow : (qrow >> 5));
        else { int kr = kidx - 64; ok = (PHASE == 1) ? ((kr >> 5) <= qrow) : (kr <= qrow); }
        float sv = ok ? s[n][r] * SCALE_ : -1e30f;
        s[n][r] = sv;
        rmax[r] = fmaxf(rmax[r], sv);
      }
    }
    float fac[4];
    #pragma unroll
    for (int r = 0; r < 4; r++) {
      float v = rmax[r];
      v = fmaxf(v, __shfl_xor(v, 1));
      v = fmaxf(v, __shfl_xor(v, 2));
      v = fmaxf(v, __shfl_xor(v, 4));
      v = fmaxf(v, __shfl_xor(v, 8));
      float mn = fmaxf(m[r], v);
      fac[r] = __expf(m[r] - mn);
      m[r] = mn;
    }
    float rsum[4] = {0.f, 0.f, 0.f, 0.f};
    #pragma unroll
    for (int n = 0; n < 4; n++) {
      #pragma unroll
      for (int r = 0; r < 4; r++) {
        float p = __expf(s[n][r] - m[r]);
        Pt[w][l4 * 4 + r][n * 16 + l15] = f2bf(p);
        rsum[r] += p;
      }
    }
    #pragma unroll
    for (int r = 0; r < 4; r++) {
      float v = rsum[r];
      v += __shfl_xor(v, 1); v += __shfl_xor(v, 2);
      v += __shfl_xor(v, 4); v += __shfl_xor(v, 8);
      lsum[r] = lsum[r] * fac[r] + v;
      #pragma unroll
      for (int dt = 0; dt < 4; dt++) acc[dt][r] *= fac[r];
    }

    asm volatile("s_waitcnt lgkmcnt(0)" ::: "memory");   // P write->read, same wave

    // ---- PV ----
    s8v pf0 = *(const s8v*)&Pt[w][l15][l4 * 8];
    s8v pf1 = *(const s8v*)&Pt[w][l15][32 + l4 * 8];
    #pragma unroll
    for (int dt = 0; dt < 4; dt++) {
      s8v vf0 = *(const s8v*)&Vt[dt * 16 + l15][l4 * 8];
      s8v vf1 = *(const s8v*)&Vt[dt * 16 + l15][32 + l4 * 8];
      acc[dt] = __builtin_amdgcn_mfma_f32_16x16x32_bf16(pf0, vf0, acc[dt], 0, 0, 0);
      acc[dt] = __builtin_amdgcn_mfma_f32_16x16x32_bf16(pf1, vf1, acc[dt], 0, 0, 0);
    }
  }

  #pragma unroll
  for (int r = 0; r < 4; r++) {
    float linv = 1.f / lsum[r];
    int qrow = qw + l4 * 4 + r;
    u16* o = Out + ((size_t)b * LQ + qrow) * D_ + h * 64 + l15;
    #pragma unroll
    for (int dt = 0; dt < 4; dt++) o[dt * 16] = f2bf(acc[dt][r] * linv);
  }
}

extern "C" void kernel_launch(void* const* d_in, const int* in_sizes, int n_in,
                              void* d_out, int out_size, void* d_ws, size_t ws_size,
                              hipStream_t stream)
{
  (void)out_size; (void)ws_size;

  static const int expect[22] = {
    131072, 4194304,
    1048576, 1024, 262144, 256,
    262144, 256, 1048576, 1024,
    1048576, 1024, 262144, 256,
    262144, 256, 1048576, 1024,
    262144, 256, 262144, 256
  };
  if (n_in < 22) return;
  for (int i = 0; i < 22; i++) if (in_sizes[i] != expect[i]) return;

  const float* sum_x = (const float*)d_in[0];
  const float* reg_x = (const float*)d_in[1];
  const float* w_sq = (const float*)d_in[2];  const float* b_sq = (const float*)d_in[3];
  const float* w_sk = (const float*)d_in[4];  const float* b_sk = (const float*)d_in[5];
  const float* w_sv = (const float*)d_in[6];  const float* b_sv = (const float*)d_in[7];
  const float* w_so = (const float*)d_in[8];  const float* b_so = (const float*)d_in[9];
  const float* w_rq = (const float*)d_in[10]; const float* b_rq = (const float*)d_in[11];
  const float* w_rk = (const float*)d_in[12]; const float* b_rk = (const float*)d_in[13];
  const float* w_rv = (const float*)d_in[14]; const float* b_rv = (const float*)d_in[15];
  const float* w_ro = (const float*)d_in[16]; const float* b_ro = (const float*)d_in[17];
  const float* w_k2 = (const float*)d_in[18]; const float* b_k2 = (const float*)d_in[19];
  const float* w_v2 = (const float*)d_in[20]; const float* b_v2 = (const float*)d_in[21];

  // bf16 workspace layout (u16 elements)
  u16* ws    = (u16*)d_ws;
  u16* xs_bf = ws;                    // 131072
  u16* xr_bf = xs_bf + 131072;        // 4194304
  u16* wt_sq = xr_bf + 4194304;       // 1048576
  u16* wt_so = wt_sq + 1048576;       // 1048576
  u16* wt_rq = wt_so + 1048576;       // 1048576
  u16* wt_ro = wt_rq + 1048576;       // 1048576
  u16* wt_sk = wt_ro + 1048576;       // 262144
  u16* wt_sv = wt_sk + 262144;
  u16* wt_rk = wt_sv + 262144;
  u16* wt_rv = wt_rk + 262144;
  u16* wt_k2 = wt_rv + 262144;
  u16* wt_v2 = wt_k2 + 262144;        // +262144
  u16* sq    = wt_v2 + 262144;        // 131072   [B][H][S][64]
  u16* sk    = sq    + 131072;        // 32768    [B][KVH][S][64]
  u16* sv    = sk    + 32768;         // 32768
  u16* rq    = sv    + 32768;         // 4194304  [B][H][R][64]
  u16* rk    = rq    + 4194304;       // 1048576  [B][KVH][R][64]
  u16* rv    = rk    + 1048576;       // 1048576
  u16* sattn = rv    + 1048576;       // 131072   [B*S][D]
  u16* k2    = sattn + 131072;        // 32768
  u16* v2    = k2    + 32768;         // 32768
  u16* rattn = v2    + 32768;         // 4194304  [B*R][D]

  float* out_sum = (float*)d_out;          // (B,S,D) fp32
  float* out_reg = out_sum + 131072;       // (B,R,D) fp32

  dim3 blk(256);

  // ---- prep: convert/transposes ----
  W6 big;
  big.w[0] = w_sq; big.o[0] = wt_sq;
  big.w[1] = w_so; big.o[1] = wt_so;
  big.w[2] = w_rq; big.o[2] = wt_rq;
  big.w[3] = w_ro; big.o[3] = wt_ro;
  big.w[4] = w_sq; big.o[4] = wt_sq;   // unused slots
  big.w[5] = w_sq; big.o[5] = wt_sq;
  W6 small;
  small.w[0] = w_sk; small.o[0] = wt_sk;
  small.w[1] = w_sv; small.o[1] = wt_sv;
  small.w[2] = w_rk; small.o[2] = wt_rk;
  small.w[3] = w_rv; small.o[3] = wt_rv;
  small.w[4] = w_k2; small.o[4] = wt_k2;
  small.w[5] = w_v2; small.o[5] = wt_v2;
  transw_k<<<dim3(32, 32, 4), blk, 0, stream>>>(big, 1024);
  transw_k<<<dim3(8, 32, 6),  blk, 0, stream>>>(small, 256);
  convx_k<<<dim3(2112), blk, 0, stream>>>(sum_x, reg_x, xs_bf, xr_bf);

  // ---- QKV projections (+RoPE fused) ----
  mgemm_k<1><<<dim3(8, 1),  blk, 0, stream>>>(xs_bf, wt_sq, b_sq, sq, 1024, 1024, 64);
  mgemm_k<1><<<dim3(2, 1),  blk, 0, stream>>>(xs_bf, wt_sk, b_sk, sk, 1024, 256, 64);
  mgemm_k<3><<<dim3(2, 1),  blk, 0, stream>>>(xs_bf, wt_sv, b_sv, sv, 1024, 256, 64);
  mgemm_k<2><<<dim3(8, 32), blk, 0, stream>>>(xr_bf, wt_rq, b_rq, rq, 1024, 1024, 2048);
  mgemm_k<2><<<dim3(2, 32), blk, 0, stream>>>(xr_bf, wt_rk, b_rk, rk, 1024, 256, 2048);
  mgemm_k<3><<<dim3(2, 32), blk, 0, stream>>>(xr_bf, wt_rv, b_rv, rv, 1024, 256, 2048);

  // ---- phase 1: summarize ----
  mattn_k<1><<<dim3(B_ * H_), blk, 0, stream>>>(sq, sk, rk, sv, rv, sattn);

  // ---- K2/V2 + summary out-projection ----
  mgemm_k<3><<<dim3(2, 1), blk, 0, stream>>>(sattn, wt_k2, b_k2, k2, 1024, 256, 64);
  mgemm_k<3><<<dim3(2, 1), blk, 0, stream>>>(sattn, wt_v2, b_v2, v2, 1024, 256, 64);
  mgemm_k<4><<<dim3(8, 1), blk, 0, stream>>>(sattn, wt_so, b_so, out_sum, 1024, 1024, 64);

  // ---- phase 2: updating ----
  mattn_k<2><<<dim3(B_ * H_ * 32), blk, 0, stream>>>(rq, k2, rk, v2, rv, rattn);

  // ---- regular out-projection ----
  mgemm_k<4><<<dim3(8, 32), blk, 0, stream>>>(rattn, wt_ro, b_ro, out_reg, 1024, 1024, 2048);
}

// Round 7
// 381.548 us; speedup vs baseline: 6.7901x; 1.4298x over previous
//
#include <hip/hip_runtime.h>

typedef unsigned short u16;
typedef __attribute__((ext_vector_type(8))) short s8v;   // 8 x bf16 MFMA A/B frag
typedef __attribute__((ext_vector_type(4))) float f4v;   // MFMA C/D frag

#define B_    2
#define S_    64
#define R_    2048
#define D_    1024
#define H_    16
#define KVH_  4
#define LOG2_10K 13.287712379549449f

__device__ __forceinline__ u16 f2bf(float f) {
  union { float f; unsigned int i; } v; v.f = f;
  unsigned int x = v.i;
  return (u16)((x + 0x7FFFu + ((x >> 16) & 1u)) >> 16);
}

// ---------------------------------------------------------------------------
// Prep: weight transpose+convert  W[K=1024][C] f32  ->  WT[C][1024] bf16
// ---------------------------------------------------------------------------
struct W6 { const float* w[6]; u16* o[6]; };

__global__ __launch_bounds__(256)
void transw_k(W6 ws, int C)
{
  __shared__ float t[32][33];
  const int c0 = blockIdx.x * 32, k0 = blockIdx.y * 32;
  const float* w = ws.w[blockIdx.z];
  u16* o = ws.o[blockIdx.z];
  const int x = threadIdx.x & 31, y = threadIdx.x >> 5;       // y: 0..7
  #pragma unroll
  for (int j = 0; j < 4; j++)
    t[y + 8 * j][x] = w[(size_t)(k0 + y + 8 * j) * C + c0 + x];
  __syncthreads();
  #pragma unroll
  for (int j = 0; j < 4; j++)
    o[(size_t)(c0 + y + 8 * j) * 1024 + k0 + x] = f2bf(t[x][y + 8 * j]);
}

// Prep: activation convert f32 -> bf16 (sum_x then reg_x, fused)
__global__ __launch_bounds__(256)
void convx_k(const float* __restrict__ xa, const float* __restrict__ xb,
             u16* __restrict__ oa, u16* __restrict__ ob)
{
  int i = (blockIdx.x * 256 + threadIdx.x) * 8;
  const float* src; u16* dst; int off;
  if (i < 131072) { src = xa; dst = oa; off = i; }
  else            { src = xb; dst = ob; off = i - 131072; }
  float4 a = *(const float4*)(src + off);
  float4 b = *(const float4*)(src + off + 4);
  s8v r;
  r[0] = (short)f2bf(a.x); r[1] = (short)f2bf(a.y);
  r[2] = (short)f2bf(a.z); r[3] = (short)f2bf(a.w);
  r[4] = (short)f2bf(b.x); r[5] = (short)f2bf(b.y);
  r[6] = (short)f2bf(b.z); r[7] = (short)f2bf(b.w);
  *(s8v*)(dst + off) = r;
}

// Prep: V transpose  [bh][LB][64] bf16 -> [bh][64][LB] bf16
struct VJ { const u16* in; u16* out; int lb; };

__global__ __launch_bounds__(256)
void vtrans_k(VJ j0, VJ j1)
{
  VJ j = (blockIdx.z == 0) ? j0 : j1;
  const int p0 = blockIdx.x * 64;
  if (p0 >= j.lb) return;
  __shared__ u16 T[64][72];
  const int tid = threadIdx.x;
  const int bh = blockIdx.y;
  #pragma unroll
  for (int it = 0; it < 2; it++) {
    int idx = tid + it * 256;
    int p = idx >> 3, c = (idx & 7) * 8;
    *(s8v*)&T[p][c] = *(const s8v*)(j.in + ((size_t)bh * j.lb + p0 + p) * 64 + c);
  }
  __syncthreads();
  #pragma unroll
  for (int it = 0; it < 2; it++) {
    int idx = tid + it * 256;
    int d = idx >> 3, pc = (idx & 7) * 8;
    u16 tmp[8];
    #pragma unroll
    for (int q = 0; q < 8; q++) tmp[q] = T[pc + q][d];
    *(s8v*)(j.out + ((size_t)bh * 64 + d) * j.lb + p0 + pc) = *(s8v*)tmp;
  }
}

// ---------------------------------------------------------------------------
// Epilogue store helpers. acc D-frag: col = l15 (B-free), row = l4*4+reg.
// KIND: 0 = head-split bf16 [b][NH][LB][64]
//       1 = RoPE-1D + head-split bf16        (SC: *0.125 after rope)
//       2 = RoPE-2D + head-split bf16
//       3 = fp32 row-major [N][1024]
// ---------------------------------------------------------------------------
template<int KIND, bool SC>
__device__ __forceinline__ void epi_store(
    const f4v (&acc)[4][4], const float* __restrict__ Bp, void* __restrict__ outp,
    int cb, int row0, int NH, int LB, int LBS, int l15, int l4)
{
  float bv[4];
  #pragma unroll
  for (int cc = 0; cc < 4; cc++) bv[cc] = Bp[cb + cc * 16 + l15];

  if constexpr (KIND == 3) {
    float* out = (float*)outp;
    #pragma unroll
    for (int rc = 0; rc < 4; rc++)
      #pragma unroll
      for (int reg = 0; reg < 4; reg++) {
        int row = row0 + rc * 16 + l4 * 4 + reg;
        #pragma unroll
        for (int cc = 0; cc < 4; cc++)
          out[(size_t)row * 1024 + cb + cc * 16 + l15] = acc[rc][cc][reg] + bv[cc];
      }
  } else if constexpr (KIND == 0) {
    u16* out = (u16*)outp;
    const int hh = cb >> 6;
    #pragma unroll
    for (int rc = 0; rc < 4; rc++)
      #pragma unroll
      for (int reg = 0; reg < 4; reg++) {
        int row = row0 + rc * 16 + l4 * 4 + reg;
        int b = row >> LBS, pos = row & (LB - 1);
        size_t base = (((size_t)b * NH + hh) * LB + pos) * 64;
        #pragma unroll
        for (int cc = 0; cc < 4; cc++)
          out[base + cc * 16 + l15] = f2bf(acc[rc][cc][reg] + bv[cc]);
      }
  } else {
    u16* out = (u16*)outp;
    const int hh = cb >> 6;
    float inv_lo, inv_hi;
    if constexpr (KIND == 1) {
      inv_lo = exp2f(-(float)l15 * (LOG2_10K / 32.f));
      inv_hi = inv_lo * exp2f(-16.f * (LOG2_10K / 32.f));
    } else {
      inv_lo = exp2f(-(float)l15 * (LOG2_10K / 16.f));
      inv_hi = inv_lo;
    }
    #pragma unroll
    for (int rc = 0; rc < 4; rc++)
      #pragma unroll
      for (int reg = 0; reg < 4; reg++) {
        int row = row0 + rc * 16 + l4 * 4 + reg;
        int b = row >> LBS, pos = row & (LB - 1);
        int bar = pos >> 5, tib = pos & 31;
        size_t base = (((size_t)b * NH + hh) * LB + pos) * 64;
        #pragma unroll
        for (int cc = 0; cc < 4; cc++) {
          float inv = (cc & 1) ? inv_hi : inv_lo;
          float bse = (KIND == 1) ? (float)pos : (float)((cc & 1) ? tib : bar);
          float ang = bse * inv;
          float sn, cs;
          sincosf(ang, &sn, &cs);
          float v0 = acc[rc][cc][reg] + bv[cc];
          float v1 = acc[rc][cc ^ 2][reg] + bv[cc ^ 2];
          float rot = (cc < 2) ? -v1 : v1;
          float val = v0 * cs + rot * sn;
          if constexpr (SC) val *= 0.125f;   // attention scale folded into Q
          out[base + cc * 16 + l15] = f2bf(val);
        }
      }
  }
}

// ---------------------------------------------------------------------------
// Fused MFMA GEMM over concatenated weights. X:[N][1024] bf16, WT:[C][1024].
// 128x128 tile, BK=64, 4 waves (2x2 of 64x64).
// SIDE 0: sum-QKV  C=1536, ranges {q:ROPE1D*0.125, k:ROPE1D, v:HS},  LB=64
// SIDE 1: reg-QKV  C=1536, ranges {q:ROPE2D*0.125, k:ROPE2D, v:HS},  LB=2048
// SIDE 2: p1-out   C=1536, ranges {k2:HS, v2:HS, so:F32},            LB=64
// SIDE 3: ro       C=1024, all F32
// ---------------------------------------------------------------------------
template<int SIDE>
__global__ __launch_bounds__(256)
void mgemm_f(const u16* __restrict__ X, const u16* __restrict__ WT,
             const float* __restrict__ B0, const float* __restrict__ B1,
             const float* __restrict__ B2,
             void* __restrict__ O0, void* __restrict__ O1, void* __restrict__ O2)
{
  constexpr int RB1 = (SIDE == 2) ? 256 : 1024;
  constexpr int RB2 = (SIDE == 2) ? 512 : 1280;
  constexpr int LB  = (SIDE == 1) ? 2048 : 64;
  constexpr int LBS = (SIDE == 1) ? 11 : 6;

  __shared__ u16 As[128][72];
  __shared__ u16 Bs[128][72];

  const int tid  = threadIdx.x;
  const int lane = tid & 63;
  const int w    = tid >> 6;
  const int l15  = lane & 15;
  const int l4   = lane >> 4;
  const int wro  = (w >> 1) * 64;
  const int wco  = (w & 1) * 64;
  const int c0   = blockIdx.x * 128, r0 = blockIdx.y * 128;

  f4v acc[4][4];
  #pragma unroll
  for (int i = 0; i < 4; i++)
    #pragma unroll
    for (int j = 0; j < 4; j++) acc[i][j] = (f4v){0.f, 0.f, 0.f, 0.f};

  for (int k0 = 0; k0 < 1024; k0 += 64) {
    __syncthreads();
    #pragma unroll
    for (int it = 0; it < 4; it++) {
      int seg = tid + it * 256;
      int r = seg >> 3, sg = seg & 7;
      *(s8v*)&As[r][sg * 8] = *(const s8v*)(X  + (size_t)(r0 + r) * 1024 + k0 + sg * 8);
      *(s8v*)&Bs[r][sg * 8] = *(const s8v*)(WT + (size_t)(c0 + r) * 1024 + k0 + sg * 8);
    }
    __syncthreads();

    s8v af[4][2], bf[4][2];
    #pragma unroll
    for (int rc = 0; rc < 4; rc++) {
      af[rc][0] = *(const s8v*)&As[wro + rc * 16 + l15][l4 * 8];
      af[rc][1] = *(const s8v*)&As[wro + rc * 16 + l15][32 + l4 * 8];
    }
    #pragma unroll
    for (int cc = 0; cc < 4; cc++) {
      bf[cc][0] = *(const s8v*)&Bs[wco + cc * 16 + l15][l4 * 8];
      bf[cc][1] = *(const s8v*)&Bs[wco + cc * 16 + l15][32 + l4 * 8];
    }
    #pragma unroll
    for (int rc = 0; rc < 4; rc++)
      #pragma unroll
      for (int cc = 0; cc < 4; cc++) {
        acc[rc][cc] = __builtin_amdgcn_mfma_f32_16x16x32_bf16(af[rc][0], bf[cc][0], acc[rc][cc], 0, 0, 0);
        acc[rc][cc] = __builtin_amdgcn_mfma_f32_16x16x32_bf16(af[rc][1], bf[cc][1], acc[rc][cc], 0, 0, 0);
      }
  }

  const int row0 = r0 + wro;
  const int cgw  = c0 + wco;

  if constexpr (SIDE == 3) {
    epi_store<3, false>(acc, B0, O0, cgw, row0, 16, 64, 6, l15, l4);
  } else if constexpr (SIDE == 2) {
    if (cgw < RB1)      epi_store<0, false>(acc, B0, O0, cgw,       row0, 4,  LB, LBS, l15, l4);
    else if (cgw < RB2) epi_store<0, false>(acc, B1, O1, cgw - RB1, row0, 4,  LB, LBS, l15, l4);
    else                epi_store<3, false>(acc, B2, O2, cgw - RB2, row0, 16, LB, LBS, l15, l4);
  } else {
    constexpr int RK = (SIDE == 0) ? 1 : 2;
    if (cgw < RB1)      epi_store<RK, true >(acc, B0, O0, cgw,       row0, 16, LB, LBS, l15, l4);
    else if (cgw < RB2) epi_store<RK, false>(acc, B1, O1, cgw - RB1, row0, 4,  LB, LBS, l15, l4);
    else                epi_store<0,  false>(acc, B2, O2, cgw - RB2, row0, 4,  LB, LBS, l15, l4);
  }
}

// ---------------------------------------------------------------------------
// MFMA flash attention, bf16 I/O, pre-scaled Q, pre-transposed V.
// PHASE 1: 4 waves, 64 q/block;  PHASE 2: 8 waves, 128 q/block.
// Keys = concat([summary(64), regular(2048)]). Key 0 valid for every query.
// Mask fast-path: only boundary tiles mask; fully-invalid tiles skipped
// per-wave (barrier-safe); rescale skipped exactly when tile max <= m.
// ---------------------------------------------------------------------------
template<int PHASE>
__global__ __launch_bounds__(PHASE == 1 ? 256 : 512)
void mattn_k(const u16* __restrict__ Q, const u16* __restrict__ KS,
             const u16* __restrict__ KR, const u16* __restrict__ VST,
             const u16* __restrict__ VRT, u16* __restrict__ Out)
{
  constexpr int NW = (PHASE == 1) ? 4 : 8;
  constexpr int NT = NW * 64;
  constexpr int QB = NW * 16;
  const int LQ  = (PHASE == 1) ? S_ : R_;
  const int NQB = LQ / QB;
  const int gid = blockIdx.x;
  const int qb  = gid % NQB;
  const int h   = (gid / NQB) % H_;
  const int b   = gid / (NQB * H_);
  const int q0  = qb * QB;
  const int kh  = h >> 2;                      // GQA repeat_interleave(4)

  __shared__ u16 Kt[64][72];                   // K tile   [key][d]
  __shared__ u16 Vt[64][72];                   // V^T tile [d][key]
  __shared__ u16 Pt[NW][16][72];               // per-wave P [q][key]

  const int tid  = threadIdx.x;
  const int lane = tid & 63;
  const int w    = tid >> 6;
  const int l15  = lane & 15;
  const int l4   = lane >> 4;
  const int qw   = q0 + w * 16;

  const u16* qp = Q + (((size_t)b * H_ + h) * LQ + qw + l15) * 64;
  s8v qf0 = *(const s8v*)(qp + l4 * 8);
  s8v qf1 = *(const s8v*)(qp + 32 + l4 * 8);

  f4v acc[4];
  #pragma unroll
  for (int dt = 0; dt < 4; dt++) acc[dt] = (f4v){0.f, 0.f, 0.f, 0.f};
  float m[4]    = {-1e30f, -1e30f, -1e30f, -1e30f};
  float lsum[4] = {0.f, 0.f, 0.f, 0.f};

  const int kend   = (PHASE == 1) ? (64 + R_) : (64 + q0 + QB);
  const int ntiles = kend >> 6;
  const size_t bh_kv = (size_t)b * KVH_ + kh;

  for (int kt = 0; kt < ntiles; kt++) {
    const int kbase = kt * 64;
    __syncthreads();                           // prev-tile LDS reads done

    // ---- stage K [key][d] and V^T [d][key], b128 loads both sides ----
    const u16* kfsrc = (kbase == 0) ? (KS + bh_kv * 64 * 64)
                                    : (KR + (bh_kv * R_ + (kbase - 64)) * 64);
    const u16* vtsrc;
    int vstride;
    if (kbase == 0) { vtsrc = VST + bh_kv * 64 * 64;                 vstride = 64; }
    else            { vtsrc = VRT + bh_kv * 64 * R_ + (kbase - 64);  vstride = R_; }
    #pragma unroll
    for (int it = 0; it < 4096 / (8 * NT); it++) {
      int idx = tid + it * NT;
      int r = idx >> 3, sg = (idx & 7) * 8;
      *(s8v*)&Kt[r][sg] = *(const s8v*)(kfsrc + r * 64 + sg);
      *(s8v*)&Vt[r][sg] = *(const s8v*)(vtsrc + (size_t)r * vstride + sg);
    }
    __syncthreads();

    // per-wave: skip fully-invalid tiles (barriers already passed)
    bool active = (kbase == 0) ||
      (PHASE == 1 ? (((kbase - 64) >> 5) <= qw + 15) : ((kbase - 64) <= qw + 15));
    if (!active) continue;

    // ---- QK^T ----
    f4v s[4];
    #pragma unroll
    for (int n = 0; n < 4; n++) {
      s8v kf0 = *(const s8v*)&Kt[n * 16 + l15][l4 * 8];
      s8v kf1 = *(const s8v*)&Kt[n * 16 + l15][32 + l4 * 8];
      f4v t = {0.f, 0.f, 0.f, 0.f};
      t = __builtin_amdgcn_mfma_f32_16x16x32_bf16(qf0, kf0, t, 0, 0, 0);
      t = __builtin_amdgcn_mfma_f32_16x16x32_bf16(qf1, kf1, t, 0, 0, 0);
      s[n] = t;
    }

    // ---- mask (boundary tiles only) + row-max ----
    bool need_mask = (kbase == 0) ||
      (PHASE == 1 ? (((kbase - 1) >> 5) > qw) : ((kbase - 1) > qw));
    float v4[4] = {-1e30f, -1e30f, -1e30f, -1e30f};
    if (need_mask) {
      #pragma unroll
      for (int n = 0; n < 4; n++) {
        int kidx = kbase + n * 16 + l15;
        #pragma unroll
        for (int r = 0; r < 4; r++) {
          int qrow = qw + l4 * 4 + r;
          bool ok;
          if (kbase == 0) ok = kidx <= ((PHASE == 1) ? qrow : (qrow >> 5));
          else { int kr = kidx - 64; ok = (PHASE == 1) ? ((kr >> 5) <= qrow) : (kr <= qrow); }
          float sv = ok ? s[n][r] : -1e30f;
          s[n][r] = sv;
          v4[r] = fmaxf(v4[r], sv);
        }
      }
    } else {
      #pragma unroll
      for (int n = 0; n < 4; n++)
        #pragma unroll
        for (int r = 0; r < 4; r++) v4[r] = fmaxf(v4[r], s[n][r]);
    }
    #pragma unroll
    for (int r = 0; r < 4; r++) {
      float v = v4[r];
      v = fmaxf(v, __shfl_xor(v, 1));
      v = fmaxf(v, __shfl_xor(v, 2));
      v = fmaxf(v, __shfl_xor(v, 4));
      v = fmaxf(v, __shfl_xor(v, 8));
      v4[r] = v;
    }
    // exact rescale-skip: if tile max <= m for all rows, fac == 1
    bool up = (v4[0] > m[0]) || (v4[1] > m[1]) || (v4[2] > m[2]) || (v4[3] > m[3]);
    if (__any(up)) {
      #pragma unroll
      for (int r = 0; r < 4; r++) {
        float mn = fmaxf(m[r], v4[r]);
        float f  = __expf(m[r] - mn);
        m[r] = mn;
        lsum[r] *= f;
        #pragma unroll
        for (int dt = 0; dt < 4; dt++) acc[dt][r] *= f;
      }
    }
    float rs[4] = {0.f, 0.f, 0.f, 0.f};
    #pragma unroll
    for (int n = 0; n < 4; n++) {
      #pragma unroll
      for (int r = 0; r < 4; r++) {
        float p = __expf(s[n][r] - m[r]);      // masked: exp(-1e30-m) == 0
        Pt[w][l4 * 4 + r][n * 16 + l15] = f2bf(p);
        rs[r] += p;
      }
    }
    #pragma unroll
    for (int r = 0; r < 4; r++) {
      float v = rs[r];
      v += __shfl_xor(v, 1); v += __shfl_xor(v, 2);
      v += __shfl_xor(v, 4); v += __shfl_xor(v, 8);
      lsum[r] += v;
    }

    asm volatile("s_waitcnt lgkmcnt(0)" ::: "memory");   // P write->read, same wave

    // ---- PV ----
    s8v pf0 = *(const s8v*)&Pt[w][l15][l4 * 8];
    s8v pf1 = *(const s8v*)&Pt[w][l15][32 + l4 * 8];
    #pragma unroll
    for (int dt = 0; dt < 4; dt++) {
      s8v vf0 = *(const s8v*)&Vt[dt * 16 + l15][l4 * 8];
      s8v vf1 = *(const s8v*)&Vt[dt * 16 + l15][32 + l4 * 8];
      acc[dt] = __builtin_amdgcn_mfma_f32_16x16x32_bf16(pf0, vf0, acc[dt], 0, 0, 0);
      acc[dt] = __builtin_amdgcn_mfma_f32_16x16x32_bf16(pf1, vf1, acc[dt], 0, 0, 0);
    }
  }

  #pragma unroll
  for (int r = 0; r < 4; r++) {
    float linv = 1.f / lsum[r];
    int qrow = qw + l4 * 4 + r;
    u16* o = Out + ((size_t)b * LQ + qrow) * D_ + h * 64 + l15;
    #pragma unroll
    for (int dt = 0; dt < 4; dt++) o[dt * 16] = f2bf(acc[dt][r] * linv);
  }
}

extern "C" void kernel_launch(void* const* d_in, const int* in_sizes, int n_in,
                              void* d_out, int out_size, void* d_ws, size_t ws_size,
                              hipStream_t stream)
{
  (void)out_size; (void)ws_size;

  static const int expect[22] = {
    131072, 4194304,
    1048576, 1024, 262144, 256,
    262144, 256, 1048576, 1024,
    1048576, 1024, 262144, 256,
    262144, 256, 1048576, 1024,
    262144, 256, 262144, 256
  };
  if (n_in < 22) return;
  for (int i = 0; i < 22; i++) if (in_sizes[i] != expect[i]) return;

  const float* sum_x = (const float*)d_in[0];
  const float* reg_x = (const float*)d_in[1];
  const float* w_sq = (const float*)d_in[2];  const float* b_sq = (const float*)d_in[3];
  const float* w_sk = (const float*)d_in[4];  const float* b_sk = (const float*)d_in[5];
  const float* w_sv = (const float*)d_in[6];  const float* b_sv = (const float*)d_in[7];
  const float* w_so = (const float*)d_in[8];  const float* b_so = (const float*)d_in[9];
  const float* w_rq = (const float*)d_in[10]; const float* b_rq = (const float*)d_in[11];
  const float* w_rk = (const float*)d_in[12]; const float* b_rk = (const float*)d_in[13];
  const float* w_rv = (const float*)d_in[14]; const float* b_rv = (const float*)d_in[15];
  const float* w_ro = (const float*)d_in[16]; const float* b_ro = (const float*)d_in[17];
  const float* w_k2 = (const float*)d_in[18]; const float* b_k2 = (const float*)d_in[19];
  const float* w_v2 = (const float*)d_in[20]; const float* b_v2 = (const float*)d_in[21];

  // bf16 workspace layout (u16 elements)
  u16* ws    = (u16*)d_ws;
  u16* xs_bf = ws;                    // 131072
  u16* xr_bf = xs_bf + 131072;        // 4194304
  u16* wt_s  = xr_bf + 4194304;       // 1572864  [sq|sk|sv] cat (dead after QKV;
                                      //          then hosts rvT/svT/v2T)
  u16* wt_r  = wt_s  + 1572864;       // 1572864  [rq|rk|rv] cat
  u16* wt_p  = wt_r  + 1572864;       // 1572864  [k2|v2|so] cat
  u16* wt_ro = wt_p  + 1572864;       // 1048576
  u16* sq    = wt_ro + 1048576;       // 131072   [B][H][S][64]
  u16* sk    = sq    + 131072;        // 32768    [B][KVH][S][64]
  u16* sv    = sk    + 32768;         // 32768
  u16* rq    = sv    + 32768;         // 4194304  [B][H][R][64]
  u16* rk    = rq    + 4194304;       // 1048576  [B][KVH][R][64]
  u16* rv    = rk    + 1048576;       // 1048576
  u16* sattn = rv    + 1048576;       // 131072   [B*S][D]
  u16* k2    = sattn + 131072;        // 32768
  u16* v2    = k2    + 32768;         // 32768
  u16* rattn = v2    + 32768;         // 4194304  [B*R][D]

  // transposed-V aliases inside the dead wt_s region
  u16* rvT = wt_s;                    // 1048576  [B][KVH][64][R]
  u16* svT = wt_s + 1048576;          // 32768    [B][KVH][64][S]
  u16* v2T = wt_s + 1081344;          // 32768

  float* out_sum = (float*)d_out;          // (B,S,D) fp32
  float* out_reg = out_sum + 131072;       // (B,R,D) fp32

  dim3 blk(256);

  // ---- prep: weight transposes + activation convert ----
  W6 big;
  big.w[0] = w_sq; big.o[0] = wt_s;
  big.w[1] = w_rq; big.o[1] = wt_r;
  big.w[2] = w_so; big.o[2] = wt_p + 512 * 1024;
  big.w[3] = w_ro; big.o[3] = wt_ro;
  big.w[4] = w_sq; big.o[4] = wt_s;    // unused
  big.w[5] = w_sq; big.o[5] = wt_s;
  W6 small;
  small.w[0] = w_sk; small.o[0] = wt_s + 1024 * 1024;
  small.w[1] = w_sv; small.o[1] = wt_s + 1280 * 1024;
  small.w[2] = w_rk; small.o[2] = wt_r + 1024 * 1024;
  small.w[3] = w_rv; small.o[3] = wt_r + 1280 * 1024;
  small.w[4] = w_k2; small.o[4] = wt_p;
  small.w[5] = w_v2; small.o[5] = wt_p + 256 * 1024;
  transw_k<<<dim3(32, 32, 4), blk, 0, stream>>>(big, 1024);
  transw_k<<<dim3(8, 32, 6),  blk, 0, stream>>>(small, 256);
  convx_k<<<dim3(2112), blk, 0, stream>>>(sum_x, reg_x, xs_bf, xr_bf);

  // ---- fused QKV projections (+RoPE, +Q-scale) ----
  mgemm_f<0><<<dim3(12, 1),  blk, 0, stream>>>(xs_bf, wt_s, b_sq, b_sk, b_sv, sq, sk, sv);
  mgemm_f<1><<<dim3(12, 32), blk, 0, stream>>>(xr_bf, wt_r, b_rq, b_rk, b_rv, rq, rk, rv);

  // ---- V transposes (wt_s is dead now) ----
  VJ jrv = {rv, rvT, 2048};
  VJ jsv = {sv, svT, 64};
  vtrans_k<<<dim3(32, 8, 2), blk, 0, stream>>>(jrv, jsv);

  // ---- phase 1: summarize ----
  mattn_k<1><<<dim3(B_ * H_), dim3(256), 0, stream>>>(sq, sk, rk, svT, rvT, sattn);

  // ---- fused k2/v2/out_sum ----
  mgemm_f<2><<<dim3(12, 1), blk, 0, stream>>>(sattn, wt_p, b_k2, b_v2, b_so, k2, v2, out_sum);
  VJ jv2 = {v2, v2T, 64};
  vtrans_k<<<dim3(1, 8, 1), blk, 0, stream>>>(jv2, jv2);

  // ---- phase 2: updating ----
  mattn_k<2><<<dim3(B_ * H_ * 16), dim3(512), 0, stream>>>(rq, k2, rk, v2T, rvT, rattn);

  // ---- regular out-projection ----
  mgemm_f<3><<<dim3(8, 32), blk, 0, stream>>>(rattn, wt_ro, b_ro, nullptr, nullptr,
                                              out_reg, nullptr, nullptr);
}

// Round 9
// 296.551 us; speedup vs baseline: 8.7363x; 1.2866x over previous
//
#include <hip/hip_runtime.h>

typedef unsigned short u16;
typedef __attribute__((ext_vector_type(8))) short s8v;   // 8 x bf16 MFMA A/B frag
typedef __attribute__((ext_vector_type(4))) float f4v;   // MFMA C/D frag

#define B_    2
#define S_    64
#define R_    2048
#define D_    1024
#define H_    16
#define KVH_  4
#define LOG2_10K 13.287712379549449f

__device__ __forceinline__ u16 f2bf(float f) {
  union { float f; unsigned int i; } v; v.f = f;
  unsigned int x = v.i;
  return (u16)((x + 0x7FFFu + ((x >> 16) & 1u)) >> 16);
}

// ---------------------------------------------------------------------------
// Prep: weight transpose+convert  W[K=1024][C] f32  ->  WT[C][1024] bf16
// ---------------------------------------------------------------------------
struct W6 { const float* w[6]; u16* o[6]; };

__global__ __launch_bounds__(256)
void transw_k(W6 ws, int C)
{
  __shared__ float t[32][33];
  const int c0 = blockIdx.x * 32, k0 = blockIdx.y * 32;
  const float* w = ws.w[blockIdx.z];
  u16* o = ws.o[blockIdx.z];
  const int x = threadIdx.x & 31, y = threadIdx.x >> 5;       // y: 0..7
  #pragma unroll
  for (int j = 0; j < 4; j++)
    t[y + 8 * j][x] = w[(size_t)(k0 + y + 8 * j) * C + c0 + x];
  __syncthreads();
  #pragma unroll
  for (int j = 0; j < 4; j++)
    o[(size_t)(c0 + y + 8 * j) * 1024 + k0 + x] = f2bf(t[x][y + 8 * j]);
}

// Prep: activation convert f32 -> bf16 (sum_x then reg_x, fused)
__global__ __launch_bounds__(256)
void convx_k(const float* __restrict__ xa, const float* __restrict__ xb,
             u16* __restrict__ oa, u16* __restrict__ ob)
{
  int i = (blockIdx.x * 256 + threadIdx.x) * 8;
  const float* src; u16* dst; int off;
  if (i < 131072) { src = xa; dst = oa; off = i; }
  else            { src = xb; dst = ob; off = i - 131072; }
  float4 a = *(const float4*)(src + off);
  float4 b = *(const float4*)(src + off + 4);
  s8v r;
  r[0] = (short)f2bf(a.x); r[1] = (short)f2bf(a.y);
  r[2] = (short)f2bf(a.z); r[3] = (short)f2bf(a.w);
  r[4] = (short)f2bf(b.x); r[5] = (short)f2bf(b.y);
  r[6] = (short)f2bf(b.z); r[7] = (short)f2bf(b.w);
  *(s8v*)(dst + off) = r;
}

// Prep: V transpose  [bh][LB][64] bf16 -> [bh][64][LB] bf16
struct VJ { const u16* in; u16* out; int lb; };

__global__ __launch_bounds__(256)
void vtrans_k(VJ j0, VJ j1)
{
  VJ j = (blockIdx.z == 0) ? j0 : j1;
  const int p0 = blockIdx.x * 64;
  if (p0 >= j.lb) return;
  __shared__ u16 T[64][72];
  const int tid = threadIdx.x;
  const int bh = blockIdx.y;
  #pragma unroll
  for (int it = 0; it < 2; it++) {
    int idx = tid + it * 256;
    int p = idx >> 3, c = (idx & 7) * 8;
    *(s8v*)&T[p][c] = *(const s8v*)(j.in + ((size_t)bh * j.lb + p0 + p) * 64 + c);
  }
  __syncthreads();
  #pragma unroll
  for (int it = 0; it < 2; it++) {
    int idx = tid + it * 256;
    int d = idx >> 3, pc = (idx & 7) * 8;
    u16 tmp[8];
    #pragma unroll
    for (int q = 0; q < 8; q++) tmp[q] = T[pc + q][d];
    *(s8v*)(j.out + ((size_t)bh * 64 + d) * j.lb + p0 + pc) = *(s8v*)tmp;
  }
}

// ---------------------------------------------------------------------------
// Epilogue store helpers. acc D-frag: col = l15 (B-free), row = l4*4+reg.
// KIND: 0 = head-split bf16 [b][NH][LB][64]
//       1 = RoPE-1D + head-split bf16        (SC: *0.125 after rope)
//       2 = RoPE-2D + head-split bf16
//       3 = fp32 row-major [N][1024]
// ---------------------------------------------------------------------------
template<int KIND, bool SC>
__device__ __forceinline__ void epi_store(
    const f4v (&acc)[4][4], const float* __restrict__ Bp, void* __restrict__ outp,
    int cb, int row0, int NH, int LB, int LBS, int l15, int l4)
{
  float bv[4];
  #pragma unroll
  for (int cc = 0; cc < 4; cc++) bv[cc] = Bp[cb + cc * 16 + l15];

  if constexpr (KIND == 3) {
    float* out = (float*)outp;
    #pragma unroll
    for (int rc = 0; rc < 4; rc++)
      #pragma unroll
      for (int reg = 0; reg < 4; reg++) {
        int row = row0 + rc * 16 + l4 * 4 + reg;
        #pragma unroll
        for (int cc = 0; cc < 4; cc++)
          out[(size_t)row * 1024 + cb + cc * 16 + l15] = acc[rc][cc][reg] + bv[cc];
      }
  } else if constexpr (KIND == 0) {
    u16* out = (u16*)outp;
    const int hh = cb >> 6;
    #pragma unroll
    for (int rc = 0; rc < 4; rc++)
      #pragma unroll
      for (int reg = 0; reg < 4; reg++) {
        int row = row0 + rc * 16 + l4 * 4 + reg;
        int b = row >> LBS, pos = row & (LB - 1);
        size_t base = (((size_t)b * NH + hh) * LB + pos) * 64;
        #pragma unroll
        for (int cc = 0; cc < 4; cc++)
          out[base + cc * 16 + l15] = f2bf(acc[rc][cc][reg] + bv[cc]);
      }
  } else {
    u16* out = (u16*)outp;
    const int hh = cb >> 6;
    float inv_lo, inv_hi;
    if constexpr (KIND == 1) {
      inv_lo = exp2f(-(float)l15 * (LOG2_10K / 32.f));
      inv_hi = inv_lo * exp2f(-16.f * (LOG2_10K / 32.f));
    } else {
      inv_lo = exp2f(-(float)l15 * (LOG2_10K / 16.f));
      inv_hi = inv_lo;
    }
    #pragma unroll
    for (int rc = 0; rc < 4; rc++)
      #pragma unroll
      for (int reg = 0; reg < 4; reg++) {
        int row = row0 + rc * 16 + l4 * 4 + reg;
        int b = row >> LBS, pos = row & (LB - 1);
        int bar = pos >> 5, tib = pos & 31;
        size_t base = (((size_t)b * NH + hh) * LB + pos) * 64;
        #pragma unroll
        for (int cc = 0; cc < 4; cc++) {
          float inv = (cc & 1) ? inv_hi : inv_lo;
          float bse = (KIND == 1) ? (float)pos : (float)((cc & 1) ? tib : bar);
          float ang = bse * inv;
          float sn, cs;
          sincosf(ang, &sn, &cs);
          float v0 = acc[rc][cc][reg] + bv[cc];
          float v1 = acc[rc][cc ^ 2][reg] + bv[cc ^ 2];
          float rot = (cc < 2) ? -v1 : v1;
          float val = v0 * cs + rot * sn;
          if constexpr (SC) val *= 0.125f;   // attention scale folded into Q
          out[base + cc * 16 + l15] = f2bf(val);
        }
      }
  }
}

// ---------------------------------------------------------------------------
// Fused MFMA GEMM over concatenated weights (unchanged from round 7).
// ---------------------------------------------------------------------------
template<int SIDE>
__global__ __launch_bounds__(256)
void mgemm_f(const u16* __restrict__ X, const u16* __restrict__ WT,
             const float* __restrict__ B0, const float* __restrict__ B1,
             const float* __restrict__ B2,
             void* __restrict__ O0, void* __restrict__ O1, void* __restrict__ O2)
{
  constexpr int RB1 = (SIDE == 2) ? 256 : 1024;
  constexpr int RB2 = (SIDE == 2) ? 512 : 1280;
  constexpr int LB  = (SIDE == 1) ? 2048 : 64;
  constexpr int LBS = (SIDE == 1) ? 11 : 6;

  __shared__ u16 As[128][72];
  __shared__ u16 Bs[128][72];

  const int tid  = threadIdx.x;
  const int lane = tid & 63;
  const int w    = tid >> 6;
  const int l15  = lane & 15;
  const int l4   = lane >> 4;
  const int wro  = (w >> 1) * 64;
  const int wco  = (w & 1) * 64;
  const int c0   = blockIdx.x * 128, r0 = blockIdx.y * 128;

  f4v acc[4][4];
  #pragma unroll
  for (int i = 0; i < 4; i++)
    #pragma unroll
    for (int j = 0; j < 4; j++) acc[i][j] = (f4v){0.f, 0.f, 0.f, 0.f};

  for (int k0 = 0; k0 < 1024; k0 += 64) {
    __syncthreads();
    #pragma unroll
    for (int it = 0; it < 4; it++) {
      int seg = tid + it * 256;
      int r = seg >> 3, sg = seg & 7;
      *(s8v*)&As[r][sg * 8] = *(const s8v*)(X  + (size_t)(r0 + r) * 1024 + k0 + sg * 8);
      *(s8v*)&Bs[r][sg * 8] = *(const s8v*)(WT + (size_t)(c0 + r) * 1024 + k0 + sg * 8);
    }
    __syncthreads();

    s8v af[4][2], bf[4][2];
    #pragma unroll
    for (int rc = 0; rc < 4; rc++) {
      af[rc][0] = *(const s8v*)&As[wro + rc * 16 + l15][l4 * 8];
      af[rc][1] = *(const s8v*)&As[wro + rc * 16 + l15][32 + l4 * 8];
    }
    #pragma unroll
    for (int cc = 0; cc < 4; cc++) {
      bf[cc][0] = *(const s8v*)&Bs[wco + cc * 16 + l15][l4 * 8];
      bf[cc][1] = *(const s8v*)&Bs[wco + cc * 16 + l15][32 + l4 * 8];
    }
    #pragma unroll
    for (int rc = 0; rc < 4; rc++)
      #pragma unroll
      for (int cc = 0; cc < 4; cc++) {
        acc[rc][cc] = __builtin_amdgcn_mfma_f32_16x16x32_bf16(af[rc][0], bf[cc][0], acc[rc][cc], 0, 0, 0);
        acc[rc][cc] = __builtin_amdgcn_mfma_f32_16x16x32_bf16(af[rc][1], bf[cc][1], acc[rc][cc], 0, 0, 0);
      }
  }

  const int row0 = r0 + wro;
  const int cgw  = c0 + wco;

  if constexpr (SIDE == 3) {
    epi_store<3, false>(acc, B0, O0, cgw, row0, 16, 64, 6, l15, l4);
  } else if constexpr (SIDE == 2) {
    if (cgw < RB1)      epi_store<0, false>(acc, B0, O0, cgw,       row0, 4,  LB, LBS, l15, l4);
    else if (cgw < RB2) epi_store<0, false>(acc, B1, O1, cgw - RB1, row0, 4,  LB, LBS, l15, l4);
    else                epi_store<3, false>(acc, B2, O2, cgw - RB2, row0, 16, LB, LBS, l15, l4);
  } else {
    constexpr int RK = (SIDE == 0) ? 1 : 2;
    if (cgw < RB1)      epi_store<RK, true >(acc, B0, O0, cgw,       row0, 16, LB, LBS, l15, l4);
    else if (cgw < RB2) epi_store<RK, false>(acc, B1, O1, cgw - RB1, row0, 4,  LB, LBS, l15, l4);
    else                epi_store<0,  false>(acc, B2, O2, cgw - RB2, row0, 4,  LB, LBS, l15, l4);
  }
}

// ---------------------------------------------------------------------------
// Shared flash-attention tile compute (one wave, 16 q-rows, 64-key tile).
// Kc/Vc point at the CURRENT LDS buffers; Ptw at this wave's P buffer.
// ---------------------------------------------------------------------------
template<int PHASE>
__device__ __forceinline__ void attn_tile(
    const u16 (&Kc)[64][72], const u16 (&Vc)[64][72], u16 (&Ptw)[16][72],
    const s8v& qf0, const s8v& qf1, f4v (&acc)[4],
    float (&m)[4], float (&lsum)[4],
    int kbase, int qw, int l15, int l4)
{
  // ---- QK^T ----
  f4v s[4];
  #pragma unroll
  for (int n = 0; n < 4; n++) {
    s8v kf0 = *(const s8v*)&Kc[n * 16 + l15][l4 * 8];
    s8v kf1 = *(const s8v*)&Kc[n * 16 + l15][32 + l4 * 8];
    f4v t = {0.f, 0.f, 0.f, 0.f};
    t = __builtin_amdgcn_mfma_f32_16x16x32_bf16(qf0, kf0, t, 0, 0, 0);
    t = __builtin_amdgcn_mfma_f32_16x16x32_bf16(qf1, kf1, t, 0, 0, 0);
    s[n] = t;
  }

  // ---- mask (boundary tiles only) + row-max ----
  bool need_mask = (kbase == 0) ||
    (PHASE == 1 ? (((kbase - 1) >> 5) > qw) : ((kbase - 1) > qw));
  float v4[4] = {-1e30f, -1e30f, -1e30f, -1e30f};
  if (need_mask) {
    #pragma unroll
    for (int n = 0; n < 4; n++) {
      int kidx = kbase + n * 16 + l15;
      #pragma unroll
      for (int r = 0; r < 4; r++) {
        int qrow = qw + l4 * 4 + r;
        bool ok;
        if (kbase == 0) ok = kidx <= ((PHASE == 1) ? qrow : (qrow >> 5));
        else { int kr = kidx - 64; ok = (PHASE == 1) ? ((kr >> 5) <= qrow) : (kr <= qrow); }
        float sv = ok ? s[n][r] : -1e30f;
        s[n][r] = sv;
        v4[r] = fmaxf(v4[r], sv);
      }
    }
  } else {
    #pragma unroll
    for (int n = 0; n < 4; n++)
      #pragma unroll
      for (int r = 0; r < 4; r++) v4[r] = fmaxf(v4[r], s[n][r]);
  }
  #pragma unroll
  for (int r = 0; r < 4; r++) {
    float v = v4[r];
    v = fmaxf(v, __shfl_xor(v, 1));
    v = fmaxf(v, __shfl_xor(v, 2));
    v = fmaxf(v, __shfl_xor(v, 4));
    v = fmaxf(v, __shfl_xor(v, 8));
    v4[r] = v;
  }
  // exact rescale-skip: if tile max <= m for all rows, fac == 1
  bool up = (v4[0] > m[0]) || (v4[1] > m[1]) || (v4[2] > m[2]) || (v4[3] > m[3]);
  if (__any(up)) {
    #pragma unroll
    for (int r = 0; r < 4; r++) {
      float mn = fmaxf(m[r], v4[r]);
      float f  = __expf(m[r] - mn);
      m[r] = mn;
      lsum[r] *= f;
      #pragma unroll
      for (int dt = 0; dt < 4; dt++) acc[dt][r] *= f;
    }
  }
  float rs[4] = {0.f, 0.f, 0.f, 0.f};
  #pragma unroll
  for (int n = 0; n < 4; n++) {
    #pragma unroll
    for (int r = 0; r < 4; r++) {
      float p = __expf(s[n][r] - m[r]);        // masked: exp(-1e30-m) == 0
      Ptw[l4 * 4 + r][n * 16 + l15] = f2bf(p);
      rs[r] += p;
    }
  }
  #pragma unroll
  for (int r = 0; r < 4; r++) {
    float v = rs[r];
    v += __shfl_xor(v, 1); v += __shfl_xor(v, 2);
    v += __shfl_xor(v, 4); v += __shfl_xor(v, 8);
    lsum[r] += v;
  }

  asm volatile("s_waitcnt lgkmcnt(0)" ::: "memory");   // P write->read, same wave

  // ---- PV ----
  s8v pf0 = *(const s8v*)&Ptw[l15][l4 * 8];
  s8v pf1 = *(const s8v*)&Ptw[l15][32 + l4 * 8];
  #pragma unroll
  for (int dt = 0; dt < 4; dt++) {
    s8v vf0 = *(const s8v*)&Vc[dt * 16 + l15][l4 * 8];
    s8v vf1 = *(const s8v*)&Vc[dt * 16 + l15][32 + l4 * 8];
    acc[dt] = __builtin_amdgcn_mfma_f32_16x16x32_bf16(pf0, vf0, acc[dt], 0, 0, 0);
    acc[dt] = __builtin_amdgcn_mfma_f32_16x16x32_bf16(pf1, vf1, acc[dt], 0, 0, 0);
  }
}

// ---------------------------------------------------------------------------
// Phase 2 attention: 8 waves, 128 q/block, double-buffered K/V staging,
// one barrier per tile, complementary qb pairing for load balance.
// ---------------------------------------------------------------------------
__global__ __launch_bounds__(512)
void attn2_k(const u16* __restrict__ Q, const u16* __restrict__ KS,
             const u16* __restrict__ KR, const u16* __restrict__ VST,
             const u16* __restrict__ VRT, u16* __restrict__ Out)
{
  const int gid = blockIdx.x;
  const int qb  = (gid & 256) ? (15 - (gid & 15)) : (gid & 15);
  const int bh  = gid >> 4;                    // note: bh in 0..31 across both halves
  const int h   = bh & 15, b = bh >> 4;
  const int q0  = qb * 128;
  const int kh  = h >> 2;

  __shared__ u16 Kt[2][64][72];
  __shared__ u16 Vt[2][64][72];
  __shared__ u16 Pt[8][16][72];

  const int tid = threadIdx.x, lane = tid & 63, w = tid >> 6;
  const int l15 = lane & 15, l4 = lane >> 4;
  const int qw  = q0 + w * 16;

  const u16* qp = Q + (((size_t)b * H_ + h) * R_ + qw + l15) * 64;
  s8v qf0 = *(const s8v*)(qp + l4 * 8);
  s8v qf1 = *(const s8v*)(qp + 32 + l4 * 8);

  f4v acc[4];
  #pragma unroll
  for (int dt = 0; dt < 4; dt++) acc[dt] = (f4v){0.f, 0.f, 0.f, 0.f};
  float m[4]    = {-1e30f, -1e30f, -1e30f, -1e30f};
  float lsum[4] = {0.f, 0.f, 0.f, 0.f};

  const int ntiles = (64 + q0 + 128) >> 6;
  const size_t bh_kv = (size_t)b * KVH_ + kh;

  const int r_ = tid >> 3, sg_ = (tid & 7) * 8;

  // prologue: stage tile 0 (summary K / V^T)
  {
    const u16* kp = KS  + bh_kv * 4096;
    const u16* vp = VST + bh_kv * 4096;
    s8v k0 = *(const s8v*)(kp + r_ * 64 + sg_);
    s8v v0 = *(const s8v*)(vp + r_ * 64 + sg_);
    *(s8v*)&Kt[0][r_][sg_] = k0;
    *(s8v*)&Vt[0][r_][sg_] = v0;
  }
  __syncthreads();

  for (int kt = 0; kt < ntiles; kt++) {
    const int cur = kt & 1;
    const int kbase = kt * 64;
    const bool pre = (kt + 1 < ntiles);
    s8v knx, vnx;
    if (pre) {                                  // issue next-tile loads early
      const int nb = kbase;                     // next kbase-64 = kbase
      const u16* kp = KR  + (bh_kv * R_ + nb) * 64;
      const u16* vp = VRT + bh_kv * 64 * R_ + nb;
      knx = *(const s8v*)(kp + r_ * 64 + sg_);
      vnx = *(const s8v*)(vp + (size_t)r_ * R_ + sg_);
    }

    const bool active = (kbase == 0) || (kbase - 64 <= qw + 15);
    if (active)
      attn_tile<2>(Kt[cur], Vt[cur], Pt[w], qf0, qf1, acc, m, lsum,
                   kbase, qw, l15, l4);

    if (pre) {                                  // write-late into other buffer
      *(s8v*)&Kt[cur ^ 1][r_][sg_] = knx;
      *(s8v*)&Vt[cur ^ 1][r_][sg_] = vnx;
    }
    __syncthreads();
  }

  #pragma unroll
  for (int r = 0; r < 4; r++) {
    float linv = 1.f / lsum[r];
    int qrow = qw + l4 * 4 + r;
    u16* o = Out + ((size_t)b * R_ + qrow) * D_ + h * 64 + l15;
    #pragma unroll
    for (int dt = 0; dt < 4; dt++) o[dt * 16] = f2bf(acc[dt][r] * linv);
  }
}

// ---------------------------------------------------------------------------
// Phase 1 attention, split-K: 8 chunks x 32 (b,h); 4 waves, 64 q/block.
// Each chunk flashes tiles [kt0,kt1) and stores partial (O, m, l) fp32.
// ---------------------------------------------------------------------------
__global__ __launch_bounds__(256)
void attn1_k(const u16* __restrict__ Q, const u16* __restrict__ KS,
             const u16* __restrict__ KR, const u16* __restrict__ VST,
             const u16* __restrict__ VRT,
             float* __restrict__ pO, float* __restrict__ pml)
{
  const int gid = blockIdx.x;                  // 256
  const int ck  = gid & 7;
  const int bh  = gid >> 3;
  const int h   = bh & 15, b = bh >> 4;
  const int kh  = h >> 2;
  const int kt0 = (ck * 33) >> 3;              // 33 tiles total
  const int kt1 = ((ck + 1) * 33) >> 3;

  __shared__ u16 Kt[2][64][72];
  __shared__ u16 Vt[2][64][72];
  __shared__ u16 Pt[4][16][72];

  const int tid = threadIdx.x, lane = tid & 63, w = tid >> 6;
  const int l15 = lane & 15, l4 = lane >> 4;
  const int qw  = w * 16;

  const u16* qp = Q + (((size_t)b * H_ + h) * S_ + qw + l15) * 64;
  s8v qf0 = *(const s8v*)(qp + l4 * 8);
  s8v qf1 = *(const s8v*)(qp + 32 + l4 * 8);

  f4v acc[4];
  #pragma unroll
  for (int dt = 0; dt < 4; dt++) acc[dt] = (f4v){0.f, 0.f, 0.f, 0.f};
  float m[4]    = {-1e30f, -1e30f, -1e30f, -1e30f};
  float lsum[4] = {0.f, 0.f, 0.f, 0.f};

  const size_t bh_kv = (size_t)b * KVH_ + kh;
  const int r_ = tid >> 3, sg_ = (tid & 7) * 8;     // rows r_ and r_+32

  // prologue: stage tile kt0
  {
    const u16 *kp, *vp; int vstr;
    if (kt0 == 0) { kp = KS + bh_kv * 4096; vp = VST + bh_kv * 4096; vstr = 64; }
    else {
      kp = KR  + (bh_kv * R_ + kt0 * 64 - 64) * 64;
      vp = VRT + bh_kv * 64 * R_ + (kt0 * 64 - 64);
      vstr = R_;
    }
    s8v ka0 = *(const s8v*)(kp + r_ * 64 + sg_);
    s8v ka1 = *(const s8v*)(kp + (r_ + 32) * 64 + sg_);
    s8v va0 = *(const s8v*)(vp + (size_t)r_ * vstr + sg_);
    s8v va1 = *(const s8v*)(vp + (size_t)(r_ + 32) * vstr + sg_);
    *(s8v*)&Kt[0][r_][sg_]      = ka0;
    *(s8v*)&Kt[0][r_ + 32][sg_] = ka1;
    *(s8v*)&Vt[0][r_][sg_]      = va0;
    *(s8v*)&Vt[0][r_ + 32][sg_] = va1;
  }
  __syncthreads();

  for (int kt = kt0; kt < kt1; kt++) {
    const int cur = (kt - kt0) & 1;
    const int kbase = kt * 64;
    const bool pre = (kt + 1 < kt1);
    s8v ka0, ka1, va0, va1;
    if (pre) {                                 // next tile is always regular
      const u16* kp = KR  + (bh_kv * R_ + kbase) * 64;
      const u16* vp = VRT + bh_kv * 64 * R_ + kbase;
      ka0 = *(const s8v*)(kp + r_ * 64 + sg_);
      ka1 = *(const s8v*)(kp + (r_ + 32) * 64 + sg_);
      va0 = *(const s8v*)(vp + (size_t)r_ * R_ + sg_);
      va1 = *(const s8v*)(vp + (size_t)(r_ + 32) * R_ + sg_);
    }

    const bool active = (kbase == 0) || (((kbase - 64) >> 5) <= qw + 15);
    if (active)
      attn_tile<1>(Kt[cur], Vt[cur], Pt[w], qf0, qf1, acc, m, lsum,
                   kbase, qw, l15, l4);

    if (pre) {
      *(s8v*)&Kt[cur ^ 1][r_][sg_]      = ka0;
      *(s8v*)&Kt[cur ^ 1][r_ + 32][sg_] = ka1;
      *(s8v*)&Vt[cur ^ 1][r_][sg_]      = va0;
      *(s8v*)&Vt[cur ^ 1][r_ + 32][sg_] = va1;
    }
    __syncthreads();
  }

  // partial epilogue: unnormalized O, plus (m, l) per row
  #pragma unroll
  for (int r = 0; r < 4; r++) {
    int qrow = qw + l4 * 4 + r;
    float* po = pO + (((size_t)ck * 32 + bh) * 64 + qrow) * 64;
    #pragma unroll
    for (int dt = 0; dt < 4; dt++) po[dt * 16 + l15] = acc[dt][r];
    if (l15 == 0) {
      float* pm = pml + (((size_t)ck * 32 + bh) * 64 + qrow) * 2;
      pm[0] = m[r]; pm[1] = lsum[r];
    }
  }
}

// Combine 8 phase-1 partials -> sattn bf16 [b*64+q][1024]
__global__ __launch_bounds__(256)
void comb1_k(const float* __restrict__ pO, const float* __restrict__ pml,
             u16* __restrict__ sattn)
{
  const int bh = blockIdx.x;                   // 32
  const int b = bh >> 4, h = bh & 15;
  const int q  = threadIdx.x >> 2;
  const int d0 = (threadIdx.x & 3) * 16;
  float mv[8], lv[8], mstar = -1e30f;
  #pragma unroll
  for (int c = 0; c < 8; c++) {
    const float* p = pml + (((size_t)c * 32 + bh) * 64 + q) * 2;
    mv[c] = p[0]; lv[c] = p[1];
    mstar = fmaxf(mstar, mv[c]);
  }
  float o[16];
  #pragma unroll
  for (int j = 0; j < 16; j++) o[j] = 0.f;
  float lsum = 0.f;
  #pragma unroll
  for (int c = 0; c < 8; c++) {
    float wgt = __expf(mv[c] - mstar);
    lsum += lv[c] * wgt;
    const float* po = pO + (((size_t)c * 32 + bh) * 64 + q) * 64 + d0;
    #pragma unroll
    for (int j = 0; j < 16; j++) o[j] += po[j] * wgt;
  }
  float inv = 1.f / lsum;
  u16* out = sattn + ((size_t)(b * 64 + q)) * 1024 + h * 64 + d0;
  #pragma unroll
  for (int j = 0; j < 16; j++) out[j] = f2bf(o[j] * inv);
}

extern "C" void kernel_launch(void* const* d_in, const int* in_sizes, int n_in,
                              void* d_out, int out_size, void* d_ws, size_t ws_size,
                              hipStream_t stream)
{
  (void)out_size; (void)ws_size;

  static const int expect[22] = {
    131072, 4194304,
    1048576, 1024, 262144, 256,
    262144, 256, 1048576, 1024,
    1048576, 1024, 262144, 256,
    262144, 256, 1048576, 1024,
    262144, 256, 262144, 256
  };
  if (n_in < 22) return;
  for (int i = 0; i < 22; i++) if (in_sizes[i] != expect[i]) return;

  const float* sum_x = (const float*)d_in[0];
  const float* reg_x = (const float*)d_in[1];
  const float* w_sq = (const float*)d_in[2];  const float* b_sq = (const float*)d_in[3];
  const float* w_sk = (const float*)d_in[4];  const float* b_sk = (const float*)d_in[5];
  const float* w_sv = (const float*)d_in[6];  const float* b_sv = (const float*)d_in[7];
  const float* w_so = (const float*)d_in[8];  const float* b_so = (const float*)d_in[9];
  const float* w_rq = (const float*)d_in[10]; const float* b_rq = (const float*)d_in[11];
  const float* w_rk = (const float*)d_in[12]; const float* b_rk = (const float*)d_in[13];
  const float* w_rv = (const float*)d_in[14]; const float* b_rv = (const float*)d_in[15];
  const float* w_ro = (const float*)d_in[16]; const float* b_ro = (const float*)d_in[17];
  const float* w_k2 = (const float*)d_in[18]; const float* b_k2 = (const float*)d_in[19];
  const float* w_v2 = (const float*)d_in[20]; const float* b_v2 = (const float*)d_in[21];

  // bf16 workspace layout (u16 elements)
  u16* ws    = (u16*)d_ws;
  u16* xs_bf = ws;                    // 131072
  u16* xr_bf = xs_bf + 131072;        // 4194304
  u16* wt_s  = xr_bf + 4194304;       // 1572864  [sq|sk|sv] (dead after QKV -> V^T)
  u16* wt_r  = wt_s  + 1572864;       // 1572864  [rq|rk|rv]
  u16* wt_p  = wt_r  + 1572864;       // 1572864  [k2|v2|so]
  u16* wt_ro = wt_p  + 1572864;       // 1048576
  u16* sq    = wt_ro + 1048576;       // 131072   [B][H][S][64]
  u16* sk    = sq    + 131072;        // 32768    [B][KVH][S][64]
  u16* sv    = sk    + 32768;         // 32768
  u16* rq    = sv    + 32768;         // 4194304  [B][H][R][64]
  u16* rk    = rq    + 4194304;       // 1048576  [B][KVH][R][64]
  u16* rv    = rk    + 1048576;       // 1048576
  u16* sattn = rv    + 1048576;       // 131072   [B*S][D]
  u16* k2    = sattn + 131072;        // 32768
  u16* v2    = k2    + 32768;         // 32768
  u16* rattn = v2    + 32768;         // 4194304  [B*R][D]

  // transposed-V aliases inside the dead wt_s region
  u16* rvT = wt_s;                    // 1048576  [B][KVH][64][R]
  u16* svT = wt_s + 1048576;          // 32768    [B][KVH][64][S]
  u16* v2T = wt_s + 1081344;          // 32768

  // phase-1 partials alias the not-yet-written rattn region (fp32 views)
  float* pO  = (float*)rattn;         // 1,048,576 f32 (4 MB of rattn's 8 MB)
  float* pml = pO + 1048576;          // 32768 f32

  float* out_sum = (float*)d_out;          // (B,S,D) fp32
  float* out_reg = out_sum + 131072;       // (B,R,D) fp32

  dim3 blk(256);

  // ---- prep: weight transposes + activation convert ----
  W6 big;
  big.w[0] = w_sq; big.o[0] = wt_s;
  big.w[1] = w_rq; big.o[1] = wt_r;
  big.w[2] = w_so; big.o[2] = wt_p + 512 * 1024;
  big.w[3] = w_ro; big.o[3] = wt_ro;
  big.w[4] = w_sq; big.o[4] = wt_s;    // unused
  big.w[5] = w_sq; big.o[5] = wt_s;
  W6 small;
  small.w[0] = w_sk; small.o[0] = wt_s + 1024 * 1024;
  small.w[1] = w_sv; small.o[1] = wt_s + 1280 * 1024;
  small.w[2] = w_rk; small.o[2] = wt_r + 1024 * 1024;
  small.w[3] = w_rv; small.o[3] = wt_r + 1280 * 1024;
  small.w[4] = w_k2; small.o[4] = wt_p;
  small.w[5] = w_v2; small.o[5] = wt_p + 256 * 1024;
  transw_k<<<dim3(32, 32, 4), blk, 0, stream>>>(big, 1024);
  transw_k<<<dim3(8, 32, 6),  blk, 0, stream>>>(small, 256);
  convx_k<<<dim3(2112), blk, 0, stream>>>(sum_x, reg_x, xs_bf, xr_bf);

  // ---- fused QKV projections (+RoPE, +Q-scale) ----
  mgemm_f<0><<<dim3(12, 1),  blk, 0, stream>>>(xs_bf, wt_s, b_sq, b_sk, b_sv, sq, sk, sv);
  mgemm_f<1><<<dim3(12, 32), blk, 0, stream>>>(xr_bf, wt_r, b_rq, b_rk, b_rv, rq, rk, rv);

  // ---- V transposes (wt_s is dead now) ----
  VJ jrv = {rv, rvT, 2048};
  VJ jsv = {sv, svT, 64};
  vtrans_k<<<dim3(32, 8, 2), blk, 0, stream>>>(jrv, jsv);

  // ---- phase 1: summarize (split-K over 8 chunks) + combine ----
  attn1_k<<<dim3(256), blk, 0, stream>>>(sq, sk, rk, svT, rvT, pO, pml);
  comb1_k<<<dim3(32), blk, 0, stream>>>(pO, pml, sattn);

  // ---- fused k2/v2/out_sum ----
  mgemm_f<2><<<dim3(12, 1), blk, 0, stream>>>(sattn, wt_p, b_k2, b_v2, b_so, k2, v2, out_sum);
  VJ jv2 = {v2, v2T, 64};
  vtrans_k<<<dim3(1, 8, 1), blk, 0, stream>>>(jv2, jv2);

  // ---- phase 2: updating (double-buffered, balanced) ----
  attn2_k<<<dim3(512), dim3(512), 0, stream>>>(rq, k2, rk, v2T, rvT, rattn);

  // ---- regular out-projection ----
  mgemm_f<3><<<dim3(8, 32), blk, 0, stream>>>(rattn, wt_ro, b_ro, nullptr, nullptr,
                                              out_reg, nullptr, nullptr);
}

// Round 10
// 240.493 us; speedup vs baseline: 10.7727x; 1.2331x over previous
//
#include <hip/hip_runtime.h>

typedef unsigned short u16;
typedef __attribute__((ext_vector_type(8))) short s8v;   // 8 x bf16 MFMA A/B frag
typedef __attribute__((ext_vector_type(4))) float f4v;   // MFMA C/D frag

#define B_    2
#define S_    64
#define R_    2048
#define D_    1024
#define H_    16
#define KVH_  4
#define LOG2_10K 13.287712379549449f

__device__ __forceinline__ u16 f2bf(float f) {
  union { float f; unsigned int i; } v; v.f = f;
  unsigned int x = v.i;
  return (u16)((x + 0x7FFFu + ((x >> 16) & 1u)) >> 16);
}

// ---------------------------------------------------------------------------
// Prep kernels (unchanged)
// ---------------------------------------------------------------------------
struct W6 { const float* w[6]; u16* o[6]; };

__global__ __launch_bounds__(256)
void transw_k(W6 ws, int C)
{
  __shared__ float t[32][33];
  const int c0 = blockIdx.x * 32, k0 = blockIdx.y * 32;
  const float* w = ws.w[blockIdx.z];
  u16* o = ws.o[blockIdx.z];
  const int x = threadIdx.x & 31, y = threadIdx.x >> 5;
  #pragma unroll
  for (int j = 0; j < 4; j++)
    t[y + 8 * j][x] = w[(size_t)(k0 + y + 8 * j) * C + c0 + x];
  __syncthreads();
  #pragma unroll
  for (int j = 0; j < 4; j++)
    o[(size_t)(c0 + y + 8 * j) * 1024 + k0 + x] = f2bf(t[x][y + 8 * j]);
}

__global__ __launch_bounds__(256)
void convx_k(const float* __restrict__ xa, const float* __restrict__ xb,
             u16* __restrict__ oa, u16* __restrict__ ob)
{
  int i = (blockIdx.x * 256 + threadIdx.x) * 8;
  const float* src; u16* dst; int off;
  if (i < 131072) { src = xa; dst = oa; off = i; }
  else            { src = xb; dst = ob; off = i - 131072; }
  float4 a = *(const float4*)(src + off);
  float4 b = *(const float4*)(src + off + 4);
  s8v r;
  r[0] = (short)f2bf(a.x); r[1] = (short)f2bf(a.y);
  r[2] = (short)f2bf(a.z); r[3] = (short)f2bf(a.w);
  r[4] = (short)f2bf(b.x); r[5] = (short)f2bf(b.y);
  r[6] = (short)f2bf(b.z); r[7] = (short)f2bf(b.w);
  *(s8v*)(dst + off) = r;
}

struct VJ { const u16* in; u16* out; int lb; };

__global__ __launch_bounds__(256)
void vtrans_k(VJ j0, VJ j1)
{
  VJ j = (blockIdx.z == 0) ? j0 : j1;
  const int p0 = blockIdx.x * 64;
  if (p0 >= j.lb) return;
  __shared__ u16 T[64][72];
  const int tid = threadIdx.x;
  const int bh = blockIdx.y;
  #pragma unroll
  for (int it = 0; it < 2; it++) {
    int idx = tid + it * 256;
    int p = idx >> 3, c = (idx & 7) * 8;
    *(s8v*)&T[p][c] = *(const s8v*)(j.in + ((size_t)bh * j.lb + p0 + p) * 64 + c);
  }
  __syncthreads();
  #pragma unroll
  for (int it = 0; it < 2; it++) {
    int idx = tid + it * 256;
    int d = idx >> 3, pc = (idx & 7) * 8;
    u16 tmp[8];
    #pragma unroll
    for (int q = 0; q < 8; q++) tmp[q] = T[pc + q][d];
    *(s8v*)(j.out + ((size_t)bh * 64 + d) * j.lb + p0 + pc) = *(s8v*)tmp;
  }
}

// ---------------------------------------------------------------------------
// GEMM core: 128x128 tile, BK=64, 4 waves (2x2 of 64x64). acc D-frag:
// col = l15 (B-free), row = l4*4+reg. LDS [128][72] per side (2-way max alias).
// ---------------------------------------------------------------------------
__device__ __forceinline__ void gemm_core(
    const u16* __restrict__ Xrow, const u16* __restrict__ WTrow,
    u16 (*As)[72], u16 (*Bs)[72], f4v (&acc)[4][4],
    int tid, int l15, int l4, int wro, int wco)
{
  for (int k0 = 0; k0 < 1024; k0 += 64) {
    __syncthreads();
    #pragma unroll
    for (int it = 0; it < 4; it++) {
      int seg = tid + it * 256;
      int r = seg >> 3, sg = (seg & 7) * 8;
      *(s8v*)&As[r][sg] = *(const s8v*)(Xrow  + (size_t)r * 1024 + k0 + sg);
      *(s8v*)&Bs[r][sg] = *(const s8v*)(WTrow + (size_t)r * 1024 + k0 + sg);
    }
    __syncthreads();

    s8v af[4][2], bf4[4][2];
    #pragma unroll
    for (int rc = 0; rc < 4; rc++) {
      af[rc][0] = *(const s8v*)&As[wro + rc * 16 + l15][l4 * 8];
      af[rc][1] = *(const s8v*)&As[wro + rc * 16 + l15][32 + l4 * 8];
    }
    #pragma unroll
    for (int cc = 0; cc < 4; cc++) {
      bf4[cc][0] = *(const s8v*)&Bs[wco + cc * 16 + l15][l4 * 8];
      bf4[cc][1] = *(const s8v*)&Bs[wco + cc * 16 + l15][32 + l4 * 8];
    }
    #pragma unroll
    for (int rc = 0; rc < 4; rc++)
      #pragma unroll
      for (int cc = 0; cc < 4; cc++) {
        acc[rc][cc] = __builtin_amdgcn_mfma_f32_16x16x32_bf16(af[rc][0], bf4[cc][0], acc[rc][cc], 0, 0, 0);
        acc[rc][cc] = __builtin_amdgcn_mfma_f32_16x16x32_bf16(af[rc][1], bf4[cc][1], acc[rc][cc], 0, 0, 0);
      }
  }
  __syncthreads();   // all LDS reads done before epilogue reuses the buffers
}

// Wave epilogue -> LDS staging tile Es[128][136] (bf16 values, bias+RoPE applied).
// ropeMode: 0 = none, 1 = rope (rope2d picks table). sc: *0.125 after rope.
__device__ __forceinline__ void epi_to_lds(
    const f4v (&acc)[4][4], const float* __restrict__ Bp, u16* __restrict__ Es,
    int cbr, int wro, int wco, int grb, int LB,
    int ropeMode, bool rope2d, bool sc, int l15, int l4)
{
  float bv[4];
  #pragma unroll
  for (int cc = 0; cc < 4; cc++) bv[cc] = Bp[cbr + cc * 16 + l15];

  if (ropeMode == 0) {
    #pragma unroll
    for (int rc = 0; rc < 4; rc++)
      #pragma unroll
      for (int reg = 0; reg < 4; reg++) {
        int lrow = wro + rc * 16 + l4 * 4 + reg;
        #pragma unroll
        for (int cc = 0; cc < 4; cc++)
          Es[lrow * 136 + wco + cc * 16 + l15] = f2bf(acc[rc][cc][reg] + bv[cc]);
      }
  } else {
    float step = rope2d ? (LOG2_10K / 16.f) : (LOG2_10K / 32.f);
    float inv_lo = exp2f(-(float)l15 * step);
    float inv_hi = rope2d ? inv_lo : inv_lo * exp2f(-16.f * step);
    #pragma unroll
    for (int rc = 0; rc < 4; rc++)
      #pragma unroll
      for (int reg = 0; reg < 4; reg++) {
        int lrow = wro + rc * 16 + l4 * 4 + reg;
        int grow = grb + lrow;
        int pos = grow & (LB - 1);
        int bar = pos >> 5, tib = pos & 31;
        #pragma unroll
        for (int cc = 0; cc < 4; cc++) {
          float inv = (cc & 1) ? inv_hi : inv_lo;
          float bse = rope2d ? (float)((cc & 1) ? tib : bar) : (float)pos;
          float ang = bse * inv;
          float sn, cs;
          sincosf(ang, &sn, &cs);
          float v0 = acc[rc][cc][reg] + bv[cc];
          float v1 = acc[rc][cc ^ 2][reg] + bv[cc ^ 2];
          float rot = (cc < 2) ? -v1 : v1;
          float val = v0 * cs + rot * sn;
          if (sc) val *= 0.125f;
          Es[lrow * 136 + wco + cc * 16 + l15] = f2bf(val);
        }
      }
  }
}

// Cooperative full-line store: Es[128][136] -> head-split bf16 [b][NH][LB][64].
// Each instruction: 8 lanes x 16B = one full 128B output row.
__device__ __forceinline__ void store_tile_bf16(
    const u16* __restrict__ Es, u16* __restrict__ out,
    int grb, int c0r, int NH, int LB, int LBS, int tid)
{
  #pragma unroll
  for (int it = 0; it < 8; it++) {
    int idx = it * 256 + tid;
    int r = idx >> 4, ch = idx & 15;
    int grow = grb + r;
    int b = grow >> LBS, pos = grow & (LB - 1);
    int cg = c0r + ch * 8;
    size_t base = (((size_t)b * NH + (cg >> 6)) * LB + pos) * 64 + (cg & 63);
    *(s8v*)(out + base) = *(const s8v*)(Es + r * 136 + ch * 8);
  }
}

// ---------------------------------------------------------------------------
// Fused QKV GEMM (summary + regular), XCD-swizzled. grid = 396 (12 x 33).
// by==0: summary rows (wt_s, RoPE-1D, LB=64); by>=1: regular (wt_r, RoPE-2D).
// ---------------------------------------------------------------------------
struct QkvA {
  const u16 *X, *WTs, *WTr;
  const float *b0s, *b1s, *b2s, *b0r, *b1r, *b2r;
  u16 *o0s, *o1s, *o2s, *o0r, *o1r, *o2r;
};

__global__ __launch_bounds__(256)
void qkv_k(QkvA a)
{
  // bijective XCD swizzle, nwg=396: q=49, rem=4
  int orig = blockIdx.x;
  int xcd = orig & 7, sidx = orig >> 3;
  int wg = (xcd < 4) ? (xcd * 50 + sidx) : (200 + (xcd - 4) * 49 + sidx);
  const int bx = wg % 12, by = wg / 12;
  const bool issum = (by == 0);
  const int c0 = bx * 128;

  __shared__ u16 LDS_[2][128][72];
  u16 (*As)[72] = LDS_[0];
  u16 (*Bs)[72] = LDS_[1];
  u16* Es = &LDS_[0][0][0];

  const int tid  = threadIdx.x;
  const int lane = tid & 63;
  const int w    = tid >> 6;
  const int l15  = lane & 15;
  const int l4   = lane >> 4;
  const int wro  = (w >> 1) * 64;
  const int wco  = (w & 1) * 64;

  f4v acc[4][4];
  #pragma unroll
  for (int i = 0; i < 4; i++)
    #pragma unroll
    for (int j = 0; j < 4; j++) acc[i][j] = (f4v){0.f, 0.f, 0.f, 0.f};

  const u16* Xrow  = a.X + (size_t)by * 128 * 1024;
  const u16* WTrow = (issum ? a.WTs : a.WTr) + (size_t)c0 * 1024;
  gemm_core(Xrow, WTrow, As, Bs, acc, tid, l15, l4, wro, wco);

  const int LB  = issum ? 64 : 2048;
  const int LBS = issum ? 6 : 11;
  const int grb = issum ? 0 : (by - 1) * 128;

  const float* Bp; u16* Outp; int NH, rs, ropeMode; bool sc;
  if (c0 < 1024)      { Bp = issum ? a.b0s : a.b0r; Outp = issum ? a.o0s : a.o0r; NH = 16; rs = 0;    ropeMode = 1; sc = true;  }
  else if (c0 < 1280) { Bp = issum ? a.b1s : a.b1r; Outp = issum ? a.o1s : a.o1r; NH = 4;  rs = 1024; ropeMode = 1; sc = false; }
  else                { Bp = issum ? a.b2s : a.b2r; Outp = issum ? a.o2s : a.o2r; NH = 4;  rs = 1280; ropeMode = 0; sc = false; }

  epi_to_lds(acc, Bp, Es, c0 - rs + wco, wro, wco, grb, LB, ropeMode, !issum, sc, l15, l4);
  __syncthreads();
  store_tile_bf16(Es, Outp, grb, c0 - rs, NH, LB, LBS, tid);
}

// ---------------------------------------------------------------------------
// Phase-1 output GEMM: k2 / v2 (bf16, Es path) + so (fp32 direct). grid = 12.
// ---------------------------------------------------------------------------
__global__ __launch_bounds__(256)
void gemm_p1_k(const u16* __restrict__ X, const u16* __restrict__ WT,
               const float* __restrict__ bk2, const float* __restrict__ bv2,
               const float* __restrict__ bso,
               u16* __restrict__ k2, u16* __restrict__ v2, float* __restrict__ outsum)
{
  const int c0 = blockIdx.x * 128;

  __shared__ u16 LDS_[2][128][72];
  u16 (*As)[72] = LDS_[0];
  u16 (*Bs)[72] = LDS_[1];
  u16* Es = &LDS_[0][0][0];

  const int tid  = threadIdx.x;
  const int lane = tid & 63;
  const int w    = tid >> 6;
  const int l15  = lane & 15;
  const int l4   = lane >> 4;
  const int wro  = (w >> 1) * 64;
  const int wco  = (w & 1) * 64;

  f4v acc[4][4];
  #pragma unroll
  for (int i = 0; i < 4; i++)
    #pragma unroll
    for (int j = 0; j < 4; j++) acc[i][j] = (f4v){0.f, 0.f, 0.f, 0.f};

  gemm_core(X, WT + (size_t)c0 * 1024, As, Bs, acc, tid, l15, l4, wro, wco);

  if (c0 < 512) {
    const float* Bp = (c0 < 256) ? bk2 : bv2;
    u16* Outp = (c0 < 256) ? k2 : v2;
    int rs = (c0 < 256) ? 0 : 256;
    epi_to_lds(acc, Bp, Es, c0 - rs + wco, wro, wco, 0, 64, 0, false, false, l15, l4);
    __syncthreads();
    store_tile_bf16(Es, Outp, 0, c0 - rs, 4, 64, 6, tid);
  } else {
    // so: fp32 [128][1024], 64B-contiguous per instruction (full sectors)
    float bv[4];
    #pragma unroll
    for (int cc = 0; cc < 4; cc++) bv[cc] = bso[c0 - 512 + wco + cc * 16 + l15];
    #pragma unroll
    for (int rc = 0; rc < 4; rc++)
      #pragma unroll
      for (int reg = 0; reg < 4; reg++) {
        int row = wro + rc * 16 + l4 * 4 + reg;
        #pragma unroll
        for (int cc = 0; cc < 4; cc++)
          outsum[(size_t)row * 1024 + c0 - 512 + wco + cc * 16 + l15] = acc[rc][cc][reg] + bv[cc];
      }
  }
}

// ---------------------------------------------------------------------------
// ro GEMM: rattn[4096][1024] @ wt_ro -> out_reg fp32. grid = 256, XCD-swizzled.
// ---------------------------------------------------------------------------
__global__ __launch_bounds__(256)
void gemm_ro_k(const u16* __restrict__ X, const u16* __restrict__ WT,
               const float* __restrict__ Bp, float* __restrict__ out)
{
  int orig = blockIdx.x;
  int wg = (orig & 7) * 32 + (orig >> 3);        // 256 = 8*32 exact
  const int bx = wg & 7, by = wg >> 3;
  const int c0 = bx * 128, r0 = by * 128;

  __shared__ u16 LDS_[2][128][72];
  u16 (*As)[72] = LDS_[0];
  u16 (*Bs)[72] = LDS_[1];

  const int tid  = threadIdx.x;
  const int lane = tid & 63;
  const int w    = tid >> 6;
  const int l15  = lane & 15;
  const int l4   = lane >> 4;
  const int wro  = (w >> 1) * 64;
  const int wco  = (w & 1) * 64;

  f4v acc[4][4];
  #pragma unroll
  for (int i = 0; i < 4; i++)
    #pragma unroll
    for (int j = 0; j < 4; j++) acc[i][j] = (f4v){0.f, 0.f, 0.f, 0.f};

  gemm_core(X + (size_t)r0 * 1024, WT + (size_t)c0 * 1024, As, Bs, acc,
            tid, l15, l4, wro, wco);

  float bv[4];
  #pragma unroll
  for (int cc = 0; cc < 4; cc++) bv[cc] = Bp[c0 + wco + cc * 16 + l15];
  #pragma unroll
  for (int rc = 0; rc < 4; rc++)
    #pragma unroll
    for (int reg = 0; reg < 4; reg++) {
      int row = r0 + wro + rc * 16 + l4 * 4 + reg;
      #pragma unroll
      for (int cc = 0; cc < 4; cc++)
        out[(size_t)row * 1024 + c0 + wco + cc * 16 + l15] = acc[rc][cc][reg] + bv[cc];
    }
}

// ---------------------------------------------------------------------------
// Shared flash-attention tile compute (unchanged from round 8).
// ---------------------------------------------------------------------------
template<int PHASE>
__device__ __forceinline__ void attn_tile(
    const u16 (&Kc)[64][72], const u16 (&Vc)[64][72], u16 (&Ptw)[16][72],
    const s8v& qf0, const s8v& qf1, f4v (&acc)[4],
    float (&m)[4], float (&lsum)[4],
    int kbase, int qw, int l15, int l4)
{
  f4v s[4];
  #pragma unroll
  for (int n = 0; n < 4; n++) {
    s8v kf0 = *(const s8v*)&Kc[n * 16 + l15][l4 * 8];
    s8v kf1 = *(const s8v*)&Kc[n * 16 + l15][32 + l4 * 8];
    f4v t = {0.f, 0.f, 0.f, 0.f};
    t = __builtin_amdgcn_mfma_f32_16x16x32_bf16(qf0, kf0, t, 0, 0, 0);
    t = __builtin_amdgcn_mfma_f32_16x16x32_bf16(qf1, kf1, t, 0, 0, 0);
    s[n] = t;
  }

  bool need_mask = (kbase == 0) ||
    (PHASE == 1 ? (((kbase - 1) >> 5) > qw) : ((kbase - 1) > qw));
  float v4[4] = {-1e30f, -1e30f, -1e30f, -1e30f};
  if (need_mask) {
    #pragma unroll
    for (int n = 0; n < 4; n++) {
      int kidx = kbase + n * 16 + l15;
      #pragma unroll
      for (int r = 0; r < 4; r++) {
        int qrow = qw + l4 * 4 + r;
        bool ok;
        if (kbase == 0) ok = kidx <= ((PHASE == 1) ? qrow : (qrow >> 5));
        else { int kr = kidx - 64; ok = (PHASE == 1) ? ((kr >> 5) <= qrow) : (kr <= qrow); }
        float sv = ok ? s[n][r] : -1e30f;
        s[n][r] = sv;
        v4[r] = fmaxf(v4[r], sv);
      }
    }
  } else {
    #pragma unroll
    for (int n = 0; n < 4; n++)
      #pragma unroll
      for (int r = 0; r < 4; r++) v4[r] = fmaxf(v4[r], s[n][r]);
  }
  #pragma unroll
  for (int r = 0; r < 4; r++) {
    float v = v4[r];
    v = fmaxf(v, __shfl_xor(v, 1));
    v = fmaxf(v, __shfl_xor(v, 2));
    v = fmaxf(v, __shfl_xor(v, 4));
    v = fmaxf(v, __shfl_xor(v, 8));
    v4[r] = v;
  }
  bool up = (v4[0] > m[0]) || (v4[1] > m[1]) || (v4[2] > m[2]) || (v4[3] > m[3]);
  if (__any(up)) {
    #pragma unroll
    for (int r = 0; r < 4; r++) {
      float mn = fmaxf(m[r], v4[r]);
      float f  = __expf(m[r] - mn);
      m[r] = mn;
      lsum[r] *= f;
      #pragma unroll
      for (int dt = 0; dt < 4; dt++) acc[dt][r] *= f;
    }
  }
  float rs[4] = {0.f, 0.f, 0.f, 0.f};
  #pragma unroll
  for (int n = 0; n < 4; n++) {
    #pragma unroll
    for (int r = 0; r < 4; r++) {
      float p = __expf(s[n][r] - m[r]);
      Ptw[l4 * 4 + r][n * 16 + l15] = f2bf(p);
      rs[r] += p;
    }
  }
  #pragma unroll
  for (int r = 0; r < 4; r++) {
    float v = rs[r];
    v += __shfl_xor(v, 1); v += __shfl_xor(v, 2);
    v += __shfl_xor(v, 4); v += __shfl_xor(v, 8);
    lsum[r] += v;
  }

  asm volatile("s_waitcnt lgkmcnt(0)" ::: "memory");

  s8v pf0 = *(const s8v*)&Ptw[l15][l4 * 8];
  s8v pf1 = *(const s8v*)&Ptw[l15][32 + l4 * 8];
  #pragma unroll
  for (int dt = 0; dt < 4; dt++) {
    s8v vf0 = *(const s8v*)&Vc[dt * 16 + l15][l4 * 8];
    s8v vf1 = *(const s8v*)&Vc[dt * 16 + l15][32 + l4 * 8];
    acc[dt] = __builtin_amdgcn_mfma_f32_16x16x32_bf16(pf0, vf0, acc[dt], 0, 0, 0);
    acc[dt] = __builtin_amdgcn_mfma_f32_16x16x32_bf16(pf1, vf1, acc[dt], 0, 0, 0);
  }
}

// ---------------------------------------------------------------------------
// Phase 2 attention (round-8 structure; full-line O store via Pt staging).
// ---------------------------------------------------------------------------
__global__ __launch_bounds__(512)
void attn2_k(const u16* __restrict__ Q, const u16* __restrict__ KS,
             const u16* __restrict__ KR, const u16* __restrict__ VST,
             const u16* __restrict__ VRT, u16* __restrict__ Out)
{
  const int gid = blockIdx.x;
  const int qb  = (gid & 256) ? (15 - (gid & 15)) : (gid & 15);
  const int bh  = gid >> 4;
  const int h   = bh & 15, b = bh >> 4;
  const int q0  = qb * 128;
  const int kh  = h >> 2;

  __shared__ u16 Kt[2][64][72];
  __shared__ u16 Vt[2][64][72];
  __shared__ u16 Pt[8][16][72];

  const int tid = threadIdx.x, lane = tid & 63, w = tid >> 6;
  const int l15 = lane & 15, l4 = lane >> 4;
  const int qw  = q0 + w * 16;

  const u16* qp = Q + (((size_t)b * H_ + h) * R_ + qw + l15) * 64;
  s8v qf0 = *(const s8v*)(qp + l4 * 8);
  s8v qf1 = *(const s8v*)(qp + 32 + l4 * 8);

  f4v acc[4];
  #pragma unroll
  for (int dt = 0; dt < 4; dt++) acc[dt] = (f4v){0.f, 0.f, 0.f, 0.f};
  float m[4]    = {-1e30f, -1e30f, -1e30f, -1e30f};
  float lsum[4] = {0.f, 0.f, 0.f, 0.f};

  const int ntiles = (64 + q0 + 128) >> 6;
  const size_t bh_kv = (size_t)b * KVH_ + kh;

  const int r_ = tid >> 3, sg_ = (tid & 7) * 8;

  {
    const u16* kp = KS  + bh_kv * 4096;
    const u16* vp = VST + bh_kv * 4096;
    s8v k0 = *(const s8v*)(kp + r_ * 64 + sg_);
    s8v v0 = *(const s8v*)(vp + r_ * 64 + sg_);
    *(s8v*)&Kt[0][r_][sg_] = k0;
    *(s8v*)&Vt[0][r_][sg_] = v0;
  }
  __syncthreads();

  for (int kt = 0; kt < ntiles; kt++) {
    const int cur = kt & 1;
    const int kbase = kt * 64;
    const bool pre = (kt + 1 < ntiles);
    s8v knx, vnx;
    if (pre) {
      const int nb = kbase;
      const u16* kp = KR  + (bh_kv * R_ + nb) * 64;
      const u16* vp = VRT + bh_kv * 64 * R_ + nb;
      knx = *(const s8v*)(kp + r_ * 64 + sg_);
      vnx = *(const s8v*)(vp + (size_t)r_ * R_ + sg_);
    }

    const bool active = (kbase == 0) || (kbase - 64 <= qw + 15);
    if (active)
      attn_tile<2>(Kt[cur], Vt[cur], Pt[w], qf0, qf1, acc, m, lsum,
                   kbase, qw, l15, l4);

    if (pre) {
      *(s8v*)&Kt[cur ^ 1][r_][sg_] = knx;
      *(s8v*)&Vt[cur ^ 1][r_][sg_] = vnx;
    }
    __syncthreads();
  }

  // stage O (bf16) into this wave's Pt, then full-line stores
  #pragma unroll
  for (int r = 0; r < 4; r++) {
    float linv = 1.f / lsum[r];
    #pragma unroll
    for (int dt = 0; dt < 4; dt++)
      Pt[w][l4 * 4 + r][dt * 16 + l15] = f2bf(acc[dt][r] * linv);
  }
  asm volatile("s_waitcnt lgkmcnt(0)" ::: "memory");
  {
    int rl = lane >> 3, ch = lane & 7;
    #pragma unroll
    for (int rr = 0; rr < 2; rr++) {
      int row = rr * 8 + rl;
      u16* o = Out + ((size_t)b * R_ + qw + row) * D_ + h * 64 + ch * 8;
      *(s8v*)o = *(const s8v*)&Pt[w][row][ch * 8];
    }
  }
}

// ---------------------------------------------------------------------------
// Phase 1 attention, split-K (unchanged; fp32 partials are full-sector writes).
// ---------------------------------------------------------------------------
__global__ __launch_bounds__(256)
void attn1_k(const u16* __restrict__ Q, const u16* __restrict__ KS,
             const u16* __restrict__ KR, const u16* __restrict__ VST,
             const u16* __restrict__ VRT,
             float* __restrict__ pO, float* __restrict__ pml)
{
  const int gid = blockIdx.x;
  const int ck  = gid & 7;
  const int bh  = gid >> 3;
  const int h   = bh & 15, b = bh >> 4;
  const int kh  = h >> 2;
  const int kt0 = (ck * 33) >> 3;
  const int kt1 = ((ck + 1) * 33) >> 3;

  __shared__ u16 Kt[2][64][72];
  __shared__ u16 Vt[2][64][72];
  __shared__ u16 Pt[4][16][72];

  const int tid = threadIdx.x, lane = tid & 63, w = tid >> 6;
  const int l15 = lane & 15, l4 = lane >> 4;
  const int qw  = w * 16;

  const u16* qp = Q + (((size_t)b * H_ + h) * S_ + qw + l15) * 64;
  s8v qf0 = *(const s8v*)(qp + l4 * 8);
  s8v qf1 = *(const s8v*)(qp + 32 + l4 * 8);

  f4v acc[4];
  #pragma unroll
  for (int dt = 0; dt < 4; dt++) acc[dt] = (f4v){0.f, 0.f, 0.f, 0.f};
  float m[4]    = {-1e30f, -1e30f, -1e30f, -1e30f};
  float lsum[4] = {0.f, 0.f, 0.f, 0.f};

  const size_t bh_kv = (size_t)b * KVH_ + kh;
  const int r_ = tid >> 3, sg_ = (tid & 7) * 8;

  {
    const u16 *kp, *vp; int vstr;
    if (kt0 == 0) { kp = KS + bh_kv * 4096; vp = VST + bh_kv * 4096; vstr = 64; }
    else {
      kp = KR  + (bh_kv * R_ + kt0 * 64 - 64) * 64;
      vp = VRT + bh_kv * 64 * R_ + (kt0 * 64 - 64);
      vstr = R_;
    }
    s8v ka0 = *(const s8v*)(kp + r_ * 64 + sg_);
    s8v ka1 = *(const s8v*)(kp + (r_ + 32) * 64 + sg_);
    s8v va0 = *(const s8v*)(vp + (size_t)r_ * vstr + sg_);
    s8v va1 = *(const s8v*)(vp + (size_t)(r_ + 32) * vstr + sg_);
    *(s8v*)&Kt[0][r_][sg_]      = ka0;
    *(s8v*)&Kt[0][r_ + 32][sg_] = ka1;
    *(s8v*)&Vt[0][r_][sg_]      = va0;
    *(s8v*)&Vt[0][r_ + 32][sg_] = va1;
  }
  __syncthreads();

  for (int kt = kt0; kt < kt1; kt++) {
    const int cur = (kt - kt0) & 1;
    const int kbase = kt * 64;
    const bool pre = (kt + 1 < kt1);
    s8v ka0, ka1, va0, va1;
    if (pre) {
      const u16* kp = KR  + (bh_kv * R_ + kbase) * 64;
      const u16* vp = VRT + bh_kv * 64 * R_ + kbase;
      ka0 = *(const s8v*)(kp + r_ * 64 + sg_);
      ka1 = *(const s8v*)(kp + (r_ + 32) * 64 + sg_);
      va0 = *(const s8v*)(vp + (size_t)r_ * R_ + sg_);
      va1 = *(const s8v*)(vp + (size_t)(r_ + 32) * R_ + sg_);
    }

    const bool active = (kbase == 0) || (((kbase - 64) >> 5) <= qw + 15);
    if (active)
      attn_tile<1>(Kt[cur], Vt[cur], Pt[w], qf0, qf1, acc, m, lsum,
                   kbase, qw, l15, l4);

    if (pre) {
      *(s8v*)&Kt[cur ^ 1][r_][sg_]      = ka0;
      *(s8v*)&Kt[cur ^ 1][r_ + 32][sg_] = ka1;
      *(s8v*)&Vt[cur ^ 1][r_][sg_]      = va0;
      *(s8v*)&Vt[cur ^ 1][r_ + 32][sg_] = va1;
    }
    __syncthreads();
  }

  #pragma unroll
  for (int r = 0; r < 4; r++) {
    int qrow = qw + l4 * 4 + r;
    float* po = pO + (((size_t)ck * 32 + bh) * 64 + qrow) * 64;
    #pragma unroll
    for (int dt = 0; dt < 4; dt++) po[dt * 16 + l15] = acc[dt][r];
    if (l15 == 0) {
      float* pm = pml + (((size_t)ck * 32 + bh) * 64 + qrow) * 2;
      pm[0] = m[r]; pm[1] = lsum[r];
    }
  }
}

// Combine 8 phase-1 partials -> sattn bf16 (vectorized 16B stores)
__global__ __launch_bounds__(256)
void comb1_k(const float* __restrict__ pO, const float* __restrict__ pml,
             u16* __restrict__ sattn)
{
  const int bh = blockIdx.x;
  const int b = bh >> 4, h = bh & 15;
  const int q  = threadIdx.x >> 2;
  const int d0 = (threadIdx.x & 3) * 16;
  float mv[8], lv[8], mstar = -1e30f;
  #pragma unroll
  for (int c = 0; c < 8; c++) {
    const float* p = pml + (((size_t)c * 32 + bh) * 64 + q) * 2;
    mv[c] = p[0]; lv[c] = p[1];
    mstar = fmaxf(mstar, mv[c]);
  }
  float o[16];
  #pragma unroll
  for (int j = 0; j < 16; j++) o[j] = 0.f;
  float lsum = 0.f;
  #pragma unroll
  for (int c = 0; c < 8; c++) {
    float wgt = __expf(mv[c] - mstar);
    lsum += lv[c] * wgt;
    const float* po = pO + (((size_t)c * 32 + bh) * 64 + q) * 64 + d0;
    #pragma unroll
    for (int j = 0; j < 16; j++) o[j] += po[j] * wgt;
  }
  float inv = 1.f / lsum;
  u16 ob[16];
  #pragma unroll
  for (int j = 0; j < 16; j++) ob[j] = f2bf(o[j] * inv);
  u16* out = sattn + ((size_t)(b * 64 + q)) * 1024 + h * 64 + d0;
  *(s8v*)out       = *(s8v*)&ob[0];
  *(s8v*)(out + 8) = *(s8v*)&ob[8];
}

extern "C" void kernel_launch(void* const* d_in, const int* in_sizes, int n_in,
                              void* d_out, int out_size, void* d_ws, size_t ws_size,
                              hipStream_t stream)
{
  (void)out_size; (void)ws_size;

  static const int expect[22] = {
    131072, 4194304,
    1048576, 1024, 262144, 256,
    262144, 256, 1048576, 1024,
    1048576, 1024, 262144, 256,
    262144, 256, 1048576, 1024,
    262144, 256, 262144, 256
  };
  if (n_in < 22) return;
  for (int i = 0; i < 22; i++) if (in_sizes[i] != expect[i]) return;

  const float* sum_x = (const float*)d_in[0];
  const float* reg_x = (const float*)d_in[1];
  const float* w_sq = (const float*)d_in[2];  const float* b_sq = (const float*)d_in[3];
  const float* w_sk = (const float*)d_in[4];  const float* b_sk = (const float*)d_in[5];
  const float* w_sv = (const float*)d_in[6];  const float* b_sv = (const float*)d_in[7];
  const float* w_so = (const float*)d_in[8];  const float* b_so = (const float*)d_in[9];
  const float* w_rq = (const float*)d_in[10]; const float* b_rq = (const float*)d_in[11];
  const float* w_rk = (const float*)d_in[12]; const float* b_rk = (const float*)d_in[13];
  const float* w_rv = (const float*)d_in[14]; const float* b_rv = (const float*)d_in[15];
  const float* w_ro = (const float*)d_in[16]; const float* b_ro = (const float*)d_in[17];
  const float* w_k2 = (const float*)d_in[18]; const float* b_k2 = (const float*)d_in[19];
  const float* w_v2 = (const float*)d_in[20]; const float* b_v2 = (const float*)d_in[21];

  // bf16 workspace layout (u16 elements); xs_bf and xr_bf are contiguous rows
  u16* ws    = (u16*)d_ws;
  u16* xs_bf = ws;                    // 131072  (rows 0..127 of unified X)
  u16* xr_bf = xs_bf + 131072;        // 4194304 (rows 128..4223)
  u16* wt_s  = xr_bf + 4194304;       // 1572864  [sq|sk|sv] (dead after QKV -> V^T)
  u16* wt_r  = wt_s  + 1572864;       // 1572864  [rq|rk|rv]
  u16* wt_p  = wt_r  + 1572864;       // 1572864  [k2|v2|so]
  u16* wt_ro = wt_p  + 1572864;       // 1048576
  u16* sq    = wt_ro + 1048576;       // 131072   [B][H][S][64]
  u16* sk    = sq    + 131072;        // 32768    [B][KVH][S][64]
  u16* sv    = sk    + 32768;         // 32768
  u16* rq    = sv    + 32768;         // 4194304  [B][H][R][64]
  u16* rk    = rq    + 4194304;       // 1048576  [B][KVH][R][64]
  u16* rv    = rk    + 1048576;       // 1048576
  u16* sattn = rv    + 1048576;       // 131072   [B*S][D]
  u16* k2    = sattn + 131072;        // 32768
  u16* v2    = k2    + 32768;         // 32768
  u16* rattn = v2    + 32768;         // 4194304  [B*R][D]

  u16* rvT = wt_s;                    // 1048576  [B][KVH][64][R]
  u16* svT = wt_s + 1048576;          // 32768    [B][KVH][64][S]
  u16* v2T = wt_s + 1081344;          // 32768

  float* pO  = (float*)rattn;
  float* pml = pO + 1048576;

  float* out_sum = (float*)d_out;
  float* out_reg = out_sum + 131072;

  dim3 blk(256);

  W6 big;
  big.w[0] = w_sq; big.o[0] = wt_s;
  big.w[1] = w_rq; big.o[1] = wt_r;
  big.w[2] = w_so; big.o[2] = wt_p + 512 * 1024;
  big.w[3] = w_ro; big.o[3] = wt_ro;
  big.w[4] = w_sq; big.o[4] = wt_s;
  big.w[5] = w_sq; big.o[5] = wt_s;
  W6 small;
  small.w[0] = w_sk; small.o[0] = wt_s + 1024 * 1024;
  small.w[1] = w_sv; small.o[1] = wt_s + 1280 * 1024;
  small.w[2] = w_rk; small.o[2] = wt_r + 1024 * 1024;
  small.w[3] = w_rv; small.o[3] = wt_r + 1280 * 1024;
  small.w[4] = w_k2; small.o[4] = wt_p;
  small.w[5] = w_v2; small.o[5] = wt_p + 256 * 1024;
  transw_k<<<dim3(32, 32, 4), blk, 0, stream>>>(big, 1024);
  transw_k<<<dim3(8, 32, 6),  blk, 0, stream>>>(small, 256);
  convx_k<<<dim3(2112), blk, 0, stream>>>(sum_x, reg_x, xs_bf, xr_bf);

  // fused QKV (summary + regular), XCD-swizzled, full-line stores
  QkvA qa;
  qa.X = xs_bf; qa.WTs = wt_s; qa.WTr = wt_r;
  qa.b0s = b_sq; qa.b1s = b_sk; qa.b2s = b_sv;
  qa.b0r = b_rq; qa.b1r = b_rk; qa.b2r = b_rv;
  qa.o0s = sq; qa.o1s = sk; qa.o2s = sv;
  qa.o0r = rq; qa.o1r = rk; qa.o2r = rv;
  qkv_k<<<dim3(396), blk, 0, stream>>>(qa);

  VJ jrv = {rv, rvT, 2048};
  VJ jsv = {sv, svT, 64};
  vtrans_k<<<dim3(32, 8, 2), blk, 0, stream>>>(jrv, jsv);

  attn1_k<<<dim3(256), blk, 0, stream>>>(sq, sk, rk, svT, rvT, pO, pml);
  comb1_k<<<dim3(32), blk, 0, stream>>>(pO, pml, sattn);

  gemm_p1_k<<<dim3(12), blk, 0, stream>>>(sattn, wt_p, b_k2, b_v2, b_so, k2, v2, out_sum);
  VJ jv2 = {v2, v2T, 64};
  vtrans_k<<<dim3(1, 8, 1), blk, 0, stream>>>(jv2, jv2);

  attn2_k<<<dim3(512), dim3(512), 0, stream>>>(rq, k2, rk, v2T, rvT, rattn);

  gemm_ro_k<<<dim3(256), blk, 0, stream>>>(rattn, wt_ro, b_ro, out_reg);
}

// Round 11
// 226.982 us; speedup vs baseline: 11.4140x; 1.0595x over previous
//
#include <hip/hip_runtime.h>

typedef unsigned short u16;
typedef __attribute__((ext_vector_type(8))) short s8v;   // 8 x bf16 MFMA A/B frag
typedef __attribute__((ext_vector_type(4))) float f4v;   // MFMA C/D frag

#define B_    2
#define S_    64
#define R_    2048
#define D_    1024
#define H_    16
#define KVH_  4
#define LOG2_10K 13.287712379549449f

__device__ __forceinline__ u16 f2bf(float f) {
  union { float f; unsigned int i; } v; v.f = f;
  unsigned int x = v.i;
  return (u16)((x + 0x7FFFu + ((x >> 16) & 1u)) >> 16);
}

// ---------------------------------------------------------------------------
// Prep kernels (unchanged)
// ---------------------------------------------------------------------------
struct W6 { const float* w[6]; u16* o[6]; };

__global__ __launch_bounds__(256)
void transw_k(W6 ws, int C)
{
  __shared__ float t[32][33];
  const int c0 = blockIdx.x * 32, k0 = blockIdx.y * 32;
  const float* w = ws.w[blockIdx.z];
  u16* o = ws.o[blockIdx.z];
  const int x = threadIdx.x & 31, y = threadIdx.x >> 5;
  #pragma unroll
  for (int j = 0; j < 4; j++)
    t[y + 8 * j][x] = w[(size_t)(k0 + y + 8 * j) * C + c0 + x];
  __syncthreads();
  #pragma unroll
  for (int j = 0; j < 4; j++)
    o[(size_t)(c0 + y + 8 * j) * 1024 + k0 + x] = f2bf(t[x][y + 8 * j]);
}

__global__ __launch_bounds__(256)
void convx_k(const float* __restrict__ xa, const float* __restrict__ xb,
             u16* __restrict__ oa, u16* __restrict__ ob)
{
  int i = (blockIdx.x * 256 + threadIdx.x) * 8;
  const float* src; u16* dst; int off;
  if (i < 131072) { src = xa; dst = oa; off = i; }
  else            { src = xb; dst = ob; off = i - 131072; }
  float4 a = *(const float4*)(src + off);
  float4 b = *(const float4*)(src + off + 4);
  s8v r;
  r[0] = (short)f2bf(a.x); r[1] = (short)f2bf(a.y);
  r[2] = (short)f2bf(a.z); r[3] = (short)f2bf(a.w);
  r[4] = (short)f2bf(b.x); r[5] = (short)f2bf(b.y);
  r[6] = (short)f2bf(b.z); r[7] = (short)f2bf(b.w);
  *(s8v*)(dst + off) = r;
}

struct VJ { const u16* in; u16* out; int lb; };

__global__ __launch_bounds__(256)
void vtrans_k(VJ j0, VJ j1)
{
  VJ j = (blockIdx.z == 0) ? j0 : j1;
  const int p0 = blockIdx.x * 64;
  if (p0 >= j.lb) return;
  __shared__ u16 T[64][72];
  const int tid = threadIdx.x;
  const int bh = blockIdx.y;
  #pragma unroll
  for (int it = 0; it < 2; it++) {
    int idx = tid + it * 256;
    int p = idx >> 3, c = (idx & 7) * 8;
    *(s8v*)&T[p][c] = *(const s8v*)(j.in + ((size_t)bh * j.lb + p0 + p) * 64 + c);
  }
  __syncthreads();
  #pragma unroll
  for (int it = 0; it < 2; it++) {
    int idx = tid + it * 256;
    int d = idx >> 3, pc = (idx & 7) * 8;
    u16 tmp[8];
    #pragma unroll
    for (int q = 0; q < 8; q++) tmp[q] = T[pc + q][d];
    *(s8v*)(j.out + ((size_t)bh * 64 + d) * j.lb + p0 + pc) = *(s8v*)tmp;
  }
}

// ---------------------------------------------------------------------------
// Double-buffered GEMM core: 128x128 tile, BK=64, 16 K-steps, 4 waves.
// Register-staged prefetch of step k+1 issued BEFORE step k's MFMAs (T14);
// write-late into the alternate LDS buffer; ONE barrier per K-step.
// Adb/Bdb each hold two 128-row buffers: rows [0..127] and [128..255].
// acc D-frag: col = l15 (B-free), row = l4*4+reg.
// ---------------------------------------------------------------------------
__device__ __forceinline__ void gemm_core_db(
    const u16* __restrict__ Xrow, const u16* __restrict__ WTrow,
    u16 (*Adb)[72], u16 (*Bdb)[72], f4v (&acc)[4][4],
    int tid, int l15, int l4, int wro, int wco)
{
  s8v pa[4], pb[4];
  // prologue: stage K-step 0 into buffer 0
  #pragma unroll
  for (int it = 0; it < 4; it++) {
    int seg = tid + it * 256;
    int r = seg >> 3, sg = (seg & 7) * 8;
    pa[it] = *(const s8v*)(Xrow  + (size_t)r * 1024 + sg);
    pb[it] = *(const s8v*)(WTrow + (size_t)r * 1024 + sg);
  }
  #pragma unroll
  for (int it = 0; it < 4; it++) {
    int seg = tid + it * 256;
    int r = seg >> 3, sg = (seg & 7) * 8;
    *(s8v*)&Adb[r][sg] = pa[it];
    *(s8v*)&Bdb[r][sg] = pb[it];
  }
  __syncthreads();

  #pragma unroll 2
  for (int k = 0; k < 16; k++) {
    const int off = (k & 1) * 128;
    if (k + 1 < 16) {                          // issue next-step loads EARLY
      const int k0 = (k + 1) * 64;
      #pragma unroll
      for (int it = 0; it < 4; it++) {
        int seg = tid + it * 256;
        int r = seg >> 3, sg = (seg & 7) * 8;
        pa[it] = *(const s8v*)(Xrow  + (size_t)r * 1024 + k0 + sg);
        pb[it] = *(const s8v*)(WTrow + (size_t)r * 1024 + k0 + sg);
      }
    }
    // frags + MFMA on current buffer (hides the loads above)
    s8v af[4][2], bf4[4][2];
    #pragma unroll
    for (int rc = 0; rc < 4; rc++) {
      af[rc][0] = *(const s8v*)&Adb[off + wro + rc * 16 + l15][l4 * 8];
      af[rc][1] = *(const s8v*)&Adb[off + wro + rc * 16 + l15][32 + l4 * 8];
    }
    #pragma unroll
    for (int cc = 0; cc < 4; cc++) {
      bf4[cc][0] = *(const s8v*)&Bdb[off + wco + cc * 16 + l15][l4 * 8];
      bf4[cc][1] = *(const s8v*)&Bdb[off + wco + cc * 16 + l15][32 + l4 * 8];
    }
    #pragma unroll
    for (int rc = 0; rc < 4; rc++)
      #pragma unroll
      for (int cc = 0; cc < 4; cc++) {
        acc[rc][cc] = __builtin_amdgcn_mfma_f32_16x16x32_bf16(af[rc][0], bf4[cc][0], acc[rc][cc], 0, 0, 0);
        acc[rc][cc] = __builtin_amdgcn_mfma_f32_16x16x32_bf16(af[rc][1], bf4[cc][1], acc[rc][cc], 0, 0, 0);
      }
    if (k + 1 < 16) {                          // write-late into other buffer
      const int noff = ((k + 1) & 1) * 128;
      #pragma unroll
      for (int it = 0; it < 4; it++) {
        int seg = tid + it * 256;
        int r = seg >> 3, sg = (seg & 7) * 8;
        *(s8v*)&Adb[noff + r][sg] = pa[it];
        *(s8v*)&Bdb[noff + r][sg] = pb[it];
      }
    }
    __syncthreads();                           // one barrier per K-step
  }
}

// Wave epilogue -> LDS staging tile Es[128][136] (bf16 values, bias+RoPE applied).
// ropeMode: 0 = none, 1 = rope (rope2d picks table). sc: *0.125 after rope.
__device__ __forceinline__ void epi_to_lds(
    const f4v (&acc)[4][4], const float* __restrict__ Bp, u16* __restrict__ Es,
    int cbr, int wro, int wco, int grb, int LB,
    int ropeMode, bool rope2d, bool sc, int l15, int l4)
{
  float bv[4];
  #pragma unroll
  for (int cc = 0; cc < 4; cc++) bv[cc] = Bp[cbr + cc * 16 + l15];

  if (ropeMode == 0) {
    #pragma unroll
    for (int rc = 0; rc < 4; rc++)
      #pragma unroll
      for (int reg = 0; reg < 4; reg++) {
        int lrow = wro + rc * 16 + l4 * 4 + reg;
        #pragma unroll
        for (int cc = 0; cc < 4; cc++)
          Es[lrow * 136 + wco + cc * 16 + l15] = f2bf(acc[rc][cc][reg] + bv[cc]);
      }
  } else {
    float step = rope2d ? (LOG2_10K / 16.f) : (LOG2_10K / 32.f);
    float inv_lo = exp2f(-(float)l15 * step);
    float inv_hi = rope2d ? inv_lo : inv_lo * exp2f(-16.f * step);
    #pragma unroll
    for (int rc = 0; rc < 4; rc++)
      #pragma unroll
      for (int reg = 0; reg < 4; reg++) {
        int lrow = wro + rc * 16 + l4 * 4 + reg;
        int grow = grb + lrow;
        int pos = grow & (LB - 1);
        int bar = pos >> 5, tib = pos & 31;
        #pragma unroll
        for (int cc = 0; cc < 4; cc++) {
          float inv = (cc & 1) ? inv_hi : inv_lo;
          float bse = rope2d ? (float)((cc & 1) ? tib : bar) : (float)pos;
          float ang = bse * inv;
          float sn, cs;
          sincosf(ang, &sn, &cs);
          float v0 = acc[rc][cc][reg] + bv[cc];
          float v1 = acc[rc][cc ^ 2][reg] + bv[cc ^ 2];
          float rot = (cc < 2) ? -v1 : v1;
          float val = v0 * cs + rot * sn;
          if (sc) val *= 0.125f;
          Es[lrow * 136 + wco + cc * 16 + l15] = f2bf(val);
        }
      }
  }
}

// Cooperative full-line store: Es[128][136] -> head-split bf16 [b][NH][LB][64].
__device__ __forceinline__ void store_tile_bf16(
    const u16* __restrict__ Es, u16* __restrict__ out,
    int grb, int c0r, int NH, int LB, int LBS, int tid)
{
  #pragma unroll
  for (int it = 0; it < 8; it++) {
    int idx = it * 256 + tid;
    int r = idx >> 4, ch = idx & 15;
    int grow = grb + r;
    int b = grow >> LBS, pos = grow & (LB - 1);
    int cg = c0r + ch * 8;
    size_t base = (((size_t)b * NH + (cg >> 6)) * LB + pos) * 64 + (cg & 63);
    *(s8v*)(out + base) = *(const s8v*)(Es + r * 136 + ch * 8);
  }
}

// ---------------------------------------------------------------------------
// Fused QKV GEMM (summary + regular), XCD-swizzled. grid = 396 (12 x 33).
// ---------------------------------------------------------------------------
struct QkvA {
  const u16 *X, *WTs, *WTr;
  const float *b0s, *b1s, *b2s, *b0r, *b1r, *b2r;
  u16 *o0s, *o1s, *o2s, *o0r, *o1r, *o2r;
};

__global__ __launch_bounds__(256)
void qkv_k(QkvA a)
{
  // bijective XCD swizzle, nwg=396: q=49, rem=4
  int orig = blockIdx.x;
  int xcd = orig & 7, sidx = orig >> 3;
  int wg = (xcd < 4) ? (xcd * 50 + sidx) : (200 + (xcd - 4) * 49 + sidx);
  const int bx = wg % 12, by = wg / 12;
  const bool issum = (by == 0);
  const int c0 = bx * 128;

  __shared__ u16 Adb[256][72];
  __shared__ u16 Bdb[256][72];
  u16* Es = &Adb[0][0];                        // 34.8 KB alias inside Adb (36.9 KB)

  const int tid  = threadIdx.x;
  const int lane = tid & 63;
  const int w    = tid >> 6;
  const int l15  = lane & 15;
  const int l4   = lane >> 4;
  const int wro  = (w >> 1) * 64;
  const int wco  = (w & 1) * 64;

  f4v acc[4][4];
  #pragma unroll
  for (int i = 0; i < 4; i++)
    #pragma unroll
    for (int j = 0; j < 4; j++) acc[i][j] = (f4v){0.f, 0.f, 0.f, 0.f};

  const u16* Xrow  = a.X + (size_t)by * 128 * 1024;
  const u16* WTrow = (issum ? a.WTs : a.WTr) + (size_t)c0 * 1024;
  gemm_core_db(Xrow, WTrow, Adb, Bdb, acc, tid, l15, l4, wro, wco);

  const int LB  = issum ? 64 : 2048;
  const int LBS = issum ? 6 : 11;
  const int grb = issum ? 0 : (by - 1) * 128;

  const float* Bp; u16* Outp; int NH, rs, ropeMode; bool sc;
  if (c0 < 1024)      { Bp = issum ? a.b0s : a.b0r; Outp = issum ? a.o0s : a.o0r; NH = 16; rs = 0;    ropeMode = 1; sc = true;  }
  else if (c0 < 1280) { Bp = issum ? a.b1s : a.b1r; Outp = issum ? a.o1s : a.o1r; NH = 4;  rs = 1024; ropeMode = 1; sc = false; }
  else                { Bp = issum ? a.b2s : a.b2r; Outp = issum ? a.o2s : a.o2r; NH = 4;  rs = 1280; ropeMode = 0; sc = false; }

  epi_to_lds(acc, Bp, Es, c0 - rs + wco, wro, wco, grb, LB, ropeMode, !issum, sc, l15, l4);
  __syncthreads();
  store_tile_bf16(Es, Outp, grb, c0 - rs, NH, LB, LBS, tid);
}

// ---------------------------------------------------------------------------
// Phase-1 output GEMM: k2 / v2 (bf16, Es path) + so (fp32 direct). grid = 12.
// ---------------------------------------------------------------------------
__global__ __launch_bounds__(256)
void gemm_p1_k(const u16* __restrict__ X, const u16* __restrict__ WT,
               const float* __restrict__ bk2, const float* __restrict__ bv2,
               const float* __restrict__ bso,
               u16* __restrict__ k2, u16* __restrict__ v2, float* __restrict__ outsum)
{
  const int c0 = blockIdx.x * 128;

  __shared__ u16 Adb[256][72];
  __shared__ u16 Bdb[256][72];
  u16* Es = &Adb[0][0];

  const int tid  = threadIdx.x;
  const int lane = tid & 63;
  const int w    = tid >> 6;
  const int l15  = lane & 15;
  const int l4   = lane >> 4;
  const int wro  = (w >> 1) * 64;
  const int wco  = (w & 1) * 64;

  f4v acc[4][4];
  #pragma unroll
  for (int i = 0; i < 4; i++)
    #pragma unroll
    for (int j = 0; j < 4; j++) acc[i][j] = (f4v){0.f, 0.f, 0.f, 0.f};

  gemm_core_db(X, WT + (size_t)c0 * 1024, Adb, Bdb, acc, tid, l15, l4, wro, wco);

  if (c0 < 512) {
    const float* Bp = (c0 < 256) ? bk2 : bv2;
    u16* Outp = (c0 < 256) ? k2 : v2;
    int rs = (c0 < 256) ? 0 : 256;
    epi_to_lds(acc, Bp, Es, c0 - rs + wco, wro, wco, 0, 64, 0, false, false, l15, l4);
    __syncthreads();
    store_tile_bf16(Es, Outp, 0, c0 - rs, 4, 64, 6, tid);
  } else {
    float bv[4];
    #pragma unroll
    for (int cc = 0; cc < 4; cc++) bv[cc] = bso[c0 - 512 + wco + cc * 16 + l15];
    #pragma unroll
    for (int rc = 0; rc < 4; rc++)
      #pragma unroll
      for (int reg = 0; reg < 4; reg++) {
        int row = wro + rc * 16 + l4 * 4 + reg;
        #pragma unroll
        for (int cc = 0; cc < 4; cc++)
          outsum[(size_t)row * 1024 + c0 - 512 + wco + cc * 16 + l15] = acc[rc][cc][reg] + bv[cc];
      }
  }
}

// ---------------------------------------------------------------------------
// ro GEMM: rattn[4096][1024] @ wt_ro -> out_reg fp32. grid = 256, XCD-swizzled.
// ---------------------------------------------------------------------------
__global__ __launch_bounds__(256)
void gemm_ro_k(const u16* __restrict__ X, const u16* __restrict__ WT,
               const float* __restrict__ Bp, float* __restrict__ out)
{
  int orig = blockIdx.x;
  int wg = (orig & 7) * 32 + (orig >> 3);        // 256 = 8*32 exact
  const int bx = wg & 7, by = wg >> 3;
  const int c0 = bx * 128, r0 = by * 128;

  __shared__ u16 Adb[256][72];
  __shared__ u16 Bdb[256][72];

  const int tid  = threadIdx.x;
  const int lane = tid & 63;
  const int w    = tid >> 6;
  const int l15  = lane & 15;
  const int l4   = lane >> 4;
  const int wro  = (w >> 1) * 64;
  const int wco  = (w & 1) * 64;

  f4v acc[4][4];
  #pragma unroll
  for (int i = 0; i < 4; i++)
    #pragma unroll
    for (int j = 0; j < 4; j++) acc[i][j] = (f4v){0.f, 0.f, 0.f, 0.f};

  gemm_core_db(X + (size_t)r0 * 1024, WT + (size_t)c0 * 1024, Adb, Bdb, acc,
               tid, l15, l4, wro, wco);

  float bv[4];
  #pragma unroll
  for (int cc = 0; cc < 4; cc++) bv[cc] = Bp[c0 + wco + cc * 16 + l15];
  #pragma unroll
  for (int rc = 0; rc < 4; rc++)
    #pragma unroll
    for (int reg = 0; reg < 4; reg++) {
      int row = r0 + wro + rc * 16 + l4 * 4 + reg;
      #pragma unroll
      for (int cc = 0; cc < 4; cc++)
        out[(size_t)row * 1024 + c0 + wco + cc * 16 + l15] = acc[rc][cc][reg] + bv[cc];
    }
}

// ---------------------------------------------------------------------------
// Shared flash-attention tile compute (unchanged).
// ---------------------------------------------------------------------------
template<int PHASE>
__device__ __forceinline__ void attn_tile(
    const u16 (&Kc)[64][72], const u16 (&Vc)[64][72], u16 (&Ptw)[16][72],
    const s8v& qf0, const s8v& qf1, f4v (&acc)[4],
    float (&m)[4], float (&lsum)[4],
    int kbase, int qw, int l15, int l4)
{
  f4v s[4];
  #pragma unroll
  for (int n = 0; n < 4; n++) {
    s8v kf0 = *(const s8v*)&Kc[n * 16 + l15][l4 * 8];
    s8v kf1 = *(const s8v*)&Kc[n * 16 + l15][32 + l4 * 8];
    f4v t = {0.f, 0.f, 0.f, 0.f};
    t = __builtin_amdgcn_mfma_f32_16x16x32_bf16(qf0, kf0, t, 0, 0, 0);
    t = __builtin_amdgcn_mfma_f32_16x16x32_bf16(qf1, kf1, t, 0, 0, 0);
    s[n] = t;
  }

  bool need_mask = (kbase == 0) ||
    (PHASE == 1 ? (((kbase - 1) >> 5) > qw) : ((kbase - 1) > qw));
  float v4[4] = {-1e30f, -1e30f, -1e30f, -1e30f};
  if (need_mask) {
    #pragma unroll
    for (int n = 0; n < 4; n++) {
      int kidx = kbase + n * 16 + l15;
      #pragma unroll
      for (int r = 0; r < 4; r++) {
        int qrow = qw + l4 * 4 + r;
        bool ok;
        if (kbase == 0) ok = kidx <= ((PHASE == 1) ? qrow : (qrow >> 5));
        else { int kr = kidx - 64; ok = (PHASE == 1) ? ((kr >> 5) <= qrow) : (kr <= qrow); }
        float sv = ok ? s[n][r] : -1e30f;
        s[n][r] = sv;
        v4[r] = fmaxf(v4[r], sv);
      }
    }
  } else {
    #pragma unroll
    for (int n = 0; n < 4; n++)
      #pragma unroll
      for (int r = 0; r < 4; r++) v4[r] = fmaxf(v4[r], s[n][r]);
  }
  #pragma unroll
  for (int r = 0; r < 4; r++) {
    float v = v4[r];
    v = fmaxf(v, __shfl_xor(v, 1));
    v = fmaxf(v, __shfl_xor(v, 2));
    v = fmaxf(v, __shfl_xor(v, 4));
    v = fmaxf(v, __shfl_xor(v, 8));
    v4[r] = v;
  }
  bool up = (v4[0] > m[0]) || (v4[1] > m[1]) || (v4[2] > m[2]) || (v4[3] > m[3]);
  if (__any(up)) {
    #pragma unroll
    for (int r = 0; r < 4; r++) {
      float mn = fmaxf(m[r], v4[r]);
      float f  = __expf(m[r] - mn);
      m[r] = mn;
      lsum[r] *= f;
      #pragma unroll
      for (int dt = 0; dt < 4; dt++) acc[dt][r] *= f;
    }
  }
  float rs[4] = {0.f, 0.f, 0.f, 0.f};
  #pragma unroll
  for (int n = 0; n < 4; n++) {
    #pragma unroll
    for (int r = 0; r < 4; r++) {
      float p = __expf(s[n][r] - m[r]);
      Ptw[l4 * 4 + r][n * 16 + l15] = f2bf(p);
      rs[r] += p;
    }
  }
  #pragma unroll
  for (int r = 0; r < 4; r++) {
    float v = rs[r];
    v += __shfl_xor(v, 1); v += __shfl_xor(v, 2);
    v += __shfl_xor(v, 4); v += __shfl_xor(v, 8);
    lsum[r] += v;
  }

  asm volatile("s_waitcnt lgkmcnt(0)" ::: "memory");

  s8v pf0 = *(const s8v*)&Ptw[l15][l4 * 8];
  s8v pf1 = *(const s8v*)&Ptw[l15][32 + l4 * 8];
  #pragma unroll
  for (int dt = 0; dt < 4; dt++) {
    s8v vf0 = *(const s8v*)&Vc[dt * 16 + l15][l4 * 8];
    s8v vf1 = *(const s8v*)&Vc[dt * 16 + l15][32 + l4 * 8];
    acc[dt] = __builtin_amdgcn_mfma_f32_16x16x32_bf16(pf0, vf0, acc[dt], 0, 0, 0);
    acc[dt] = __builtin_amdgcn_mfma_f32_16x16x32_bf16(pf1, vf1, acc[dt], 0, 0, 0);
  }
}

// ---------------------------------------------------------------------------
// Phase 2 attention (unchanged from round 10).
// ---------------------------------------------------------------------------
__global__ __launch_bounds__(512)
void attn2_k(const u16* __restrict__ Q, const u16* __restrict__ KS,
             const u16* __restrict__ KR, const u16* __restrict__ VST,
             const u16* __restrict__ VRT, u16* __restrict__ Out)
{
  const int gid = blockIdx.x;
  const int qb  = (gid & 256) ? (15 - (gid & 15)) : (gid & 15);
  const int bh  = gid >> 4;
  const int h   = bh & 15, b = bh >> 4;
  const int q0  = qb * 128;
  const int kh  = h >> 2;

  __shared__ u16 Kt[2][64][72];
  __shared__ u16 Vt[2][64][72];
  __shared__ u16 Pt[8][16][72];

  const int tid = threadIdx.x, lane = tid & 63, w = tid >> 6;
  const int l15 = lane & 15, l4 = lane >> 4;
  const int qw  = q0 + w * 16;

  const u16* qp = Q + (((size_t)b * H_ + h) * R_ + qw + l15) * 64;
  s8v qf0 = *(const s8v*)(qp + l4 * 8);
  s8v qf1 = *(const s8v*)(qp + 32 + l4 * 8);

  f4v acc[4];
  #pragma unroll
  for (int dt = 0; dt < 4; dt++) acc[dt] = (f4v){0.f, 0.f, 0.f, 0.f};
  float m[4]    = {-1e30f, -1e30f, -1e30f, -1e30f};
  float lsum[4] = {0.f, 0.f, 0.f, 0.f};

  const int ntiles = (64 + q0 + 128) >> 6;
  const size_t bh_kv = (size_t)b * KVH_ + kh;

  const int r_ = tid >> 3, sg_ = (tid & 7) * 8;

  {
    const u16* kp = KS  + bh_kv * 4096;
    const u16* vp = VST + bh_kv * 4096;
    s8v k0 = *(const s8v*)(kp + r_ * 64 + sg_);
    s8v v0 = *(const s8v*)(vp + r_ * 64 + sg_);
    *(s8v*)&Kt[0][r_][sg_] = k0;
    *(s8v*)&Vt[0][r_][sg_] = v0;
  }
  __syncthreads();

  for (int kt = 0; kt < ntiles; kt++) {
    const int cur = kt & 1;
    const int kbase = kt * 64;
    const bool pre = (kt + 1 < ntiles);
    s8v knx, vnx;
    if (pre) {
      const int nb = kbase;
      const u16* kp = KR  + (bh_kv * R_ + nb) * 64;
      const u16* vp = VRT + bh_kv * 64 * R_ + nb;
      knx = *(const s8v*)(kp + r_ * 64 + sg_);
      vnx = *(const s8v*)(vp + (size_t)r_ * R_ + sg_);
    }

    const bool active = (kbase == 0) || (kbase - 64 <= qw + 15);
    if (active)
      attn_tile<2>(Kt[cur], Vt[cur], Pt[w], qf0, qf1, acc, m, lsum,
                   kbase, qw, l15, l4);

    if (pre) {
      *(s8v*)&Kt[cur ^ 1][r_][sg_] = knx;
      *(s8v*)&Vt[cur ^ 1][r_][sg_] = vnx;
    }
    __syncthreads();
  }

  #pragma unroll
  for (int r = 0; r < 4; r++) {
    float linv = 1.f / lsum[r];
    #pragma unroll
    for (int dt = 0; dt < 4; dt++)
      Pt[w][l4 * 4 + r][dt * 16 + l15] = f2bf(acc[dt][r] * linv);
  }
  asm volatile("s_waitcnt lgkmcnt(0)" ::: "memory");
  {
    int rl = lane >> 3, ch = lane & 7;
    #pragma unroll
    for (int rr = 0; rr < 2; rr++) {
      int row = rr * 8 + rl;
      u16* o = Out + ((size_t)b * R_ + qw + row) * D_ + h * 64 + ch * 8;
      *(s8v*)o = *(const s8v*)&Pt[w][row][ch * 8];
    }
  }
}

// ---------------------------------------------------------------------------
// Phase 1 attention, split-K (unchanged).
// ---------------------------------------------------------------------------
__global__ __launch_bounds__(256)
void attn1_k(const u16* __restrict__ Q, const u16* __restrict__ KS,
             const u16* __restrict__ KR, const u16* __restrict__ VST,
             const u16* __restrict__ VRT,
             float* __restrict__ pO, float* __restrict__ pml)
{
  const int gid = blockIdx.x;
  const int ck  = gid & 7;
  const int bh  = gid >> 3;
  const int h   = bh & 15, b = bh >> 4;
  const int kh  = h >> 2;
  const int kt0 = (ck * 33) >> 3;
  const int kt1 = ((ck + 1) * 33) >> 3;

  __shared__ u16 Kt[2][64][72];
  __shared__ u16 Vt[2][64][72];
  __shared__ u16 Pt[4][16][72];

  const int tid = threadIdx.x, lane = tid & 63, w = tid >> 6;
  const int l15 = lane & 15, l4 = lane >> 4;
  const int qw  = w * 16;

  const u16* qp = Q + (((size_t)b * H_ + h) * S_ + qw + l15) * 64;
  s8v qf0 = *(const s8v*)(qp + l4 * 8);
  s8v qf1 = *(const s8v*)(qp + 32 + l4 * 8);

  f4v acc[4];
  #pragma unroll
  for (int dt = 0; dt < 4; dt++) acc[dt] = (f4v){0.f, 0.f, 0.f, 0.f};
  float m[4]    = {-1e30f, -1e30f, -1e30f, -1e30f};
  float lsum[4] = {0.f, 0.f, 0.f, 0.f};

  const size_t bh_kv = (size_t)b * KVH_ + kh;
  const int r_ = tid >> 3, sg_ = (tid & 7) * 8;

  {
    const u16 *kp, *vp; int vstr;
    if (kt0 == 0) { kp = KS + bh_kv * 4096; vp = VST + bh_kv * 4096; vstr = 64; }
    else {
      kp = KR  + (bh_kv * R_ + kt0 * 64 - 64) * 64;
      vp = VRT + bh_kv * 64 * R_ + (kt0 * 64 - 64);
      vstr = R_;
    }
    s8v ka0 = *(const s8v*)(kp + r_ * 64 + sg_);
    s8v ka1 = *(const s8v*)(kp + (r_ + 32) * 64 + sg_);
    s8v va0 = *(const s8v*)(vp + (size_t)r_ * vstr + sg_);
    s8v va1 = *(const s8v*)(vp + (size_t)(r_ + 32) * vstr + sg_);
    *(s8v*)&Kt[0][r_][sg_]      = ka0;
    *(s8v*)&Kt[0][r_ + 32][sg_] = ka1;
    *(s8v*)&Vt[0][r_][sg_]      = va0;
    *(s8v*)&Vt[0][r_ + 32][sg_] = va1;
  }
  __syncthreads();

  for (int kt = kt0; kt < kt1; kt++) {
    const int cur = (kt - kt0) & 1;
    const int kbase = kt * 64;
    const bool pre = (kt + 1 < kt1);
    s8v ka0, ka1, va0, va1;
    if (pre) {
      const u16* kp = KR  + (bh_kv * R_ + kbase) * 64;
      const u16* vp = VRT + bh_kv * 64 * R_ + kbase;
      ka0 = *(const s8v*)(kp + r_ * 64 + sg_);
      ka1 = *(const s8v*)(kp + (r_ + 32) * 64 + sg_);
      va0 = *(const s8v*)(vp + (size_t)r_ * R_ + sg_);
      va1 = *(const s8v*)(vp + (size_t)(r_ + 32) * R_ + sg_);
    }

    const bool active = (kbase == 0) || (((kbase - 64) >> 5) <= qw + 15);
    if (active)
      attn_tile<1>(Kt[cur], Vt[cur], Pt[w], qf0, qf1, acc, m, lsum,
                   kbase, qw, l15, l4);

    if (pre) {
      *(s8v*)&Kt[cur ^ 1][r_][sg_]      = ka0;
      *(s8v*)&Kt[cur ^ 1][r_ + 32][sg_] = ka1;
      *(s8v*)&Vt[cur ^ 1][r_][sg_]      = va0;
      *(s8v*)&Vt[cur ^ 1][r_ + 32][sg_] = va1;
    }
    __syncthreads();
  }

  #pragma unroll
  for (int r = 0; r < 4; r++) {
    int qrow = qw + l4 * 4 + r;
    float* po = pO + (((size_t)ck * 32 + bh) * 64 + qrow) * 64;
    #pragma unroll
    for (int dt = 0; dt < 4; dt++) po[dt * 16 + l15] = acc[dt][r];
    if (l15 == 0) {
      float* pm = pml + (((size_t)ck * 32 + bh) * 64 + qrow) * 2;
      pm[0] = m[r]; pm[1] = lsum[r];
    }
  }
}

// Combine 8 phase-1 partials -> sattn bf16 (vectorized 16B stores)
__global__ __launch_bounds__(256)
void comb1_k(const float* __restrict__ pO, const float* __restrict__ pml,
             u16* __restrict__ sattn)
{
  const int bh = blockIdx.x;
  const int b = bh >> 4, h = bh & 15;
  const int q  = threadIdx.x >> 2;
  const int d0 = (threadIdx.x & 3) * 16;
  float mv[8], lv[8], mstar = -1e30f;
  #pragma unroll
  for (int c = 0; c < 8; c++) {
    const float* p = pml + (((size_t)c * 32 + bh) * 64 + q) * 2;
    mv[c] = p[0]; lv[c] = p[1];
    mstar = fmaxf(mstar, mv[c]);
  }
  float o[16];
  #pragma unroll
  for (int j = 0; j < 16; j++) o[j] = 0.f;
  float lsum = 0.f;
  #pragma unroll
  for (int c = 0; c < 8; c++) {
    float wgt = __expf(mv[c] - mstar);
    lsum += lv[c] * wgt;
    const float* po = pO + (((size_t)c * 32 + bh) * 64 + q) * 64 + d0;
    #pragma unroll
    for (int j = 0; j < 16; j++) o[j] += po[j] * wgt;
  }
  float inv = 1.f / lsum;
  u16 ob[16];
  #pragma unroll
  for (int j = 0; j < 16; j++) ob[j] = f2bf(o[j] * inv);
  u16* out = sattn + ((size_t)(b * 64 + q)) * 1024 + h * 64 + d0;
  *(s8v*)out       = *(s8v*)&ob[0];
  *(s8v*)(out + 8) = *(s8v*)&ob[8];
}

extern "C" void kernel_launch(void* const* d_in, const int* in_sizes, int n_in,
                              void* d_out, int out_size, void* d_ws, size_t ws_size,
                              hipStream_t stream)
{
  (void)out_size; (void)ws_size;

  static const int expect[22] = {
    131072, 4194304,
    1048576, 1024, 262144, 256,
    262144, 256, 1048576, 1024,
    1048576, 1024, 262144, 256,
    262144, 256, 1048576, 1024,
    262144, 256, 262144, 256
  };
  if (n_in < 22) return;
  for (int i = 0; i < 22; i++) if (in_sizes[i] != expect[i]) return;

  const float* sum_x = (const float*)d_in[0];
  const float* reg_x = (const float*)d_in[1];
  const float* w_sq = (const float*)d_in[2];  const float* b_sq = (const float*)d_in[3];
  const float* w_sk = (const float*)d_in[4];  const float* b_sk = (const float*)d_in[5];
  const float* w_sv = (const float*)d_in[6];  const float* b_sv = (const float*)d_in[7];
  const float* w_so = (const float*)d_in[8];  const float* b_so = (const float*)d_in[9];
  const float* w_rq = (const float*)d_in[10]; const float* b_rq = (const float*)d_in[11];
  const float* w_rk = (const float*)d_in[12]; const float* b_rk = (const float*)d_in[13];
  const float* w_rv = (const float*)d_in[14]; const float* b_rv = (const float*)d_in[15];
  const float* w_ro = (const float*)d_in[16]; const float* b_ro = (const float*)d_in[17];
  const float* w_k2 = (const float*)d_in[18]; const float* b_k2 = (const float*)d_in[19];
  const float* w_v2 = (const float*)d_in[20]; const float* b_v2 = (const float*)d_in[21];

  u16* ws    = (u16*)d_ws;
  u16* xs_bf = ws;                    // 131072
  u16* xr_bf = xs_bf + 131072;        // 4194304
  u16* wt_s  = xr_bf + 4194304;       // 1572864  [sq|sk|sv] (dead after QKV -> V^T)
  u16* wt_r  = wt_s  + 1572864;       // 1572864  [rq|rk|rv]
  u16* wt_p  = wt_r  + 1572864;       // 1572864  [k2|v2|so]
  u16* wt_ro = wt_p  + 1572864;       // 1048576
  u16* sq    = wt_ro + 1048576;       // 131072
  u16* sk    = sq    + 131072;        // 32768
  u16* sv    = sk    + 32768;         // 32768
  u16* rq    = sv    + 32768;         // 4194304
  u16* rk    = rq    + 4194304;       // 1048576
  u16* rv    = rk    + 1048576;       // 1048576
  u16* sattn = rv    + 1048576;       // 131072
  u16* k2    = sattn + 131072;        // 32768
  u16* v2    = k2    + 32768;         // 32768
  u16* rattn = v2    + 32768;         // 4194304

  u16* rvT = wt_s;
  u16* svT = wt_s + 1048576;
  u16* v2T = wt_s + 1081344;

  float* pO  = (float*)rattn;
  float* pml = pO + 1048576;

  float* out_sum = (float*)d_out;
  float* out_reg = out_sum + 131072;

  dim3 blk(256);

  W6 big;
  big.w[0] = w_sq; big.o[0] = wt_s;
  big.w[1] = w_rq; big.o[1] = wt_r;
  big.w[2] = w_so; big.o[2] = wt_p + 512 * 1024;
  big.w[3] = w_ro; big.o[3] = wt_ro;
  big.w[4] = w_sq; big.o[4] = wt_s;
  big.w[5] = w_sq; big.o[5] = wt_s;
  W6 small;
  small.w[0] = w_sk; small.o[0] = wt_s + 1024 * 1024;
  small.w[1] = w_sv; small.o[1] = wt_s + 1280 * 1024;
  small.w[2] = w_rk; small.o[2] = wt_r + 1024 * 1024;
  small.w[3] = w_rv; small.o[3] = wt_r + 1280 * 1024;
  small.w[4] = w_k2; small.o[4] = wt_p;
  small.w[5] = w_v2; small.o[5] = wt_p + 256 * 1024;
  transw_k<<<dim3(32, 32, 4), blk, 0, stream>>>(big, 1024);
  transw_k<<<dim3(8, 32, 6),  blk, 0, stream>>>(small, 256);
  convx_k<<<dim3(2112), blk, 0, stream>>>(sum_x, reg_x, xs_bf, xr_bf);

  QkvA qa;
  qa.X = xs_bf; qa.WTs = wt_s; qa.WTr = wt_r;
  qa.b0s = b_sq; qa.b1s = b_sk; qa.b2s = b_sv;
  qa.b0r = b_rq; qa.b1r = b_rk; qa.b2r = b_rv;
  qa.o0s = sq; qa.o1s = sk; qa.o2s = sv;
  qa.o0r = rq; qa.o1r = rk; qa.o2r = rv;
  qkv_k<<<dim3(396), blk, 0, stream>>>(qa);

  VJ jrv = {rv, rvT, 2048};
  VJ jsv = {sv, svT, 64};
  vtrans_k<<<dim3(32, 8, 2), blk, 0, stream>>>(jrv, jsv);

  attn1_k<<<dim3(256), blk, 0, stream>>>(sq, sk, rk, svT, rvT, pO, pml);
  comb1_k<<<dim3(32), blk, 0, stream>>>(pO, pml, sattn);

  gemm_p1_k<<<dim3(12), blk, 0, stream>>>(sattn, wt_p, b_k2, b_v2, b_so, k2, v2, out_sum);
  VJ jv2 = {v2, v2T, 64};
  vtrans_k<<<dim3(1, 8, 1), blk, 0, stream>>>(jv2, jv2);

  attn2_k<<<dim3(512), dim3(512), 0, stream>>>(rq, k2, rk, v2T, rvT, rattn);

  gemm_ro_k<<<dim3(256), blk, 0, stream>>>(rattn, wt_ro, b_ro, out_reg);
}

// Round 12
// 164.491 us; speedup vs baseline: 15.7502x; 1.3799x over previous
//
#include <hip/hip_runtime.h>

typedef unsigned short u16;
typedef __attribute__((ext_vector_type(8))) short s8v;   // 8 x bf16 MFMA A/B frag
typedef __attribute__((ext_vector_type(4))) float f4v;   // MFMA C/D frag

#define B_    2
#define S_    64
#define R_    2048
#define D_    1024
#define H_    16
#define KVH_  4
#define LOG2_10K 13.287712379549449f

__device__ __forceinline__ u16 f2bf(float f) {
  union { float f; unsigned int i; } v; v.f = f;
  unsigned int x = v.i;
  return (u16)((x + 0x7FFFu + ((x >> 16) & 1u)) >> 16);
}

// ---------------------------------------------------------------------------
// Prep kernels (unchanged)
// ---------------------------------------------------------------------------
struct W6 { const float* w[6]; u16* o[6]; };

__global__ __launch_bounds__(256)
void transw_k(W6 ws, int C)
{
  __shared__ float t[32][33];
  const int c0 = blockIdx.x * 32, k0 = blockIdx.y * 32;
  const float* w = ws.w[blockIdx.z];
  u16* o = ws.o[blockIdx.z];
  const int x = threadIdx.x & 31, y = threadIdx.x >> 5;
  #pragma unroll
  for (int j = 0; j < 4; j++)
    t[y + 8 * j][x] = w[(size_t)(k0 + y + 8 * j) * C + c0 + x];
  __syncthreads();
  #pragma unroll
  for (int j = 0; j < 4; j++)
    o[(size_t)(c0 + y + 8 * j) * 1024 + k0 + x] = f2bf(t[x][y + 8 * j]);
}

__global__ __launch_bounds__(256)
void convx_k(const float* __restrict__ xa, const float* __restrict__ xb,
             u16* __restrict__ oa, u16* __restrict__ ob)
{
  int i = (blockIdx.x * 256 + threadIdx.x) * 8;
  const float* src; u16* dst; int off;
  if (i < 131072) { src = xa; dst = oa; off = i; }
  else            { src = xb; dst = ob; off = i - 131072; }
  float4 a = *(const float4*)(src + off);
  float4 b = *(const float4*)(src + off + 4);
  s8v r;
  r[0] = (short)f2bf(a.x); r[1] = (short)f2bf(a.y);
  r[2] = (short)f2bf(a.z); r[3] = (short)f2bf(a.w);
  r[4] = (short)f2bf(b.x); r[5] = (short)f2bf(b.y);
  r[6] = (short)f2bf(b.z); r[7] = (short)f2bf(b.w);
  *(s8v*)(dst + off) = r;
}

struct VJ { const u16* in; u16* out; int lb; };

__global__ __launch_bounds__(256)
void vtrans_k(VJ j0, VJ j1)
{
  VJ j = (blockIdx.z == 0) ? j0 : j1;
  const int p0 = blockIdx.x * 64;
  if (p0 >= j.lb) return;
  __shared__ u16 T[64][72];
  const int tid = threadIdx.x;
  const int bh = blockIdx.y;
  #pragma unroll
  for (int it = 0; it < 2; it++) {
    int idx = tid + it * 256;
    int p = idx >> 3, c = (idx & 7) * 8;
    *(s8v*)&T[p][c] = *(const s8v*)(j.in + ((size_t)bh * j.lb + p0 + p) * 64 + c);
  }
  __syncthreads();
  #pragma unroll
  for (int it = 0; it < 2; it++) {
    int idx = tid + it * 256;
    int d = idx >> 3, pc = (idx & 7) * 8;
    u16 tmp[8];
    #pragma unroll
    for (int q = 0; q < 8; q++) tmp[q] = T[pc + q][d];
    *(s8v*)(j.out + ((size_t)bh * 64 + d) * j.lb + p0 + pc) = *(s8v*)tmp;
  }
}

// ---------------------------------------------------------------------------
// Double-buffered GEMM core, 512 threads = 8 waves (4 row-bands x 2 col-bands;
// wave = 32 rows x 64 cols, acc[2][4]). 128x128 tile, BK=64, 16 K-steps.
// Register-staged prefetch (T14), write-late, one barrier per K-step.
// ---------------------------------------------------------------------------
__device__ __forceinline__ void gemm_core_db(
    const u16* __restrict__ Xrow, const u16* __restrict__ WTrow,
    u16 (*Adb)[72], u16 (*Bdb)[72], f4v (&acc)[2][4],
    int tid, int l15, int l4, int wro, int wco)
{
  s8v pa[2], pb[2];
  #pragma unroll
  for (int it = 0; it < 2; it++) {
    int seg = tid + it * 512;
    int r = seg >> 3, sg = (seg & 7) * 8;
    pa[it] = *(const s8v*)(Xrow  + (size_t)r * 1024 + sg);
    pb[it] = *(const s8v*)(WTrow + (size_t)r * 1024 + sg);
  }
  #pragma unroll
  for (int it = 0; it < 2; it++) {
    int seg = tid + it * 512;
    int r = seg >> 3, sg = (seg & 7) * 8;
    *(s8v*)&Adb[r][sg] = pa[it];
    *(s8v*)&Bdb[r][sg] = pb[it];
  }
  __syncthreads();

  #pragma unroll 2
  for (int k = 0; k < 16; k++) {
    const int off = (k & 1) * 128;
    if (k + 1 < 16) {                          // issue next-step loads EARLY
      const int k0 = (k + 1) * 64;
      #pragma unroll
      for (int it = 0; it < 2; it++) {
        int seg = tid + it * 512;
        int r = seg >> 3, sg = (seg & 7) * 8;
        pa[it] = *(const s8v*)(Xrow  + (size_t)r * 1024 + k0 + sg);
        pb[it] = *(const s8v*)(WTrow + (size_t)r * 1024 + k0 + sg);
      }
    }
    s8v af[2][2], bf4[4][2];
    #pragma unroll
    for (int rc = 0; rc < 2; rc++) {
      af[rc][0] = *(const s8v*)&Adb[off + wro + rc * 16 + l15][l4 * 8];
      af[rc][1] = *(const s8v*)&Adb[off + wro + rc * 16 + l15][32 + l4 * 8];
    }
    #pragma unroll
    for (int cc = 0; cc < 4; cc++) {
      bf4[cc][0] = *(const s8v*)&Bdb[off + wco + cc * 16 + l15][l4 * 8];
      bf4[cc][1] = *(const s8v*)&Bdb[off + wco + cc * 16 + l15][32 + l4 * 8];
    }
    #pragma unroll
    for (int rc = 0; rc < 2; rc++)
      #pragma unroll
      for (int cc = 0; cc < 4; cc++) {
        acc[rc][cc] = __builtin_amdgcn_mfma_f32_16x16x32_bf16(af[rc][0], bf4[cc][0], acc[rc][cc], 0, 0, 0);
        acc[rc][cc] = __builtin_amdgcn_mfma_f32_16x16x32_bf16(af[rc][1], bf4[cc][1], acc[rc][cc], 0, 0, 0);
      }
    if (k + 1 < 16) {                          // write-late into other buffer
      const int noff = ((k + 1) & 1) * 128;
      #pragma unroll
      for (int it = 0; it < 2; it++) {
        int seg = tid + it * 512;
        int r = seg >> 3, sg = (seg & 7) * 8;
        *(s8v*)&Adb[noff + r][sg] = pa[it];
        *(s8v*)&Bdb[noff + r][sg] = pb[it];
      }
    }
    __syncthreads();
  }
}

// Wave epilogue -> LDS staging tile Es[128][136] (bf16, bias+RoPE applied).
// Wave spans 32 rows x 64 cols; 64-col span keeps RoPE partner (cc^2) in-wave.
__device__ __forceinline__ void epi_to_lds(
    const f4v (&acc)[2][4], const float* __restrict__ Bp, u16* __restrict__ Es,
    int cbr, int wro, int wco, int grb, int LB,
    int ropeMode, bool rope2d, bool sc, int l15, int l4)
{
  float bv[4];
  #pragma unroll
  for (int cc = 0; cc < 4; cc++) bv[cc] = Bp[cbr + cc * 16 + l15];

  if (ropeMode == 0) {
    #pragma unroll
    for (int rc = 0; rc < 2; rc++)
      #pragma unroll
      for (int reg = 0; reg < 4; reg++) {
        int lrow = wro + rc * 16 + l4 * 4 + reg;
        #pragma unroll
        for (int cc = 0; cc < 4; cc++)
          Es[lrow * 136 + wco + cc * 16 + l15] = f2bf(acc[rc][cc][reg] + bv[cc]);
      }
  } else {
    float step = rope2d ? (LOG2_10K / 16.f) : (LOG2_10K / 32.f);
    float inv_lo = exp2f(-(float)l15 * step);
    float inv_hi = rope2d ? inv_lo : inv_lo * exp2f(-16.f * step);
    #pragma unroll
    for (int rc = 0; rc < 2; rc++)
      #pragma unroll
      for (int reg = 0; reg < 4; reg++) {
        int lrow = wro + rc * 16 + l4 * 4 + reg;
        int grow = grb + lrow;
        int pos = grow & (LB - 1);
        int bar = pos >> 5, tib = pos & 31;
        #pragma unroll
        for (int cc = 0; cc < 4; cc++) {
          float inv = (cc & 1) ? inv_hi : inv_lo;
          float bse = rope2d ? (float)((cc & 1) ? tib : bar) : (float)pos;
          float ang = bse * inv;
          float sn, cs;
          sincosf(ang, &sn, &cs);
          float v0 = acc[rc][cc][reg] + bv[cc];
          float v1 = acc[rc][cc ^ 2][reg] + bv[cc ^ 2];
          float rot = (cc < 2) ? -v1 : v1;
          float val = v0 * cs + rot * sn;
          if (sc) val *= 0.125f;
          Es[lrow * 136 + wco + cc * 16 + l15] = f2bf(val);
        }
      }
  }
}

// Cooperative full-line store: Es[128][136] -> head-split bf16 [b][NH][LB][64].
// 512 threads: 4 iterations cover 128 rows x 16 s8v-chunks.
__device__ __forceinline__ void store_tile_bf16(
    const u16* __restrict__ Es, u16* __restrict__ out,
    int grb, int c0r, int NH, int LB, int LBS, int tid)
{
  #pragma unroll
  for (int it = 0; it < 4; it++) {
    int idx = it * 512 + tid;
    int r = idx >> 4, ch = idx & 15;
    int grow = grb + r;
    int b = grow >> LBS, pos = grow & (LB - 1);
    int cg = c0r + ch * 8;
    size_t base = (((size_t)b * NH + (cg >> 6)) * LB + pos) * 64 + (cg & 63);
    *(s8v*)(out + base) = *(const s8v*)(Es + r * 136 + ch * 8);
  }
}

// ---------------------------------------------------------------------------
// Fused QKV GEMM (summary + regular), XCD-swizzled. grid = 396, block = 512.
// ---------------------------------------------------------------------------
struct QkvA {
  const u16 *X, *WTs, *WTr;
  const float *b0s, *b1s, *b2s, *b0r, *b1r, *b2r;
  u16 *o0s, *o1s, *o2s, *o0r, *o1r, *o2r;
};

__global__ __launch_bounds__(512)
void qkv_k(QkvA a)
{
  // bijective XCD swizzle, nwg=396: q=49, rem=4
  int orig = blockIdx.x;
  int xcd = orig & 7, sidx = orig >> 3;
  int wg = (xcd < 4) ? (xcd * 50 + sidx) : (200 + (xcd - 4) * 49 + sidx);
  const int bx = wg % 12, by = wg / 12;
  const bool issum = (by == 0);
  const int c0 = bx * 128;

  __shared__ u16 Adb[256][72];
  __shared__ u16 Bdb[256][72];
  u16* Es = &Adb[0][0];                        // 34.8 KB alias inside Adb

  const int tid  = threadIdx.x;
  const int lane = tid & 63;
  const int w    = tid >> 6;                   // 0..7
  const int l15  = lane & 15;
  const int l4   = lane >> 4;
  const int wro  = (w >> 1) * 32;
  const int wco  = (w & 1) * 64;

  f4v acc[2][4];
  #pragma unroll
  for (int i = 0; i < 2; i++)
    #pragma unroll
    for (int j = 0; j < 4; j++) acc[i][j] = (f4v){0.f, 0.f, 0.f, 0.f};

  const u16* Xrow  = a.X + (size_t)by * 128 * 1024;
  const u16* WTrow = (issum ? a.WTs : a.WTr) + (size_t)c0 * 1024;
  gemm_core_db(Xrow, WTrow, Adb, Bdb, acc, tid, l15, l4, wro, wco);

  const int LB  = issum ? 64 : 2048;
  const int LBS = issum ? 6 : 11;
  const int grb = issum ? 0 : (by - 1) * 128;

  const float* Bp; u16* Outp; int NH, rs, ropeMode; bool sc;
  if (c0 < 1024)      { Bp = issum ? a.b0s : a.b0r; Outp = issum ? a.o0s : a.o0r; NH = 16; rs = 0;    ropeMode = 1; sc = true;  }
  else if (c0 < 1280) { Bp = issum ? a.b1s : a.b1r; Outp = issum ? a.o1s : a.o1r; NH = 4;  rs = 1024; ropeMode = 1; sc = false; }
  else                { Bp = issum ? a.b2s : a.b2r; Outp = issum ? a.o2s : a.o2r; NH = 4;  rs = 1280; ropeMode = 0; sc = false; }

  epi_to_lds(acc, Bp, Es, c0 - rs + wco, wro, wco, grb, LB, ropeMode, !issum, sc, l15, l4);
  __syncthreads();
  store_tile_bf16(Es, Outp, grb, c0 - rs, NH, LB, LBS, tid);
}

// ---------------------------------------------------------------------------
// Phase-1 output GEMM: k2 / v2 (bf16) + so (fp32). grid = 12, block = 512.
// ---------------------------------------------------------------------------
__global__ __launch_bounds__(512)
void gemm_p1_k(const u16* __restrict__ X, const u16* __restrict__ WT,
               const float* __restrict__ bk2, const float* __restrict__ bv2,
               const float* __restrict__ bso,
               u16* __restrict__ k2, u16* __restrict__ v2, float* __restrict__ outsum)
{
  const int c0 = blockIdx.x * 128;

  __shared__ u16 Adb[256][72];
  __shared__ u16 Bdb[256][72];
  u16* Es = &Adb[0][0];

  const int tid  = threadIdx.x;
  const int lane = tid & 63;
  const int w    = tid >> 6;
  const int l15  = lane & 15;
  const int l4   = lane >> 4;
  const int wro  = (w >> 1) * 32;
  const int wco  = (w & 1) * 64;

  f4v acc[2][4];
  #pragma unroll
  for (int i = 0; i < 2; i++)
    #pragma unroll
    for (int j = 0; j < 4; j++) acc[i][j] = (f4v){0.f, 0.f, 0.f, 0.f};

  gemm_core_db(X, WT + (size_t)c0 * 1024, Adb, Bdb, acc, tid, l15, l4, wro, wco);

  if (c0 < 512) {
    const float* Bp = (c0 < 256) ? bk2 : bv2;
    u16* Outp = (c0 < 256) ? k2 : v2;
    int rs = (c0 < 256) ? 0 : 256;
    epi_to_lds(acc, Bp, Es, c0 - rs + wco, wro, wco, 0, 64, 0, false, false, l15, l4);
    __syncthreads();
    store_tile_bf16(Es, Outp, 0, c0 - rs, 4, 64, 6, tid);
  } else {
    float bv[4];
    #pragma unroll
    for (int cc = 0; cc < 4; cc++) bv[cc] = bso[c0 - 512 + wco + cc * 16 + l15];
    #pragma unroll
    for (int rc = 0; rc < 2; rc++)
      #pragma unroll
      for (int reg = 0; reg < 4; reg++) {
        int row = wro + rc * 16 + l4 * 4 + reg;
        #pragma unroll
        for (int cc = 0; cc < 4; cc++)
          outsum[(size_t)row * 1024 + c0 - 512 + wco + cc * 16 + l15] = acc[rc][cc][reg] + bv[cc];
      }
  }
}

// ---------------------------------------------------------------------------
// ro GEMM: rattn[4096][1024] @ wt_ro -> out_reg fp32. grid = 256, block = 512.
// ---------------------------------------------------------------------------
__global__ __launch_bounds__(512)
void gemm_ro_k(const u16* __restrict__ X, const u16* __restrict__ WT,
               const float* __restrict__ Bp, float* __restrict__ out)
{
  int orig = blockIdx.x;
  int wg = (orig & 7) * 32 + (orig >> 3);        // 256 = 8*32 exact
  const int bx = wg & 7, by = wg >> 3;
  const int c0 = bx * 128, r0 = by * 128;

  __shared__ u16 Adb[256][72];
  __shared__ u16 Bdb[256][72];

  const int tid  = threadIdx.x;
  const int lane = tid & 63;
  const int w    = tid >> 6;
  const int l15  = lane & 15;
  const int l4   = lane >> 4;
  const int wro  = (w >> 1) * 32;
  const int wco  = (w & 1) * 64;

  f4v acc[2][4];
  #pragma unroll
  for (int i = 0; i < 2; i++)
    #pragma unroll
    for (int j = 0; j < 4; j++) acc[i][j] = (f4v){0.f, 0.f, 0.f, 0.f};

  gemm_core_db(X + (size_t)r0 * 1024, WT + (size_t)c0 * 1024, Adb, Bdb, acc,
               tid, l15, l4, wro, wco);

  float bv[4];
  #pragma unroll
  for (int cc = 0; cc < 4; cc++) bv[cc] = Bp[c0 + wco + cc * 16 + l15];
  #pragma unroll
  for (int rc = 0; rc < 2; rc++)
    #pragma unroll
    for (int reg = 0; reg < 4; reg++) {
      int row = r0 + wro + rc * 16 + l4 * 4 + reg;
      #pragma unroll
      for (int cc = 0; cc < 4; cc++)
        out[(size_t)row * 1024 + c0 + wco + cc * 16 + l15] = acc[rc][cc][reg] + bv[cc];
    }
}

// ---------------------------------------------------------------------------
// Shared flash-attention tile compute (unchanged).
// ---------------------------------------------------------------------------
template<int PHASE>
__device__ __forceinline__ void attn_tile(
    const u16 (&Kc)[64][72], const u16 (&Vc)[64][72], u16 (&Ptw)[16][72],
    const s8v& qf0, const s8v& qf1, f4v (&acc)[4],
    float (&m)[4], float (&lsum)[4],
    int kbase, int qw, int l15, int l4)
{
  f4v s[4];
  #pragma unroll
  for (int n = 0; n < 4; n++) {
    s8v kf0 = *(const s8v*)&Kc[n * 16 + l15][l4 * 8];
    s8v kf1 = *(const s8v*)&Kc[n * 16 + l15][32 + l4 * 8];
    f4v t = {0.f, 0.f, 0.f, 0.f};
    t = __builtin_amdgcn_mfma_f32_16x16x32_bf16(qf0, kf0, t, 0, 0, 0);
    t = __builtin_amdgcn_mfma_f32_16x16x32_bf16(qf1, kf1, t, 0, 0, 0);
    s[n] = t;
  }

  bool need_mask = (kbase == 0) ||
    (PHASE == 1 ? (((kbase - 1) >> 5) > qw) : ((kbase - 1) > qw));
  float v4[4] = {-1e30f, -1e30f, -1e30f, -1e30f};
  if (need_mask) {
    #pragma unroll
    for (int n = 0; n < 4; n++) {
      int kidx = kbase + n * 16 + l15;
      #pragma unroll
      for (int r = 0; r < 4; r++) {
        int qrow = qw + l4 * 4 + r;
        bool ok;
        if (kbase == 0) ok = kidx <= ((PHASE == 1) ? qrow : (qrow >> 5));
        else { int kr = kidx - 64; ok = (PHASE == 1) ? ((kr >> 5) <= qrow) : (kr <= qrow); }
        float sv = ok ? s[n][r] : -1e30f;
        s[n][r] = sv;
        v4[r] = fmaxf(v4[r], sv);
      }
    }
  } else {
    #pragma unroll
    for (int n = 0; n < 4; n++)
      #pragma unroll
      for (int r = 0; r < 4; r++) v4[r] = fmaxf(v4[r], s[n][r]);
  }
  #pragma unroll
  for (int r = 0; r < 4; r++) {
    float v = v4[r];
    v = fmaxf(v, __shfl_xor(v, 1));
    v = fmaxf(v, __shfl_xor(v, 2));
    v = fmaxf(v, __shfl_xor(v, 4));
    v = fmaxf(v, __shfl_xor(v, 8));
    v4[r] = v;
  }
  bool up = (v4[0] > m[0]) || (v4[1] > m[1]) || (v4[2] > m[2]) || (v4[3] > m[3]);
  if (__any(up)) {
    #pragma unroll
    for (int r = 0; r < 4; r++) {
      float mn = fmaxf(m[r], v4[r]);
      float f  = __expf(m[r] - mn);
      m[r] = mn;
      lsum[r] *= f;
      #pragma unroll
      for (int dt = 0; dt < 4; dt++) acc[dt][r] *= f;
    }
  }
  float rs[4] = {0.f, 0.f, 0.f, 0.f};
  #pragma unroll
  for (int n = 0; n < 4; n++) {
    #pragma unroll
    for (int r = 0; r < 4; r++) {
      float p = __expf(s[n][r] - m[r]);
      Ptw[l4 * 4 + r][n * 16 + l15] = f2bf(p);
      rs[r] += p;
    }
  }
  #pragma unroll
  for (int r = 0; r < 4; r++) {
    float v = rs[r];
    v += __shfl_xor(v, 1); v += __shfl_xor(v, 2);
    v += __shfl_xor(v, 4); v += __shfl_xor(v, 8);
    lsum[r] += v;
  }

  asm volatile("s_waitcnt lgkmcnt(0)" ::: "memory");

  s8v pf0 = *(const s8v*)&Ptw[l15][l4 * 8];
  s8v pf1 = *(const s8v*)&Ptw[l15][32 + l4 * 8];
  #pragma unroll
  for (int dt = 0; dt < 4; dt++) {
    s8v vf0 = *(const s8v*)&Vc[dt * 16 + l15][l4 * 8];
    s8v vf1 = *(const s8v*)&Vc[dt * 16 + l15][32 + l4 * 8];
    acc[dt] = __builtin_amdgcn_mfma_f32_16x16x32_bf16(pf0, vf0, acc[dt], 0, 0, 0);
    acc[dt] = __builtin_amdgcn_mfma_f32_16x16x32_bf16(pf1, vf1, acc[dt], 0, 0, 0);
  }
}

// ---------------------------------------------------------------------------
// Phase 2 attention (unchanged).
// ---------------------------------------------------------------------------
__global__ __launch_bounds__(512)
void attn2_k(const u16* __restrict__ Q, const u16* __restrict__ KS,
             const u16* __restrict__ KR, const u16* __restrict__ VST,
             const u16* __restrict__ VRT, u16* __restrict__ Out)
{
  const int gid = blockIdx.x;
  const int qb  = (gid & 256) ? (15 - (gid & 15)) : (gid & 15);
  const int bh  = gid >> 4;
  const int h   = bh & 15, b = bh >> 4;
  const int q0  = qb * 128;
  const int kh  = h >> 2;

  __shared__ u16 Kt[2][64][72];
  __shared__ u16 Vt[2][64][72];
  __shared__ u16 Pt[8][16][72];

  const int tid = threadIdx.x, lane = tid & 63, w = tid >> 6;
  const int l15 = lane & 15, l4 = lane >> 4;
  const int qw  = q0 + w * 16;

  const u16* qp = Q + (((size_t)b * H_ + h) * R_ + qw + l15) * 64;
  s8v qf0 = *(const s8v*)(qp + l4 * 8);
  s8v qf1 = *(const s8v*)(qp + 32 + l4 * 8);

  f4v acc[4];
  #pragma unroll
  for (int dt = 0; dt < 4; dt++) acc[dt] = (f4v){0.f, 0.f, 0.f, 0.f};
  float m[4]    = {-1e30f, -1e30f, -1e30f, -1e30f};
  float lsum[4] = {0.f, 0.f, 0.f, 0.f};

  const int ntiles = (64 + q0 + 128) >> 6;
  const size_t bh_kv = (size_t)b * KVH_ + kh;

  const int r_ = tid >> 3, sg_ = (tid & 7) * 8;

  {
    const u16* kp = KS  + bh_kv * 4096;
    const u16* vp = VST + bh_kv * 4096;
    s8v k0 = *(const s8v*)(kp + r_ * 64 + sg_);
    s8v v0 = *(const s8v*)(vp + r_ * 64 + sg_);
    *(s8v*)&Kt[0][r_][sg_] = k0;
    *(s8v*)&Vt[0][r_][sg_] = v0;
  }
  __syncthreads();

  for (int kt = 0; kt < ntiles; kt++) {
    const int cur = kt & 1;
    const int kbase = kt * 64;
    const bool pre = (kt + 1 < ntiles);
    s8v knx, vnx;
    if (pre) {
      const int nb = kbase;
      const u16* kp = KR  + (bh_kv * R_ + nb) * 64;
      const u16* vp = VRT + bh_kv * 64 * R_ + nb;
      knx = *(const s8v*)(kp + r_ * 64 + sg_);
      vnx = *(const s8v*)(vp + (size_t)r_ * R_ + sg_);
    }

    const bool active = (kbase == 0) || (kbase - 64 <= qw + 15);
    if (active)
      attn_tile<2>(Kt[cur], Vt[cur], Pt[w], qf0, qf1, acc, m, lsum,
                   kbase, qw, l15, l4);

    if (pre) {
      *(s8v*)&Kt[cur ^ 1][r_][sg_] = knx;
      *(s8v*)&Vt[cur ^ 1][r_][sg_] = vnx;
    }
    __syncthreads();
  }

  #pragma unroll
  for (int r = 0; r < 4; r++) {
    float linv = 1.f / lsum[r];
    #pragma unroll
    for (int dt = 0; dt < 4; dt++)
      Pt[w][l4 * 4 + r][dt * 16 + l15] = f2bf(acc[dt][r] * linv);
  }
  asm volatile("s_waitcnt lgkmcnt(0)" ::: "memory");
  {
    int rl = lane >> 3, ch = lane & 7;
    #pragma unroll
    for (int rr = 0; rr < 2; rr++) {
      int row = rr * 8 + rl;
      u16* o = Out + ((size_t)b * R_ + qw + row) * D_ + h * 64 + ch * 8;
      *(s8v*)o = *(const s8v*)&Pt[w][row][ch * 8];
    }
  }
}

// ---------------------------------------------------------------------------
// Phase 1 attention, split-K (unchanged).
// ---------------------------------------------------------------------------
__global__ __launch_bounds__(256)
void attn1_k(const u16* __restrict__ Q, const u16* __restrict__ KS,
             const u16* __restrict__ KR, const u16* __restrict__ VST,
             const u16* __restrict__ VRT,
             float* __restrict__ pO, float* __restrict__ pml)
{
  const int gid = blockIdx.x;
  const int ck  = gid & 7;
  const int bh  = gid >> 3;
  const int h   = bh & 15, b = bh >> 4;
  const int kh  = h >> 2;
  const int kt0 = (ck * 33) >> 3;
  const int kt1 = ((ck + 1) * 33) >> 3;

  __shared__ u16 Kt[2][64][72];
  __shared__ u16 Vt[2][64][72];
  __shared__ u16 Pt[4][16][72];

  const int tid = threadIdx.x, lane = tid & 63, w = tid >> 6;
  const int l15 = lane & 15, l4 = lane >> 4;
  const int qw  = w * 16;

  const u16* qp = Q + (((size_t)b * H_ + h) * S_ + qw + l15) * 64;
  s8v qf0 = *(const s8v*)(qp + l4 * 8);
  s8v qf1 = *(const s8v*)(qp + 32 + l4 * 8);

  f4v acc[4];
  #pragma unroll
  for (int dt = 0; dt < 4; dt++) acc[dt] = (f4v){0.f, 0.f, 0.f, 0.f};
  float m[4]    = {-1e30f, -1e30f, -1e30f, -1e30f};
  float lsum[4] = {0.f, 0.f, 0.f, 0.f};

  const size_t bh_kv = (size_t)b * KVH_ + kh;
  const int r_ = tid >> 3, sg_ = (tid & 7) * 8;

  {
    const u16 *kp, *vp; int vstr;
    if (kt0 == 0) { kp = KS + bh_kv * 4096; vp = VST + bh_kv * 4096; vstr = 64; }
    else {
      kp = KR  + (bh_kv * R_ + kt0 * 64 - 64) * 64;
      vp = VRT + bh_kv * 64 * R_ + (kt0 * 64 - 64);
      vstr = R_;
    }
    s8v ka0 = *(const s8v*)(kp + r_ * 64 + sg_);
    s8v ka1 = *(const s8v*)(kp + (r_ + 32) * 64 + sg_);
    s8v va0 = *(const s8v*)(vp + (size_t)r_ * vstr + sg_);
    s8v va1 = *(const s8v*)(vp + (size_t)(r_ + 32) * vstr + sg_);
    *(s8v*)&Kt[0][r_][sg_]      = ka0;
    *(s8v*)&Kt[0][r_ + 32][sg_] = ka1;
    *(s8v*)&Vt[0][r_][sg_]      = va0;
    *(s8v*)&Vt[0][r_ + 32][sg_] = va1;
  }
  __syncthreads();

  for (int kt = kt0; kt < kt1; kt++) {
    const int cur = (kt - kt0) & 1;
    const int kbase = kt * 64;
    const bool pre = (kt + 1 < kt1);
    s8v ka0, ka1, va0, va1;
    if (pre) {
      const u16* kp = KR  + (bh_kv * R_ + kbase) * 64;
      const u16* vp = VRT + bh_kv * 64 * R_ + kbase;
      ka0 = *(const s8v*)(kp + r_ * 64 + sg_);
      ka1 = *(const s8v*)(kp + (r_ + 32) * 64 + sg_);
      va0 = *(const s8v*)(vp + (size_t)r_ * R_ + sg_);
      va1 = *(const s8v*)(vp + (size_t)(r_ + 32) * R_ + sg_);
    }

    const bool active = (kbase == 0) || (((kbase - 64) >> 5) <= qw + 15);
    if (active)
      attn_tile<1>(Kt[cur], Vt[cur], Pt[w], qf0, qf1, acc, m, lsum,
                   kbase, qw, l15, l4);

    if (pre) {
      *(s8v*)&Kt[cur ^ 1][r_][sg_]      = ka0;
      *(s8v*)&Kt[cur ^ 1][r_ + 32][sg_] = ka1;
      *(s8v*)&Vt[cur ^ 1][r_][sg_]      = va0;
      *(s8v*)&Vt[cur ^ 1][r_ + 32][sg_] = va1;
    }
    __syncthreads();
  }

  #pragma unroll
  for (int r = 0; r < 4; r++) {
    int qrow = qw + l4 * 4 + r;
    float* po = pO + (((size_t)ck * 32 + bh) * 64 + qrow) * 64;
    #pragma unroll
    for (int dt = 0; dt < 4; dt++) po[dt * 16 + l15] = acc[dt][r];
    if (l15 == 0) {
      float* pm = pml + (((size_t)ck * 32 + bh) * 64 + qrow) * 2;
      pm[0] = m[r]; pm[1] = lsum[r];
    }
  }
}

// Combine 8 phase-1 partials -> sattn bf16 (vectorized 16B stores)
__global__ __launch_bounds__(256)
void comb1_k(const float* __restrict__ pO, const float* __restrict__ pml,
             u16* __restrict__ sattn)
{
  const int bh = blockIdx.x;
  const int b = bh >> 4, h = bh & 15;
  const int q  = threadIdx.x >> 2;
  const int d0 = (threadIdx.x & 3) * 16;
  float mv[8], lv[8], mstar = -1e30f;
  #pragma unroll
  for (int c = 0; c < 8; c++) {
    const float* p = pml + (((size_t)c * 32 + bh) * 64 + q) * 2;
    mv[c] = p[0]; lv[c] = p[1];
    mstar = fmaxf(mstar, mv[c]);
  }
  float o[16];
  #pragma unroll
  for (int j = 0; j < 16; j++) o[j] = 0.f;
  float lsum = 0.f;
  #pragma unroll
  for (int c = 0; c < 8; c++) {
    float wgt = __expf(mv[c] - mstar);
    lsum += lv[c] * wgt;
    const float* po = pO + (((size_t)c * 32 + bh) * 64 + q) * 64 + d0;
    #pragma unroll
    for (int j = 0; j < 16; j++) o[j] += po[j] * wgt;
  }
  float inv = 1.f / lsum;
  u16 ob[16];
  #pragma unroll
  for (int j = 0; j < 16; j++) ob[j] = f2bf(o[j] * inv);
  u16* out = sattn + ((size_t)(b * 64 + q)) * 1024 + h * 64 + d0;
  *(s8v*)out       = *(s8v*)&ob[0];
  *(s8v*)(out + 8) = *(s8v*)&ob[8];
}

extern "C" void kernel_launch(void* const* d_in, const int* in_sizes, int n_in,
                              void* d_out, int out_size, void* d_ws, size_t ws_size,
                              hipStream_t stream)
{
  (void)out_size; (void)ws_size;

  static const int expect[22] = {
    131072, 4194304,
    1048576, 1024, 262144, 256,
    262144, 256, 1048576, 1024,
    1048576, 1024, 262144, 256,
    262144, 256, 1048576, 1024,
    262144, 256, 262144, 256
  };
  if (n_in < 22) return;
  for (int i = 0; i < 22; i++) if (in_sizes[i] != expect[i]) return;

  const float* sum_x = (const float*)d_in[0];
  const float* reg_x = (const float*)d_in[1];
  const float* w_sq = (const float*)d_in[2];  const float* b_sq = (const float*)d_in[3];
  const float* w_sk = (const float*)d_in[4];  const float* b_sk = (const float*)d_in[5];
  const float* w_sv = (const float*)d_in[6];  const float* b_sv = (const float*)d_in[7];
  const float* w_so = (const float*)d_in[8];  const float* b_so = (const float*)d_in[9];
  const float* w_rq = (const float*)d_in[10]; const float* b_rq = (const float*)d_in[11];
  const float* w_rk = (const float*)d_in[12]; const float* b_rk = (const float*)d_in[13];
  const float* w_rv = (const float*)d_in[14]; const float* b_rv = (const float*)d_in[15];
  const float* w_ro = (const float*)d_in[16]; const float* b_ro = (const float*)d_in[17];
  const float* w_k2 = (const float*)d_in[18]; const float* b_k2 = (const float*)d_in[19];
  const float* w_v2 = (const float*)d_in[20]; const float* b_v2 = (const float*)d_in[21];

  u16* ws    = (u16*)d_ws;
  u16* xs_bf = ws;                    // 131072
  u16* xr_bf = xs_bf + 131072;        // 4194304
  u16* wt_s  = xr_bf + 4194304;       // 1572864  [sq|sk|sv] (dead after QKV -> V^T)
  u16* wt_r  = wt_s  + 1572864;       // 1572864  [rq|rk|rv]
  u16* wt_p  = wt_r  + 1572864;       // 1572864  [k2|v2|so]
  u16* wt_ro = wt_p  + 1572864;       // 1048576
  u16* sq    = wt_ro + 1048576;       // 131072
  u16* sk    = sq    + 131072;        // 32768
  u16* sv    = sk    + 32768;         // 32768
  u16* rq    = sv    + 32768;         // 4194304
  u16* rk    = rq    + 4194304;       // 1048576
  u16* rv    = rk    + 1048576;       // 1048576
  u16* sattn = rv    + 1048576;       // 131072
  u16* k2    = sattn + 131072;        // 32768
  u16* v2    = k2    + 32768;         // 32768
  u16* rattn = v2    + 32768;         // 4194304

  u16* rvT = wt_s;
  u16* svT = wt_s + 1048576;
  u16* v2T = wt_s + 1081344;

  float* pO  = (float*)rattn;
  float* pml = pO + 1048576;

  float* out_sum = (float*)d_out;
  float* out_reg = out_sum + 131072;

  dim3 blk(256);

  W6 big;
  big.w[0] = w_sq; big.o[0] = wt_s;
  big.w[1] = w_rq; big.o[1] = wt_r;
  big.w[2] = w_so; big.o[2] = wt_p + 512 * 1024;
  big.w[3] = w_ro; big.o[3] = wt_ro;
  big.w[4] = w_sq; big.o[4] = wt_s;
  big.w[5] = w_sq; big.o[5] = wt_s;
  W6 small;
  small.w[0] = w_sk; small.o[0] = wt_s + 1024 * 1024;
  small.w[1] = w_sv; small.o[1] = wt_s + 1280 * 1024;
  small.w[2] = w_rk; small.o[2] = wt_r + 1024 * 1024;
  small.w[3] = w_rv; small.o[3] = wt_r + 1280 * 1024;
  small.w[4] = w_k2; small.o[4] = wt_p;
  small.w[5] = w_v2; small.o[5] = wt_p + 256 * 1024;
  transw_k<<<dim3(32, 32, 4), blk, 0, stream>>>(big, 1024);
  transw_k<<<dim3(8, 32, 6),  blk, 0, stream>>>(small, 256);
  convx_k<<<dim3(2112), blk, 0, stream>>>(sum_x, reg_x, xs_bf, xr_bf);

  QkvA qa;
  qa.X = xs_bf; qa.WTs = wt_s; qa.WTr = wt_r;
  qa.b0s = b_sq; qa.b1s = b_sk; qa.b2s = b_sv;
  qa.b0r = b_rq; qa.b1r = b_rk; qa.b2r = b_rv;
  qa.o0s = sq; qa.o1s = sk; qa.o2s = sv;
  qa.o0r = rq; qa.o1r = rk; qa.o2r = rv;
  qkv_k<<<dim3(396), dim3(512), 0, stream>>>(qa);

  VJ jrv = {rv, rvT, 2048};
  VJ jsv = {sv, svT, 64};
  vtrans_k<<<dim3(32, 8, 2), blk, 0, stream>>>(jrv, jsv);

  attn1_k<<<dim3(256), blk, 0, stream>>>(sq, sk, rk, svT, rvT, pO, pml);
  comb1_k<<<dim3(32), blk, 0, stream>>>(pO, pml, sattn);

  gemm_p1_k<<<dim3(12), dim3(512), 0, stream>>>(sattn, wt_p, b_k2, b_v2, b_so, k2, v2, out_sum);
  VJ jv2 = {v2, v2T, 64};
  vtrans_k<<<dim3(1, 8, 1), blk, 0, stream>>>(jv2, jv2);

  attn2_k<<<dim3(512), dim3(512), 0, stream>>>(rq, k2, rk, v2T, rvT, rattn);

  gemm_ro_k<<<dim3(256), dim3(512), 0, stream>>>(rattn, wt_ro, b_ro, out_reg);
}

// Round 13
// 135.943 us; speedup vs baseline: 19.0576x; 1.2100x over previous
//
#include <hip/hip_runtime.h>

typedef unsigned short u16;
typedef __attribute__((ext_vector_type(8))) short s8v;   // 8 x bf16 MFMA A/B frag
typedef __attribute__((ext_vector_type(4))) float f4v;   // MFMA C/D frag

#define B_    2
#define S_    64
#define R_    2048
#define D_    1024
#define H_    16
#define KVH_  4
#define LOG2_10K 13.287712379549449f
// attention scale folded into Q, in exp2 domain: 0.125 * log2(e)
#define QSC_  0.18033688011112042f

__device__ __forceinline__ u16 f2bf(float f) {          // RTNE
  union { float f; unsigned int i; } v; v.f = f;
  unsigned int x = v.i;
  return (u16)((x + 0x7FFFu + ((x >> 16) & 1u)) >> 16);
}
__device__ __forceinline__ u16 f2bf_ru(float f) {       // round-half-up (P only)
  union { float f; unsigned int i; } v; v.f = f;
  return (u16)((v.i + 0x8000u) >> 16);
}

// ---------------------------------------------------------------------------
// Prep: all 10 weight transposes in ONE launch. W[K=1024][C] f32 -> WT[C][1024]
// ---------------------------------------------------------------------------
struct WT10 { const float* w[10]; u16* o[10]; int C[10]; };

__global__ __launch_bounds__(256)
void transw_k(WT10 ws)
{
  const int z = blockIdx.z;
  const int C = ws.C[z];
  const int c0 = blockIdx.x * 32, k0 = blockIdx.y * 32;
  if (c0 >= C) return;
  __shared__ float t[32][33];
  const float* w = ws.w[z];
  u16* o = ws.o[z];
  const int x = threadIdx.x & 31, y = threadIdx.x >> 5;
  #pragma unroll
  for (int j = 0; j < 4; j++)
    t[y + 8 * j][x] = w[(size_t)(k0 + y + 8 * j) * C + c0 + x];
  __syncthreads();
  #pragma unroll
  for (int j = 0; j < 4; j++)
    o[(size_t)(c0 + y + 8 * j) * 1024 + k0 + x] = f2bf(t[x][y + 8 * j]);
}

__global__ __launch_bounds__(256)
void convx_k(const float* __restrict__ xa, const float* __restrict__ xb,
             u16* __restrict__ oa, u16* __restrict__ ob)
{
  int i = (blockIdx.x * 256 + threadIdx.x) * 8;
  const float* src; u16* dst; int off;
  if (i < 131072) { src = xa; dst = oa; off = i; }
  else            { src = xb; dst = ob; off = i - 131072; }
  float4 a = *(const float4*)(src + off);
  float4 b = *(const float4*)(src + off + 4);
  s8v r;
  r[0] = (short)f2bf(a.x); r[1] = (short)f2bf(a.y);
  r[2] = (short)f2bf(a.z); r[3] = (short)f2bf(a.w);
  r[4] = (short)f2bf(b.x); r[5] = (short)f2bf(b.y);
  r[6] = (short)f2bf(b.z); r[7] = (short)f2bf(b.w);
  *(s8v*)(dst + off) = r;
}

// ---------------------------------------------------------------------------
// Double-buffered GEMM core, 512 threads = 8 waves (4x2; wave = 32r x 64c,
// acc[2][4]). Register-staged prefetch, write-late, one barrier per K-step.
// ---------------------------------------------------------------------------
__device__ __forceinline__ void gemm_core_db(
    const u16* __restrict__ Xrow, const u16* __restrict__ WTrow,
    u16 (*Adb)[72], u16 (*Bdb)[72], f4v (&acc)[2][4],
    int tid, int l15, int l4, int wro, int wco)
{
  s8v pa[2], pb[2];
  #pragma unroll
  for (int it = 0; it < 2; it++) {
    int seg = tid + it * 512;
    int r = seg >> 3, sg = (seg & 7) * 8;
    pa[it] = *(const s8v*)(Xrow  + (size_t)r * 1024 + sg);
    pb[it] = *(const s8v*)(WTrow + (size_t)r * 1024 + sg);
  }
  #pragma unroll
  for (int it = 0; it < 2; it++) {
    int seg = tid + it * 512;
    int r = seg >> 3, sg = (seg & 7) * 8;
    *(s8v*)&Adb[r][sg] = pa[it];
    *(s8v*)&Bdb[r][sg] = pb[it];
  }
  __syncthreads();

  #pragma unroll 2
  for (int k = 0; k < 16; k++) {
    const int off = (k & 1) * 128;
    if (k + 1 < 16) {
      const int k0 = (k + 1) * 64;
      #pragma unroll
      for (int it = 0; it < 2; it++) {
        int seg = tid + it * 512;
        int r = seg >> 3, sg = (seg & 7) * 8;
        pa[it] = *(const s8v*)(Xrow  + (size_t)r * 1024 + k0 + sg);
        pb[it] = *(const s8v*)(WTrow + (size_t)r * 1024 + k0 + sg);
      }
    }
    s8v af[2][2], bf4[4][2];
    #pragma unroll
    for (int rc = 0; rc < 2; rc++) {
      af[rc][0] = *(const s8v*)&Adb[off + wro + rc * 16 + l15][l4 * 8];
      af[rc][1] = *(const s8v*)&Adb[off + wro + rc * 16 + l15][32 + l4 * 8];
    }
    #pragma unroll
    for (int cc = 0; cc < 4; cc++) {
      bf4[cc][0] = *(const s8v*)&Bdb[off + wco + cc * 16 + l15][l4 * 8];
      bf4[cc][1] = *(const s8v*)&Bdb[off + wco + cc * 16 + l15][32 + l4 * 8];
    }
    #pragma unroll
    for (int rc = 0; rc < 2; rc++)
      #pragma unroll
      for (int cc = 0; cc < 4; cc++) {
        acc[rc][cc] = __builtin_amdgcn_mfma_f32_16x16x32_bf16(af[rc][0], bf4[cc][0], acc[rc][cc], 0, 0, 0);
        acc[rc][cc] = __builtin_amdgcn_mfma_f32_16x16x32_bf16(af[rc][1], bf4[cc][1], acc[rc][cc], 0, 0, 0);
      }
    if (k + 1 < 16) {
      const int noff = ((k + 1) & 1) * 128;
      #pragma unroll
      for (int it = 0; it < 2; it++) {
        int seg = tid + it * 512;
        int r = seg >> 3, sg = (seg & 7) * 8;
        *(s8v*)&Adb[noff + r][sg] = pa[it];
        *(s8v*)&Bdb[noff + r][sg] = pb[it];
      }
    }
    __syncthreads();
  }
}

// Wave epilogue -> LDS staging tile Es[128][136] (bf16, bias+RoPE applied).
__device__ __forceinline__ void epi_to_lds(
    const f4v (&acc)[2][4], const float* __restrict__ Bp, u16* __restrict__ Es,
    int cbr, int wro, int wco, int grb, int LB,
    int ropeMode, bool rope2d, bool sc, int l15, int l4)
{
  float bv[4];
  #pragma unroll
  for (int cc = 0; cc < 4; cc++) bv[cc] = Bp[cbr + cc * 16 + l15];

  if (ropeMode == 0) {
    #pragma unroll
    for (int rc = 0; rc < 2; rc++)
      #pragma unroll
      for (int reg = 0; reg < 4; reg++) {
        int lrow = wro + rc * 16 + l4 * 4 + reg;
        #pragma unroll
        for (int cc = 0; cc < 4; cc++)
          Es[lrow * 136 + wco + cc * 16 + l15] = f2bf(acc[rc][cc][reg] + bv[cc]);
      }
  } else {
    float step = rope2d ? (LOG2_10K / 16.f) : (LOG2_10K / 32.f);
    float inv_lo = exp2f(-(float)l15 * step);
    float inv_hi = rope2d ? inv_lo : inv_lo * exp2f(-16.f * step);
    #pragma unroll
    for (int rc = 0; rc < 2; rc++)
      #pragma unroll
      for (int reg = 0; reg < 4; reg++) {
        int lrow = wro + rc * 16 + l4 * 4 + reg;
        int grow = grb + lrow;
        int pos = grow & (LB - 1);
        int bar = pos >> 5, tib = pos & 31;
        #pragma unroll
        for (int cc = 0; cc < 4; cc++) {
          float inv = (cc & 1) ? inv_hi : inv_lo;
          float bse = rope2d ? (float)((cc & 1) ? tib : bar) : (float)pos;
          float ang = bse * inv;
          float sn, cs;
          sincosf(ang, &sn, &cs);
          float v0 = acc[rc][cc][reg] + bv[cc];
          float v1 = acc[rc][cc ^ 2][reg] + bv[cc ^ 2];
          float rot = (cc < 2) ? -v1 : v1;
          float val = v0 * cs + rot * sn;
          if (sc) val *= QSC_;                 // 0.125 * log2(e): exp2-domain
          Es[lrow * 136 + wco + cc * 16 + l15] = f2bf(val);
        }
      }
  }
}

// Full-line store: Es[128][136] -> head-split bf16 [b][NH][LB][64].
__device__ __forceinline__ void store_tile_bf16(
    const u16* __restrict__ Es, u16* __restrict__ out,
    int grb, int c0r, int NH, int LB, int LBS, int tid)
{
  #pragma unroll
  for (int it = 0; it < 4; it++) {
    int idx = it * 512 + tid;
    int r = idx >> 4, ch = idx & 15;
    int grow = grb + r;
    int b = grow >> LBS, pos = grow & (LB - 1);
    int cg = c0r + ch * 8;
    size_t base = (((size_t)b * NH + (cg >> 6)) * LB + pos) * 64 + (cg & 63);
    *(s8v*)(out + base) = *(const s8v*)(Es + r * 136 + ch * 8);
  }
}

// Transposed store: Es[128 rows=pos][128 cols=d] -> VT [b][kvh][64 d][LB pos].
// Fuses the old vtrans_k into the GEMM epilogue (V tiles only feed attn as V^T).
__device__ __forceinline__ void store_tile_vT(
    const u16* __restrict__ Es, u16* __restrict__ outT,
    int grb, int kvbase, int LB, int LBS, int tid)
{
  #pragma unroll
  for (int it = 0; it < 4; it++) {
    int idx = tid + it * 512;
    int dcol = idx & 127, rg = idx >> 7;         // rg: 16 groups of 8 rows
    int grow = grb + rg * 8;
    int b = grow >> LBS, pos = grow & (LB - 1);
    u16 tmp[8];
    #pragma unroll
    for (int j = 0; j < 8; j++) tmp[j] = Es[(rg * 8 + j) * 136 + dcol];
    u16* dst = outT + (((size_t)(b * KVH_ + kvbase + (dcol >> 6))) * 64 + (dcol & 63)) * LB + pos;
    *(s8v*)dst = *(s8v*)tmp;
  }
}

// ---------------------------------------------------------------------------
// Fused QKV GEMM (summary + regular), XCD-swizzled. grid = 396, block = 512.
// v-range stores TRANSPOSED directly (svT / rvT).
// ---------------------------------------------------------------------------
struct QkvA {
  const u16 *X, *WTs, *WTr;
  const float *b0s, *b1s, *b2s, *b0r, *b1r, *b2r;
  u16 *o0s, *o1s, *o2s, *o0r, *o1r, *o2r;        // o2* are V^T outputs
};

__global__ __launch_bounds__(512)
void qkv_k(QkvA a)
{
  int orig = blockIdx.x;
  int xcd = orig & 7, sidx = orig >> 3;
  int wg = (xcd < 4) ? (xcd * 50 + sidx) : (200 + (xcd - 4) * 49 + sidx);
  const int bx = wg % 12, by = wg / 12;
  const bool issum = (by == 0);
  const int c0 = bx * 128;

  __shared__ u16 Adb[256][72];
  __shared__ u16 Bdb[256][72];
  u16* Es = &Adb[0][0];

  const int tid  = threadIdx.x;
  const int lane = tid & 63;
  const int w    = tid >> 6;
  const int l15  = lane & 15;
  const int l4   = lane >> 4;
  const int wro  = (w >> 1) * 32;
  const int wco  = (w & 1) * 64;

  f4v acc[2][4];
  #pragma unroll
  for (int i = 0; i < 2; i++)
    #pragma unroll
    for (int j = 0; j < 4; j++) acc[i][j] = (f4v){0.f, 0.f, 0.f, 0.f};

  const u16* Xrow  = a.X + (size_t)by * 128 * 1024;
  const u16* WTrow = (issum ? a.WTs : a.WTr) + (size_t)c0 * 1024;
  gemm_core_db(Xrow, WTrow, Adb, Bdb, acc, tid, l15, l4, wro, wco);

  const int LB  = issum ? 64 : 2048;
  const int LBS = issum ? 6 : 11;
  const int grb = issum ? 0 : (by - 1) * 128;

  if (c0 < 1024) {          // Q: rope + scale
    epi_to_lds(acc, issum ? a.b0s : a.b0r, Es, c0 + wco, wro, wco, grb, LB, 1, !issum, true, l15, l4);
    __syncthreads();
    store_tile_bf16(Es, issum ? a.o0s : a.o0r, grb, c0, 16, LB, LBS, tid);
  } else if (c0 < 1280) {   // K: rope
    epi_to_lds(acc, issum ? a.b1s : a.b1r, Es, c0 - 1024 + wco, wro, wco, grb, LB, 1, !issum, false, l15, l4);
    __syncthreads();
    store_tile_bf16(Es, issum ? a.o1s : a.o1r, grb, c0 - 1024, 4, LB, LBS, tid);
  } else {                  // V: no rope, transposed store
    epi_to_lds(acc, issum ? a.b2s : a.b2r, Es, c0 - 1280 + wco, wro, wco, grb, LB, 0, false, false, l15, l4);
    __syncthreads();
    store_tile_vT(Es, issum ? a.o2s : a.o2r, grb, (c0 - 1280) >> 6, LB, LBS, tid);
  }
}

// ---------------------------------------------------------------------------
// Phase-1 output GEMM: k2 (bf16) / v2 (transposed) / so (fp32). grid = 12.
// ---------------------------------------------------------------------------
__global__ __launch_bounds__(512)
void gemm_p1_k(const u16* __restrict__ X, const u16* __restrict__ WT,
               const float* __restrict__ bk2, const float* __restrict__ bv2,
               const float* __restrict__ bso,
               u16* __restrict__ k2, u16* __restrict__ v2T, float* __restrict__ outsum)
{
  const int c0 = blockIdx.x * 128;

  __shared__ u16 Adb[256][72];
  __shared__ u16 Bdb[256][72];
  u16* Es = &Adb[0][0];

  const int tid  = threadIdx.x;
  const int lane = tid & 63;
  const int w    = tid >> 6;
  const int l15  = lane & 15;
  const int l4   = lane >> 4;
  const int wro  = (w >> 1) * 32;
  const int wco  = (w & 1) * 64;

  f4v acc[2][4];
  #pragma unroll
  for (int i = 0; i < 2; i++)
    #pragma unroll
    for (int j = 0; j < 4; j++) acc[i][j] = (f4v){0.f, 0.f, 0.f, 0.f};

  gemm_core_db(X, WT + (size_t)c0 * 1024, Adb, Bdb, acc, tid, l15, l4, wro, wco);

  if (c0 < 256) {
    epi_to_lds(acc, bk2, Es, c0 + wco, wro, wco, 0, 64, 0, false, false, l15, l4);
    __syncthreads();
    store_tile_bf16(Es, k2, 0, c0, 4, 64, 6, tid);
  } else if (c0 < 512) {
    epi_to_lds(acc, bv2, Es, c0 - 256 + wco, wro, wco, 0, 64, 0, false, false, l15, l4);
    __syncthreads();
    store_tile_vT(Es, v2T, 0, (c0 - 256) >> 6, 64, 6, tid);
  } else {
    float bv[4];
    #pragma unroll
    for (int cc = 0; cc < 4; cc++) bv[cc] = bso[c0 - 512 + wco + cc * 16 + l15];
    #pragma unroll
    for (int rc = 0; rc < 2; rc++)
      #pragma unroll
      for (int reg = 0; reg < 4; reg++) {
        int row = wro + rc * 16 + l4 * 4 + reg;
        #pragma unroll
        for (int cc = 0; cc < 4; cc++)
          outsum[(size_t)row * 1024 + c0 - 512 + wco + cc * 16 + l15] = acc[rc][cc][reg] + bv[cc];
      }
  }
}

// ---------------------------------------------------------------------------
// ro GEMM (unchanged). grid = 256, block = 512, XCD-swizzled.
// ---------------------------------------------------------------------------
__global__ __launch_bounds__(512)
void gemm_ro_k(const u16* __restrict__ X, const u16* __restrict__ WT,
               const float* __restrict__ Bp, float* __restrict__ out)
{
  int orig = blockIdx.x;
  int wg = (orig & 7) * 32 + (orig >> 3);
  const int bx = wg & 7, by = wg >> 3;
  const int c0 = bx * 128, r0 = by * 128;

  __shared__ u16 Adb[256][72];
  __shared__ u16 Bdb[256][72];

  const int tid  = threadIdx.x;
  const int lane = tid & 63;
  const int w    = tid >> 6;
  const int l15  = lane & 15;
  const int l4   = lane >> 4;
  const int wro  = (w >> 1) * 32;
  const int wco  = (w & 1) * 64;

  f4v acc[2][4];
  #pragma unroll
  for (int i = 0; i < 2; i++)
    #pragma unroll
    for (int j = 0; j < 4; j++) acc[i][j] = (f4v){0.f, 0.f, 0.f, 0.f};

  gemm_core_db(X + (size_t)r0 * 1024, WT + (size_t)c0 * 1024, Adb, Bdb, acc,
               tid, l15, l4, wro, wco);

  float bv[4];
  #pragma unroll
  for (int cc = 0; cc < 4; cc++) bv[cc] = Bp[c0 + wco + cc * 16 + l15];
  #pragma unroll
  for (int rc = 0; rc < 2; rc++)
    #pragma unroll
    for (int reg = 0; reg < 4; reg++) {
      int row = r0 + wro + rc * 16 + l4 * 4 + reg;
      #pragma unroll
      for (int cc = 0; cc < 4; cc++)
        out[(size_t)row * 1024 + c0 + wco + cc * 16 + l15] = acc[rc][cc][reg] + bv[cc];
    }
}

// ---------------------------------------------------------------------------
// Swapped-operand flash tile: S^T = mfma(K,Q), O^T = mfma(V,P).
// Lane owns ONE query q = qw + l15 (D col); keys/d live in (l4,reg).
// All LDS reads identical to the unswapped version; softmax is per-lane scalar:
// reduce = 15 in-reg fmax + 2 shfl (was 32 shfl). exp2 domain (Q pre-scaled).
// ---------------------------------------------------------------------------
template<int PHASE>
__device__ __forceinline__ void attn_tile(
    const u16 (&Kc)[64][72], const u16 (&Vc)[64][72], u16 (&Ptw)[16][72],
    const s8v& qf0, const s8v& qf1, f4v (&acc)[4],
    float& m, float& lsum, int kbase, int qw, int l15, int l4)
{
  f4v s[4];
  #pragma unroll
  for (int n = 0; n < 4; n++) {
    s8v kf0 = *(const s8v*)&Kc[n * 16 + l15][l4 * 8];
    s8v kf1 = *(const s8v*)&Kc[n * 16 + l15][32 + l4 * 8];
    f4v t = {0.f, 0.f, 0.f, 0.f};
    t = __builtin_amdgcn_mfma_f32_16x16x32_bf16(kf0, qf0, t, 0, 0, 0);
    t = __builtin_amdgcn_mfma_f32_16x16x32_bf16(kf1, qf1, t, 0, 0, 0);
    s[n] = t;      // s[n][reg] = S[key = kbase + n*16 + l4*4 + reg][q = qw+l15]
  }

  const int qrow = qw + l15;
  bool need_mask = (kbase == 0) ||
    (PHASE == 1 ? (((kbase - 1) >> 5) > qw) : ((kbase - 1) > qw));
  float tmax = -1e30f;
  if (need_mask) {
    #pragma unroll
    for (int n = 0; n < 4; n++)
      #pragma unroll
      for (int reg = 0; reg < 4; reg++) {
        int kidx = kbase + n * 16 + l4 * 4 + reg;
        bool ok;
        if (kbase == 0) ok = kidx <= ((PHASE == 1) ? qrow : (qrow >> 5));
        else { int kr = kidx - 64; ok = (PHASE == 1) ? ((kr >> 5) <= qrow) : (kr <= qrow); }
        float sv = ok ? s[n][reg] : -1e30f;
        s[n][reg] = sv;
        tmax = fmaxf(tmax, sv);
      }
  } else {
    #pragma unroll
    for (int n = 0; n < 4; n++)
      #pragma unroll
      for (int reg = 0; reg < 4; reg++) tmax = fmaxf(tmax, s[n][reg]);
  }
  tmax = fmaxf(tmax, __shfl_xor(tmax, 16));
  tmax = fmaxf(tmax, __shfl_xor(tmax, 32));

  if (__any(tmax > m)) {                       // exact rescale-skip
    float mn = fmaxf(m, tmax);
    float f  = __builtin_amdgcn_exp2f(m - mn);
    m = mn;
    lsum *= f;
    #pragma unroll
    for (int dt = 0; dt < 4; dt++)
      #pragma unroll
      for (int reg = 0; reg < 4; reg++) acc[dt][reg] *= f;
  }
  float rsum = 0.f;
  #pragma unroll
  for (int n = 0; n < 4; n++) {
    float p0 = __builtin_amdgcn_exp2f(s[n][0] - m);
    float p1 = __builtin_amdgcn_exp2f(s[n][1] - m);
    float p2 = __builtin_amdgcn_exp2f(s[n][2] - m);
    float p3 = __builtin_amdgcn_exp2f(s[n][3] - m);
    rsum += (p0 + p1) + (p2 + p3);
    uint2 pk;
    pk.x = (unsigned)f2bf_ru(p0) | ((unsigned)f2bf_ru(p1) << 16);
    pk.y = (unsigned)f2bf_ru(p2) | ((unsigned)f2bf_ru(p3) << 16);
    *(uint2*)&Ptw[l15][n * 16 + l4 * 4] = pk;  // P[q][key], 8B write
  }
  rsum += __shfl_xor(rsum, 16);
  rsum += __shfl_xor(rsum, 32);
  lsum += rsum;

  asm volatile("s_waitcnt lgkmcnt(0)" ::: "memory");   // P cross-lane visibility

  s8v pf0 = *(const s8v*)&Ptw[l15][l4 * 8];
  s8v pf1 = *(const s8v*)&Ptw[l15][32 + l4 * 8];
  #pragma unroll
  for (int dt = 0; dt < 4; dt++) {
    s8v vf0 = *(const s8v*)&Vc[dt * 16 + l15][l4 * 8];
    s8v vf1 = *(const s8v*)&Vc[dt * 16 + l15][32 + l4 * 8];
    acc[dt] = __builtin_amdgcn_mfma_f32_16x16x32_bf16(vf0, pf0, acc[dt], 0, 0, 0);
    acc[dt] = __builtin_amdgcn_mfma_f32_16x16x32_bf16(vf1, pf1, acc[dt], 0, 0, 0);
  }                                             // acc[dt][reg] = O[q=l15][d=dt*16+l4*4+reg]
}

// ---------------------------------------------------------------------------
// Phase 2 attention: 8 waves, 128 q/block, dbuf staging, balanced pairing.
// ---------------------------------------------------------------------------
__global__ __launch_bounds__(512)
void attn2_k(const u16* __restrict__ Q, const u16* __restrict__ KS,
             const u16* __restrict__ KR, const u16* __restrict__ VST,
             const u16* __restrict__ VRT, u16* __restrict__ Out)
{
  const int gid = blockIdx.x;
  const int qb  = (gid & 256) ? (15 - (gid & 15)) : (gid & 15);
  const int bh  = gid >> 4;
  const int h   = bh & 15, b = bh >> 4;
  const int q0  = qb * 128;
  const int kh  = h >> 2;

  __shared__ u16 Kt[2][64][72];
  __shared__ u16 Vt[2][64][72];
  __shared__ u16 Pt[8][16][72];

  const int tid = threadIdx.x, lane = tid & 63, w = tid >> 6;
  const int l15 = lane & 15, l4 = lane >> 4;
  const int qw  = q0 + w * 16;

  const u16* qp = Q + (((size_t)b * H_ + h) * R_ + qw + l15) * 64;
  s8v qf0 = *(const s8v*)(qp + l4 * 8);
  s8v qf1 = *(const s8v*)(qp + 32 + l4 * 8);

  f4v acc[4];
  #pragma unroll
  for (int dt = 0; dt < 4; dt++) acc[dt] = (f4v){0.f, 0.f, 0.f, 0.f};
  float m = -1e30f, lsum = 0.f;

  const int ntiles = (64 + q0 + 128) >> 6;
  const size_t bh_kv = (size_t)b * KVH_ + kh;
  const int r_ = tid >> 3, sg_ = (tid & 7) * 8;

  {
    const u16* kp = KS  + bh_kv * 4096;
    const u16* vp = VST + bh_kv * 4096;
    s8v k0 = *(const s8v*)(kp + r_ * 64 + sg_);
    s8v v0 = *(const s8v*)(vp + r_ * 64 + sg_);
    *(s8v*)&Kt[0][r_][sg_] = k0;
    *(s8v*)&Vt[0][r_][sg_] = v0;
  }
  __syncthreads();

  for (int kt = 0; kt < ntiles; kt++) {
    const int cur = kt & 1;
    const int kbase = kt * 64;
    const bool pre = (kt + 1 < ntiles);
    s8v knx, vnx;
    if (pre) {
      const u16* kp = KR  + (bh_kv * R_ + kbase) * 64;
      const u16* vp = VRT + bh_kv * 64 * R_ + kbase;
      knx = *(const s8v*)(kp + r_ * 64 + sg_);
      vnx = *(const s8v*)(vp + (size_t)r_ * R_ + sg_);
    }

    const bool active = (kbase == 0) || (kbase - 64 <= qw + 15);
    if (active)
      attn_tile<2>(Kt[cur], Vt[cur], Pt[w], qf0, qf1, acc, m, lsum,
                   kbase, qw, l15, l4);

    if (pre) {
      *(s8v*)&Kt[cur ^ 1][r_][sg_] = knx;
      *(s8v*)&Vt[cur ^ 1][r_][sg_] = vnx;
    }
    __syncthreads();
  }

  // O^T epilogue: lane owns row q = qw + l15; 4 x 8B stores cover its 64 d.
  float linv = 1.f / lsum;
  u16* o = Out + ((size_t)b * R_ + qw + l15) * D_ + h * 64;
  #pragma unroll
  for (int dt = 0; dt < 4; dt++) {
    ushort4 t4;
    t4.x = f2bf(acc[dt][0] * linv);
    t4.y = f2bf(acc[dt][1] * linv);
    t4.z = f2bf(acc[dt][2] * linv);
    t4.w = f2bf(acc[dt][3] * linv);
    *(ushort4*)(o + dt * 16 + l4 * 4) = t4;
  }
}

// ---------------------------------------------------------------------------
// Phase 1 attention, split-K (swapped layout; fp32 partials).
// ---------------------------------------------------------------------------
__global__ __launch_bounds__(256)
void attn1_k(const u16* __restrict__ Q, const u16* __restrict__ KS,
             const u16* __restrict__ KR, const u16* __restrict__ VST,
             const u16* __restrict__ VRT,
             float* __restrict__ pO, float* __restrict__ pml)
{
  const int gid = blockIdx.x;
  const int ck  = gid & 7;
  const int bh  = gid >> 3;
  const int h   = bh & 15, b = bh >> 4;
  const int kh  = h >> 2;
  const int kt0 = (ck * 33) >> 3;
  const int kt1 = ((ck + 1) * 33) >> 3;

  __shared__ u16 Kt[2][64][72];
  __shared__ u16 Vt[2][64][72];
  __shared__ u16 Pt[4][16][72];

  const int tid = threadIdx.x, lane = tid & 63, w = tid >> 6;
  const int l15 = lane & 15, l4 = lane >> 4;
  const int qw  = w * 16;

  const u16* qp = Q + (((size_t)b * H_ + h) * S_ + qw + l15) * 64;
  s8v qf0 = *(const s8v*)(qp + l4 * 8);
  s8v qf1 = *(const s8v*)(qp + 32 + l4 * 8);

  f4v acc[4];
  #pragma unroll
  for (int dt = 0; dt < 4; dt++) acc[dt] = (f4v){0.f, 0.f, 0.f, 0.f};
  float m = -1e30f, lsum = 0.f;

  const size_t bh_kv = (size_t)b * KVH_ + kh;
  const int r_ = tid >> 3, sg_ = (tid & 7) * 8;

  {
    const u16 *kp, *vp; int vstr;
    if (kt0 == 0) { kp = KS + bh_kv * 4096; vp = VST + bh_kv * 4096; vstr = 64; }
    else {
      kp = KR  + (bh_kv * R_ + kt0 * 64 - 64) * 64;
      vp = VRT + bh_kv * 64 * R_ + (kt0 * 64 - 64);
      vstr = R_;
    }
    s8v ka0 = *(const s8v*)(kp + r_ * 64 + sg_);
    s8v ka1 = *(const s8v*)(kp + (r_ + 32) * 64 + sg_);
    s8v va0 = *(const s8v*)(vp + (size_t)r_ * vstr + sg_);
    s8v va1 = *(const s8v*)(vp + (size_t)(r_ + 32) * vstr + sg_);
    *(s8v*)&Kt[0][r_][sg_]      = ka0;
    *(s8v*)&Kt[0][r_ + 32][sg_] = ka1;
    *(s8v*)&Vt[0][r_][sg_]      = va0;
    *(s8v*)&Vt[0][r_ + 32][sg_] = va1;
  }
  __syncthreads();

  for (int kt = kt0; kt < kt1; kt++) {
    const int cur = (kt - kt0) & 1;
    const int kbase = kt * 64;
    const bool pre = (kt + 1 < kt1);
    s8v ka0, ka1, va0, va1;
    if (pre) {
      const u16* kp = KR  + (bh_kv * R_ + kbase) * 64;
      const u16* vp = VRT + bh_kv * 64 * R_ + kbase;
      ka0 = *(const s8v*)(kp + r_ * 64 + sg_);
      ka1 = *(const s8v*)(kp + (r_ + 32) * 64 + sg_);
      va0 = *(const s8v*)(vp + (size_t)r_ * R_ + sg_);
      va1 = *(const s8v*)(vp + (size_t)(r_ + 32) * R_ + sg_);
    }

    const bool active = (kbase == 0) || (((kbase - 64) >> 5) <= qw + 15);
    if (active)
      attn_tile<1>(Kt[cur], Vt[cur], Pt[w], qf0, qf1, acc, m, lsum,
                   kbase, qw, l15, l4);

    if (pre) {
      *(s8v*)&Kt[cur ^ 1][r_][sg_]      = ka0;
      *(s8v*)&Kt[cur ^ 1][r_ + 32][sg_] = ka1;
      *(s8v*)&Vt[cur ^ 1][r_][sg_]      = va0;
      *(s8v*)&Vt[cur ^ 1][r_ + 32][sg_] = va1;
    }
    __syncthreads();
  }

  // partial: unnormalized O^T rows + (m, l) per q = qw + l15
  float* po = pO + (((size_t)ck * 32 + bh) * 64 + qw + l15) * 64;
  #pragma unroll
  for (int dt = 0; dt < 4; dt++)
    *(f4v*)(po + dt * 16 + l4 * 4) = acc[dt];
  if (l4 == 0) {
    float* pm = pml + (((size_t)ck * 32 + bh) * 64 + qw + l15) * 2;
    pm[0] = m; pm[1] = lsum;
  }
}

// Combine 8 phase-1 partials -> sattn bf16 (exp2-domain weights)
__global__ __launch_bounds__(256)
void comb1_k(const float* __restrict__ pO, const float* __restrict__ pml,
             u16* __restrict__ sattn)
{
  const int bh = blockIdx.x;
  const int b = bh >> 4, h = bh & 15;
  const int q  = threadIdx.x >> 2;
  const int d0 = (threadIdx.x & 3) * 16;
  float mv[8], lv[8], mstar = -1e30f;
  #pragma unroll
  for (int c = 0; c < 8; c++) {
    const float* p = pml + (((size_t)c * 32 + bh) * 64 + q) * 2;
    mv[c] = p[0]; lv[c] = p[1];
    mstar = fmaxf(mstar, mv[c]);
  }
  float o[16];
  #pragma unroll
  for (int j = 0; j < 16; j++) o[j] = 0.f;
  float lsum = 0.f;
  #pragma unroll
  for (int c = 0; c < 8; c++) {
    float wgt = __builtin_amdgcn_exp2f(mv[c] - mstar);
    lsum += lv[c] * wgt;
    const float* po = pO + (((size_t)c * 32 + bh) * 64 + q) * 64 + d0;
    #pragma unroll
    for (int j = 0; j < 16; j++) o[j] += po[j] * wgt;
  }
  float inv = 1.f / lsum;
  u16 ob[16];
  #pragma unroll
  for (int j = 0; j < 16; j++) ob[j] = f2bf(o[j] * inv);
  u16* out = sattn + ((size_t)(b * 64 + q)) * 1024 + h * 64 + d0;
  *(s8v*)out       = *(s8v*)&ob[0];
  *(s8v*)(out + 8) = *(s8v*)&ob[8];
}

extern "C" void kernel_launch(void* const* d_in, const int* in_sizes, int n_in,
                              void* d_out, int out_size, void* d_ws, size_t ws_size,
                              hipStream_t stream)
{
  (void)out_size; (void)ws_size;

  static const int expect[22] = {
    131072, 4194304,
    1048576, 1024, 262144, 256,
    262144, 256, 1048576, 1024,
    1048576, 1024, 262144, 256,
    262144, 256, 1048576, 1024,
    262144, 256, 262144, 256
  };
  if (n_in < 22) return;
  for (int i = 0; i < 22; i++) if (in_sizes[i] != expect[i]) return;

  const float* sum_x = (const float*)d_in[0];
  const float* reg_x = (const float*)d_in[1];
  const float* w_sq = (const float*)d_in[2];  const float* b_sq = (const float*)d_in[3];
  const float* w_sk = (const float*)d_in[4];  const float* b_sk = (const float*)d_in[5];
  const float* w_sv = (const float*)d_in[6];  const float* b_sv = (const float*)d_in[7];
  const float* w_so = (const float*)d_in[8];  const float* b_so = (const float*)d_in[9];
  const float* w_rq = (const float*)d_in[10]; const float* b_rq = (const float*)d_in[11];
  const float* w_rk = (const float*)d_in[12]; const float* b_rk = (const float*)d_in[13];
  const float* w_rv = (const float*)d_in[14]; const float* b_rv = (const float*)d_in[15];
  const float* w_ro = (const float*)d_in[16]; const float* b_ro = (const float*)d_in[17];
  const float* w_k2 = (const float*)d_in[18]; const float* b_k2 = (const float*)d_in[19];
  const float* w_v2 = (const float*)d_in[20]; const float* b_v2 = (const float*)d_in[21];

  u16* ws    = (u16*)d_ws;
  u16* xs_bf = ws;                    // 131072
  u16* xr_bf = xs_bf + 131072;        // 4194304
  u16* wt_s  = xr_bf + 4194304;       // 1572864  [sq|sk|sv]
  u16* wt_r  = wt_s  + 1572864;       // 1572864  [rq|rk|rv]
  u16* wt_p  = wt_r  + 1572864;       // 1572864  [k2|v2|so]
  u16* wt_ro = wt_p  + 1572864;       // 1048576
  u16* sq    = wt_ro + 1048576;       // 131072   [B][H][S][64]
  u16* sk    = sq    + 131072;        // 32768    [B][KVH][S][64]
  u16* svT   = sk    + 32768;         // 32768    [B][KVH][64][S]   (V^T direct)
  u16* rq    = svT   + 32768;         // 4194304  [B][H][R][64]
  u16* rk    = rq    + 4194304;       // 1048576  [B][KVH][R][64]
  u16* rvT   = rk    + 1048576;       // 1048576  [B][KVH][64][R]   (V^T direct)
  u16* sattn = rvT   + 1048576;       // 131072   [B*S][D]
  u16* k2    = sattn + 131072;        // 32768
  u16* v2T   = k2    + 32768;         // 32768    [B][KVH][64][S]   (V^T direct)
  u16* rattn = v2T   + 32768;         // 4194304  [B*R][D]

  float* pO  = (float*)rattn;         // phase-1 partials alias rattn
  float* pml = pO + 1048576;

  float* out_sum = (float*)d_out;
  float* out_reg = out_sum + 131072;

  dim3 blk(256);

  WT10 wt;
  wt.w[0] = w_sq; wt.o[0] = wt_s;              wt.C[0] = 1024;
  wt.w[1] = w_rq; wt.o[1] = wt_r;              wt.C[1] = 1024;
  wt.w[2] = w_so; wt.o[2] = wt_p + 512 * 1024; wt.C[2] = 1024;
  wt.w[3] = w_ro; wt.o[3] = wt_ro;             wt.C[3] = 1024;
  wt.w[4] = w_sk; wt.o[4] = wt_s + 1024 * 1024; wt.C[4] = 256;
  wt.w[5] = w_sv; wt.o[5] = wt_s + 1280 * 1024; wt.C[5] = 256;
  wt.w[6] = w_rk; wt.o[6] = wt_r + 1024 * 1024; wt.C[6] = 256;
  wt.w[7] = w_rv; wt.o[7] = wt_r + 1280 * 1024; wt.C[7] = 256;
  wt.w[8] = w_k2; wt.o[8] = wt_p;               wt.C[8] = 256;
  wt.w[9] = w_v2; wt.o[9] = wt_p + 256 * 1024;  wt.C[9] = 256;
  transw_k<<<dim3(32, 32, 10), blk, 0, stream>>>(wt);
  convx_k<<<dim3(2112), blk, 0, stream>>>(sum_x, reg_x, xs_bf, xr_bf);

  QkvA qa;
  qa.X = xs_bf; qa.WTs = wt_s; qa.WTr = wt_r;
  qa.b0s = b_sq; qa.b1s = b_sk; qa.b2s = b_sv;
  qa.b0r = b_rq; qa.b1r = b_rk; qa.b2r = b_rv;
  qa.o0s = sq; qa.o1s = sk; qa.o2s = svT;
  qa.o0r = rq; qa.o1r = rk; qa.o2r = rvT;
  qkv_k<<<dim3(396), dim3(512), 0, stream>>>(qa);

  attn1_k<<<dim3(256), blk, 0, stream>>>(sq, sk, rk, svT, rvT, pO, pml);
  comb1_k<<<dim3(32), blk, 0, stream>>>(pO, pml, sattn);

  gemm_p1_k<<<dim3(12), dim3(512), 0, stream>>>(sattn, wt_p, b_k2, b_v2, b_so, k2, v2T, out_sum);

  attn2_k<<<dim3(512), dim3(512), 0, stream>>>(rq, k2, rk, v2T, rvT, rattn);

  gemm_ro_k<<<dim3(256), dim3(512), 0, stream>>>(rattn, wt_ro, b_ro, out_reg);
}